// Round 8
// baseline (800.477 us; speedup 1.0000x reference)
//
#include <hip/hip_runtime.h>

// Problem constants (fixed by setup_inputs)
#define NN   4000
#define PP   200
#define DD   8
#define KAP  16
#define NN0  1000
#define MMR  12000
#define NUGF 1e-6f

// Rpart row stride (200 R cols + 1 v col + pad)
#define RST  204
// linv slab col stride
#define ACST 64
// chol: panel-transpose LDS row stride (floats), tile count of 50x50 lower tri
#define PTS   208
#define NTILE 1275
// crh Bt row stride
#define BTS  260
// XT padded row stride (cols 200..255 zeroed once -> async 64-lane loads safe)
#define XPS  256

// ---- workspace layout (float offsets); RPART last (variable size) ----
#define OFF_THS    0
#define OFF_THI    (OFF_THS   + KAP*NN*DD)
#define OFF_TH0S   (OFF_THI   + KAP*PP*DD)
#define OFF_AFULL  (OFF_TH0S  + KAP*NN0*DD)
#define OFF_LT     (OFF_AFULL + KAP*PP*PP)
#define OFF_LROW   (OFF_LT    + KAP*PP*PP)
#define OFF_XB     (OFF_LROW  + KAP*PP*PP)
#define OFF_DLI    (OFF_XB    + KAP*PP*PP)
#define OFF_CRH    (OFF_DLI   + KAP*PP)
#define OFF_DINV   (OFF_CRH   + KAP*NN*PP)
#define OFF_DG     (OFF_DINV  + KAP*NN)
#define OFF_VV     (OFF_DG    + KAP*NN)
#define OFF_WV     (OFF_VV    + KAP*PP)
#define OFF_CG     (OFF_WV    + KAP*PP)
#define OFF_GPART  (OFF_CG    + KAP*NN)
#define OFF_GHAT   (OFF_GPART + KAP*8*1024)
#define OFF_RPART  (OFF_GHAT  + KAP*NN0)
// XT (padded, KAP*PP*XPS = 819200 floats) lives in the LROW+XB region (1.28M floats)
#define OFF_XT     OFF_LROW
// need(NCH) = OFF_RPART + KAP*NCH*PP*RST floats

// async global->LDS, 16B per lane; LDS base must be wave-uniform
__device__ __forceinline__ void gld_lds16(const float* g, float* l) {
  __builtin_amdgcn_global_load_lds(
      (const __attribute__((address_space(1))) unsigned int*)g,
      (__attribute__((address_space(3))) unsigned int*)l, 16, 0, 0);
}

// ---------------------------------------------------------------------------
// K0: per-k scaled inputs  x / exp(lmb_j)
__global__ void scale_kernel(const float* __restrict__ theta, const float* __restrict__ thetai,
                             const float* __restrict__ theta0, const float* __restrict__ Lmb,
                             float* __restrict__ ths, float* __restrict__ thi, float* __restrict__ th0s) {
  int k = blockIdx.y;
  int idx = blockIdx.x * 256 + threadIdx.x;
  const int total = (NN + PP + NN0) * DD;
  if (idx >= total) return;
  int row = idx >> 3, j = idx & 7;
  float ils = __expf(-Lmb[k * 9 + j]);
  if (row < NN) {
    ths[(k * NN + row) * DD + j] = theta[row * DD + j] * ils;
  } else if (row < NN + PP) {
    int r = row - NN;
    thi[(k * PP + r) * DD + j] = thetai[r * DD + j] * ils;
  } else {
    int r = row - NN - PP;
    th0s[(k * NN0 + r) * DD + j] = theta0[r * DD + j] * ils;
  }
}

// ---------------------------------------------------------------------------
// K0b: build C_i (full symmetric) per k into Afull
__global__ void buildci_kernel(const float* __restrict__ thi, const float* __restrict__ Lmb,
                               float* __restrict__ A) {
  int k = blockIdx.x;
  __shared__ float ti[PP * DD];
  for (int i = threadIdx.x; i < PP * DD; i += 256) ti[i] = thi[k * PP * DD + i];
  __syncthreads();
  float lsig = Lmb[k * 9 + 8];
  float* Ak = A + k * PP * PP;
  for (int idx = threadIdx.x; idx < PP * PP; idx += 256) {
    int i = idx / PP, j = idx - i * PP;
    float prod = 1.f, sum = 0.f;
#pragma unroll
    for (int t = 0; t < DD; ++t) {
      float s = fabsf(ti[i * DD + t] - ti[j * DD + t]);
      prod = __fmaf_rn(prod, s, prod);  // prod *= (1+s)
      sum += s;
    }
    float val = prod * __expf(lsig - sum);
    if (i == j) val += NUGF * __expf(lsig);
    Ak[idx] = val;
  }
}

// ---------------------------------------------------------------------------
// K1/K6: Cholesky of a 200x200 SPD matrix, REGISTER-resident trailing matrix.
// amdgpu_waves_per_eu(4,4): PIN occupancy to 4 waves/EU -> 128-VGPR budget.
__device__ __forceinline__ float rdlane(float v, int l) {
  return __int_as_float(__builtin_amdgcn_readlane(__float_as_int(v), l));
}

__global__ __launch_bounds__(1024) __attribute__((amdgpu_waves_per_eu(4, 4)))
void chol_kernel(const float* __restrict__ Ain,
                 float* __restrict__ LT,
                 float* __restrict__ dli) {
  int k = blockIdx.x;
  Ain += (size_t)k * PP * PP; LT += (size_t)k * PP * PP; dli += (size_t)k * PP;
  __shared__ __align__(16) float Ppre[8 * PTS];  // staged panel, [q][r] absolute r
  __shared__ __align__(16) float Pt[8 * PTS];    // factorized panel, [q][r]
  const int tid = threadIdx.x;

  // ---- decode owned tiles (row-tile-major lower triangle), load to regs ----
  int t_rt[2], t_ct[2];
  bool t_ok[2];
  float4 acc[2][4];
#pragma unroll
  for (int t = 0; t < 2; ++t) {
    int ti = (tid - 64) + t * 960;
    t_ok[t] = (tid >= 64) && (ti < NTILE);
    int tie = t_ok[t] ? ti : 0;
    int rt = (int)((sqrtf(8.0f * (float)tie + 1.0f) - 1.0f) * 0.5f);
    while ((rt + 1) * (rt + 2) / 2 <= tie) ++rt;
    while (rt * (rt + 1) / 2 > tie) --rt;
    int ct = tie - rt * (rt + 1) / 2;
    t_rt[t] = rt; t_ct[t] = ct;
    if (t_ok[t]) {
      const float* src = Ain + (size_t)(4 * rt) * PP + 4 * ct;
#pragma unroll
      for (int i = 0; i < 4; ++i) acc[t][i] = *(const float4*)(src + (size_t)i * PP);
    } else {
#pragma unroll
      for (int i = 0; i < 4; ++i) acc[t][i] = make_float4(0.f, 0.f, 0.f, 0.f);
    }
  }

  float preg[4][8];  // wave-0 panel registers (live across the barrier)
  for (int s = 0; s < 25; ++s) {
    const int jb = 8 * s;
    // ---- owners of the two panel tile-columns stage them to LDS ----
#pragma unroll
    for (int t = 0; t < 2; ++t) {
      if (t_ok[t] && (t_ct[t] >> 1) == s) {
        int q0 = 4 * t_ct[t] - jb;   // 0 or 4
        int r0 = 4 * t_rt[t];
#pragma unroll
        for (int i = 0; i < 4; ++i) {
          Ppre[(q0 + 0) * PTS + r0 + i] = acc[t][i].x;
          Ppre[(q0 + 1) * PTS + r0 + i] = acc[t][i].y;
          Ppre[(q0 + 2) * PTS + r0 + i] = acc[t][i].z;
          Ppre[(q0 + 3) * PTS + r0 + i] = acc[t][i].w;
        }
      }
    }
    __syncthreads();
    const int nrows = PP - jb;
    // ---- wave 0: panel factorization in registers, readlane chain ----
    if (tid < 64) {
      const int L = tid;
#pragma unroll
      for (int u = 0; u < 4; ++u) {
        int rl = L + 64 * u;
#pragma unroll
        for (int c = 0; c < 8; ++c)
          preg[u][c] = (rl < nrows && rl >= c) ? Ppre[c * PTS + jb + rl] : 0.f;
      }
#pragma unroll
      for (int jj = 0; jj < 8; ++jj) {
        float dv = rdlane(preg[0][jj], jj);
        float l = sqrtf(fmaxf(dv, 1e-12f));
        float inv = 1.0f / l;
#pragma unroll
        for (int u = 0; u < 4; ++u)
          if (u > 0 || L > jj) preg[u][jj] *= inv;
        if (L == jj) { preg[0][jj] = l; dli[jb + jj] = inv; }
#pragma unroll
        for (int c = 0; c < 8; ++c) {
          if (c > jj) {
            float pc = rdlane(preg[0][jj], c);
#pragma unroll
            for (int u = 0; u < 4; ++u)
              preg[u][c] = __fmaf_rn(-preg[u][jj], pc, preg[u][c]);
          }
        }
      }
#pragma unroll
      for (int u = 0; u < 4; ++u) {
        int rl = L + 64 * u;
        if (rl < nrows) {
#pragma unroll
          for (int c = 0; c < 8; ++c) Pt[c * PTS + jb + rl] = preg[u][c];
        }
      }
    }
    __syncthreads();
    // ---- wave 0: LT global writes off the critical path (drain overlaps) ----
    if (tid < 64) {
      const int L = tid;
#pragma unroll
      for (int u = 0; u < 4; ++u) {
        int rl = L + 64 * u;
        if (rl < nrows) {
#pragma unroll
          for (int c = 0; c < 8; ++c)
            if (rl >= c) LT[(jb + c) * PP + jb + rl] = preg[u][c];
        }
      }
    }
    // ---- rank-8 trailing update on register tiles ----
    const int ctmin = 2 * s + 2;
#pragma unroll
    for (int t = 0; t < 2; ++t) {
      if (t_ok[t] && t_ct[t] >= ctmin) {
        const float* pr = Pt + 4 * t_rt[t];
        const float* pcl = Pt + 4 * t_ct[t];
#pragma unroll
        for (int q = 0; q < 8; ++q) {
          float4 a = *(const float4*)(pr + q * PTS);   // broadcast within wave
          float4 b = *(const float4*)(pcl + q * PTS);  // consecutive float4s
          acc[t][0].x = __fmaf_rn(-a.x, b.x, acc[t][0].x);
          acc[t][0].y = __fmaf_rn(-a.x, b.y, acc[t][0].y);
          acc[t][0].z = __fmaf_rn(-a.x, b.z, acc[t][0].z);
          acc[t][0].w = __fmaf_rn(-a.x, b.w, acc[t][0].w);
          acc[t][1].x = __fmaf_rn(-a.y, b.x, acc[t][1].x);
          acc[t][1].y = __fmaf_rn(-a.y, b.y, acc[t][1].y);
          acc[t][1].z = __fmaf_rn(-a.y, b.z, acc[t][1].z);
          acc[t][1].w = __fmaf_rn(-a.y, b.w, acc[t][1].w);
          acc[t][2].x = __fmaf_rn(-a.z, b.x, acc[t][2].x);
          acc[t][2].y = __fmaf_rn(-a.z, b.y, acc[t][2].y);
          acc[t][2].z = __fmaf_rn(-a.z, b.z, acc[t][2].z);
          acc[t][2].w = __fmaf_rn(-a.z, b.w, acc[t][2].w);
          acc[t][3].x = __fmaf_rn(-a.w, b.x, acc[t][3].x);
          acc[t][3].y = __fmaf_rn(-a.w, b.y, acc[t][3].y);
          acc[t][3].z = __fmaf_rn(-a.w, b.z, acc[t][3].z);
          acc[t][3].w = __fmaf_rn(-a.w, b.w, acc[t][3].w);
        }
      }
    }
  }
}

// ---------------------------------------------------------------------------
// K2: X = L^{-1}, column-parallel forward substitution. grid (4, KAP).
// Output stored TRANSPOSED + PADDED: XT[c*XPS + t] = X[t][c]; cols t=200..255
// zeroed once (allows unconditional 64-lane global_load_lds in crh).
__global__ __launch_bounds__(256) void linv_kernel(const float* __restrict__ LT,
                                                   const float* __restrict__ dli_g,
                                                   float* __restrict__ XT) {
  int cb = blockIdx.x, k = blockIdx.y;
  LT += (size_t)k * PP * PP; dli_g += k * PP; XT += (size_t)k * PP * XPS;
  __shared__ float acc[PP * ACST];   // 51.2 KB slab: acc[r][i]
  __shared__ float Pn[8 * PP];       // panel: Pn[q][r] = LT[t0+q][r] = L[r][t0+q]
  __shared__ float xf[8 * ACST];
  __shared__ float dl[PP];
  const int tid = threadIdx.x;
  const int i = tid & 63, rg = tid >> 6;
  const int c = cb + 4 * i;          // owned column (valid if c < PP)
  for (int idx = tid; idx < PP * ACST; idx += 256) acc[idx] = 0.f;
  for (int r = tid; r < PP; r += 256) dl[r] = dli_g[r];
  // zero the padded tail (cols 200..255 of each owned row), once
  {
    float4 z4 = make_float4(0.f, 0.f, 0.f, 0.f);
    for (int idx = tid; idx < 50 * 14; idx += 256) {
      int il = idx / 14, f4 = idx - il * 14;
      int c2 = cb + 4 * il;   // < 200 by construction
      *(float4*)&XT[(size_t)c2 * XPS + 200 + 4 * f4] = z4;
    }
  }
  __syncthreads();
  for (int s = 0; s < 25; ++s) {
    const int t0 = 8 * s;
    for (int idx = tid; idx < 8 * PP; idx += 256) Pn[idx] = LT[t0 * PP + idx];
    __syncthreads();
    if (rg == 0) {
      float xq[8];
#pragma unroll
      for (int q = 0; q < 8; ++q) {
        int t = t0 + q;
        float sv = acc[t * ACST + i];
#pragma unroll
        for (int m = 0; m < 8; ++m)
          if (m < q) sv = __fmaf_rn(Pn[m * PP + t], xq[m], sv);
        float xv = (((t == c) ? 1.0f : 0.0f) - sv) * dl[t];
        xq[q] = xv;
        xf[q * ACST + i] = xv;
      }
    }
    __syncthreads();
    // XT store: float4 along t (t0+4*q4 .. +3) for owned columns
    if (tid < 128) {
      int q4 = tid >> 6, il = tid & 63;
      int c2 = cb + 4 * il;
      if (c2 < PP) {
        float4 v4 = make_float4(xf[(q4 * 4 + 0) * ACST + il], xf[(q4 * 4 + 1) * ACST + il],
                                xf[(q4 * 4 + 2) * ACST + il], xf[(q4 * 4 + 3) * ACST + il]);
        *(float4*)&XT[(size_t)c2 * XPS + t0 + 4 * q4] = v4;
      }
    }
    for (int r = t0 + 8 + rg; r < PP; r += 4) {
      float v = acc[r * ACST + i];
#pragma unroll
      for (int q = 0; q < 8; ++q)
        v = __fmaf_rn(Pn[q * PP + r], xf[q * ACST + i], v);
      acc[r * ACST + i] = v;
    }
    __syncthreads();
  }
}

// ---------------------------------------------------------------------------
// K6b: w = R^{-1} v = X^T (X v). X stored transposed/padded (XT[c*XPS+t]);
// summation ORDER identical (bit-identical w).
__global__ __launch_bounds__(256) void rsolve_kernel(const float* __restrict__ XT,
                                                     const float* __restrict__ v,
                                                     float* __restrict__ w) {
  int k = blockIdx.x;
  XT += (size_t)k * PP * XPS; v += k * PP; w += k * PP;
  __shared__ float vl[PP], yl[PP];
  int tid = threadIdx.x, lane = tid & 63, rg = tid >> 6;
  for (int i = tid; i < PP; i += 256) vl[i] = v[i];
  __syncthreads();
  // y = X v ; X[r][c] = XT[c*XPS+r]
  for (int r = rg; r < PP; r += 4) {
    float s = 0.f;
    for (int c = lane; c < PP; c += 64) s = __fmaf_rn(XT[(size_t)c * XPS + r], vl[c], s);
#pragma unroll
    for (int off = 32; off > 0; off >>= 1) s += __shfl_xor(s, off, 64);
    if (lane == 0) yl[r] = s;
  }
  __syncthreads();
  // w = X^T y ; X[r][tid] = XT[tid*XPS+r]
  if (tid < PP) {
    float s = 0.f;
    for (int r = 0; r < PP; ++r) s = __fmaf_rn(XT[(size_t)tid * XPS + r], yl[r], s);
    w[tid] = s;
  }
}

// ---------------------------------------------------------------------------
// K3: Crh = c_fi @ Linv^T, async B-staging; 32-row tiles; v6: DOUBLE-BUFFERED
// Bt. Loads for jb+16 are issued into Bt[cur^1] right AFTER the consume
// barrier, so they fly during the whole ~1024-cycle FMA phase; the post-FMA
// barrier's implicit vmcnt(0) finds them landed -> zero exposed load latency
// in steady state (v4/v5 stalled ~300cy at every pre-FMA barrier: cov phase
// << L2 latency). Barrier count, FMA values and order unchanged ->
// bit-identical. LDS 26.6->42.9 KB (3 blocks/CU); pipelining covers it.
__global__ __launch_bounds__(256) void crh_kernel(const float* __restrict__ ths,
                                                  const float* __restrict__ thi,
                                                  const float* __restrict__ Lmb,
                                                  const float* __restrict__ XT,
                                                  const float* __restrict__ Mg,
                                                  float* __restrict__ Crh,
                                                  float* __restrict__ Dinv,
                                                  float* __restrict__ Dg) {
  int k = blockIdx.y, rt = blockIdx.x, r0 = rt * 32;
  const float* thk = ths + k * NN * DD;
  const float* XTk = XT + (size_t)k * PP * XPS;
  float* Ck = Crh + (size_t)k * NN * PP;
  __shared__ __align__(16) float ts[32 * 9];
  __shared__ __align__(16) float til[PP * DD];     // inducing pts, staged once
  __shared__ __align__(16) float At[16 * 32];
  __shared__ __align__(16) float Bt[2][16 * BTS];  // double-buffered
  int tid = threadIdx.x, tx = tid & 15, ty = tid >> 4;
  const int lr = tid & 63;   // lane in wave
  const int wq = tid >> 6;   // wave id 0..3
  float lsig = Lmb[k * 9 + 8];
  {
    int r = tid >> 3, j = tid & 7;   // tid < 256 = 32*8 exactly
    ts[r * 9 + j] = thk[(r0 + r) * DD + j];
  }
  for (int idx = tid; idx < PP * DD; idx += 256) til[idx] = thi[k * PP * DD + idx];
  // prologue: issue async loads for jb=0 into Bt[0] (rows 0..15 all < PP)
#pragma unroll
  for (int u = 0; u < 4; ++u) {
    int kk = wq + 4 * u;           // wave-uniform
    gld_lds16(XTk + (size_t)kk * XPS + lr * 4, &Bt[0][kk * BTS]);
  }
  __syncthreads();   // ts/til visible (also drains prologue loads; one-time)

  float acc[2][16];
#pragma unroll
  for (int i = 0; i < 2; ++i)
#pragma unroll
    for (int q = 0; q < 16; ++q) acc[i][q] = 0.f;

  int cur = 0;
  for (int jb = 0; jb < PP; jb += 16) {
    // ---- cov -> At for this jb (LDS-only) ----
    for (int idx = tid; idx < 16 * 32; idx += 256) {
      int r = idx & 31, kk = idx >> 5;
      float va = 0.f;
      int kkg = jb + kk;
      if (kkg < PP) {
        float prod = 1.f, sum = 0.f;
#pragma unroll
        for (int t = 0; t < DD; ++t) {
          float s = fabsf(ts[r * 9 + t] - til[kkg * DD + t]);
          prod = __fmaf_rn(prod, s, prod);
          sum += s;
        }
        va = prod * __expf(lsig - sum);
      }
      At[kk * 32 + r] = va;
    }
    __syncthreads();   // At visible; Bt[cur] loads drained (issued >= 1 phase ago)
    // ---- issue next-jb loads into the OTHER buffer (fly under the FMA block)
    {
      int jn = jb + 16;
#pragma unroll
      for (int u = 0; u < 4; ++u) {
        int kk = wq + 4 * u;         // wave-uniform
        int row = jn + kk;
        if (row < PP)                // wave-uniform guard
          gld_lds16(XTk + (size_t)row * XPS + lr * 4, &Bt[cur ^ 1][kk * BTS]);
        // rows >= PP keep stale data; At[kk]=0 there -> contributes exact 0
      }
    }
    // ---- FMA block on Bt[cur] (values/order unchanged) ----
    const float* Bc = &Bt[cur][0];
#pragma unroll
    for (int kk = 0; kk < 16; ++kk) {
      float2 a2 = *(const float2*)&At[kk * 32 + ty * 2];
      const float* bp = &Bc[kk * BTS + tx * 4];
      float bv[16];
      *(float4*)&bv[0]  = *(const float4*)(bp);
      *(float4*)&bv[4]  = *(const float4*)(bp + 64);
      *(float4*)&bv[8]  = *(const float4*)(bp + 128);
      *(float4*)&bv[12] = *(const float4*)(bp + 192);
      float av[2] = {a2.x, a2.y};
#pragma unroll
      for (int i = 0; i < 2; ++i)
#pragma unroll
        for (int q = 0; q < 16; ++q)
          acc[i][q] = __fmaf_rn(av[i], bv[q], acc[i][q]);
    }
    __syncthreads();   // At rewrite protection; next-buf loads long since landed
    cur ^= 1;
  }
  // store: thread cols c = tx*4 + 64q (all multiples of 4; c<PP => full float4 valid)
#pragma unroll
  for (int i = 0; i < 2; ++i) {
    int r = r0 + ty * 2 + i;   // < 4000 always
#pragma unroll
    for (int q = 0; q < 4; ++q) {
      int c = tx * 4 + 64 * q;
      if (c < PP) {
        float4 v = make_float4(acc[i][q * 4], acc[i][q * 4 + 1], acc[i][q * 4 + 2], acc[i][q * 4 + 3]);
        *(float4*)&Ck[r * PP + c] = v;
      }
    }
  }
  // ---- fused delta: per-row sumsq (cols >= PP contribute exact zeros) ----
  float ss[2];
#pragma unroll
  for (int i = 0; i < 2; ++i) {
    float s = 0.f;
#pragma unroll
    for (int q = 0; q < 16; ++q) s = __fmaf_rn(acc[i][q], acc[i][q], s);
    ss[i] = s;
  }
#pragma unroll
  for (int off = 1; off <= 8; off <<= 1) {
#pragma unroll
    for (int i = 0; i < 2; ++i) ss[i] += __shfl_xor(ss[i], off);
  }
  if (tx == 0) {
    float sig = __expf(lsig);
#pragma unroll
    for (int i = 0; i < 2; ++i) {
      int r = r0 + ty * 2 + i;
      float delta = fmaxf(sig * (1.f + NUGF) - ss[i], NUGF);
      float di = 1.f / delta;
      Dinv[k * NN + r] = di;
      Dg[k * NN + r] = di * Mg[(size_t)k * NN + r];
    }
  }
}

// ---------------------------------------------------------------------------
// K5: R partials = Crh^T diag(Dinv) [Crh | g] over NCH K-chunks.
// 64x128 tiles; occupancy from NCH=16 (grid 8x16xKAP = 2048 = 8 blocks/CU).
template <int NCH>
__global__ __launch_bounds__(256) void syrk_kernel(const float* __restrict__ Crh,
                                                   const float* __restrict__ Dinv,
                                                   const float* __restrict__ M,
                                                   float* __restrict__ Rp) {
  const int CH = NN / NCH;
  int k = blockIdx.z, kch = blockIdx.y;
  int it = blockIdx.x >> 1, jc = blockIdx.x & 1;
  int i0 = it * 64, cb = jc * 128;
  const float* Ck = Crh + (size_t)k * NN * PP;
  float* Rk = Rp + (size_t)(k * NCH + kch) * PP * RST;
  __shared__ __align__(16) float Sc[16 * 64];
  __shared__ __align__(16) float Rw[16 * 128];
  int tid = threadIdx.x, tx = tid & 15, ty = tid >> 4;
  const int kk = ty;            // staging K-row (0..15)
  const int ii4 = tx * 4;       // quad offset
  int rbase0 = kch * CH;
  const float* pA = Ck + (size_t)(rbase0 + kk) * PP + i0 + ii4;
  const float* pB = Ck + (size_t)(rbase0 + kk) * PP + cb + ii4;
  const float* pD = Dinv + (size_t)k * NN + rbase0 + kk;
  const float* pM = M + (size_t)k * NN + rbase0 + kk;
  const bool aok = (i0 + ii4 + 3 < PP);
  const int cg0 = cb + ii4, cg1 = cb + ii4 + 64;
  const bool b0f = (cg0 + 3 < PP);
  const bool b1f = (cg1 + 3 < PP);
  float4 ra, rv0, rv1;
  float acc[4][8];
#pragma unroll
  for (int i = 0; i < 4; ++i)
#pragma unroll
    for (int q = 0; q < 8; ++q) acc[i][q] = 0.f;

  auto stage = [&](int rb) {
    bool rok = (rb + kk < CH);
    float d = rok ? *pD : 0.f;
    if (rok && aok) {
      float4 t = *(const float4*)pA;
      ra = make_float4(t.x * d, t.y * d, t.z * d, t.w * d);
    } else ra = make_float4(0.f, 0.f, 0.f, 0.f);
    if (rok) {
      rv0 = b0f ? *(const float4*)pB : make_float4(0.f, 0.f, 0.f, 0.f);
      if (b1f) rv1 = *(const float4*)(pB + 64);
      else {
        float e[4];
#pragma unroll
        for (int u = 0; u < 4; ++u) {
          int cg = cg1 + u;
          e[u] = (cg < PP) ? pB[64 + u] : ((cg == PP) ? *pM : 0.f);
        }
        rv1 = make_float4(e[0], e[1], e[2], e[3]);
      }
    } else { rv0 = make_float4(0.f, 0.f, 0.f, 0.f); rv1 = rv0; }
    pA += 16 * PP; pB += 16 * PP; pD += 16; pM += 16;
  };
  stage(0);
  for (int rb = 0; rb < CH; rb += 16) {
    __syncthreads();
    *(float4*)&Sc[kk * 64 + ii4] = ra;
    *(float4*)&Rw[kk * 128 + ii4] = rv0;
    *(float4*)&Rw[kk * 128 + ii4 + 64] = rv1;
    __syncthreads();
    stage(rb + 16);   // overlaps with compute below (guards -> 0 past end)
#pragma unroll
    for (int kq = 0; kq < 16; ++kq) {
      float4 a4 = *(const float4*)&Sc[kq * 64 + ty * 4];
      const float* bp = &Rw[kq * 128 + tx * 4];
      float bv[8];
      *(float4*)&bv[0] = *(const float4*)(bp);
      *(float4*)&bv[4] = *(const float4*)(bp + 64);
      float av[4] = {a4.x, a4.y, a4.z, a4.w};
#pragma unroll
      for (int i = 0; i < 4; ++i)
#pragma unroll
        for (int q = 0; q < 8; ++q)
          acc[i][q] = __fmaf_rn(av[i], bv[q], acc[i][q]);
    }
  }
#pragma unroll
  for (int i = 0; i < 4; ++i) {
    int r = i0 + ty * 4 + i;
    if (r < PP) {
#pragma unroll
      for (int q = 0; q < 2; ++q) {
        int c = cb + tx * 4 + 64 * q;
        if (c + 3 < PP) {
          float4 v = make_float4(acc[i][q * 4], acc[i][q * 4 + 1], acc[i][q * 4 + 2], acc[i][q * 4 + 3]);
          *(float4*)&Rk[r * RST + c] = v;
        } else if (c == PP) {
          Rk[r * RST + c] = acc[i][q * 4];   // v column
        }
      }
    }
  }
}

// K5b: R = I + sum partials -> Afull ; v = sum partials col 200 -> Vv
template <int NCH>
__global__ void reducer_kernel(const float* __restrict__ Rp, float* __restrict__ A,
                               float* __restrict__ Vv) {
  int k = blockIdx.y;
  int idx = blockIdx.x * 256 + threadIdx.x;
  if (idx < PP * PP) {
    int i = idx / PP, j = idx - i * PP;
    float s = (i == j) ? 1.0f : 0.0f;
    for (int ch = 0; ch < NCH; ++ch) s += Rp[(size_t)((k * NCH + ch) * PP + i) * RST + j];
    A[k * PP * PP + idx] = s;
  }
  if (idx < PP) {
    float sv = 0.f;
    for (int ch = 0; ch < NCH; ++ch) sv += Rp[(size_t)((k * NCH + ch) * PP + idx) * RST + PP];
    Vv[k * PP + idx] = sv;
  }
}

// ---------------------------------------------------------------------------
// K7: Cinv_g = Dg - Dinv * (Crh @ w)
__global__ void cg_kernel(const float* __restrict__ Crh, const float* __restrict__ w,
                          const float* __restrict__ Dinv, const float* __restrict__ Dg,
                          float* __restrict__ Cg) {
  int k = blockIdx.y;
  __shared__ float ws[PP];
  for (int i = threadIdx.x; i < PP; i += 256) ws[i] = w[k * PP + i];
  __syncthreads();
  int r = blockIdx.x * 4 + (threadIdx.x >> 6);
  int lane = threadIdx.x & 63;
  const float* row = Crh + (size_t)(k * NN + r) * PP;
  float s = 0.f;
  for (int c = lane; c < PP; c += 64) s = __fmaf_rn(row[c], ws[c], s);
#pragma unroll
  for (int off = 32; off > 0; off >>= 1) s += __shfl_xor(s, off, 64);
  if (lane == 0) Cg[k * NN + r] = Dg[k * NN + r] - Dinv[k * NN + r] * s;
}

// ---------------------------------------------------------------------------
// K8: ghat partials = cov(theta0, theta) @ Cinv_g, fused cov+matvec.
// 8 row-chunks of 500 -> grid 512 = 2 blocks/CU.
__global__ __launch_bounds__(256) void pred_kernel(const float* __restrict__ th0s,
                                                   const float* __restrict__ ths,
                                                   const float* __restrict__ Lmb,
                                                   const float* __restrict__ Cg,
                                                   float* __restrict__ Gp) {
  int k = blockIdx.z, rch = blockIdx.y, it = blockIdx.x;
  int i0 = it * 256 + threadIdx.x;
  const float* t0k = th0s + k * NN0 * DD;
  const float* thk = ths + k * NN * DD;
  const float* cgk = Cg + k * NN;
  __shared__ float tsl[64 * DD];
  __shared__ float cs[64];
  float t0r[DD];
  int i0c = (i0 < NN0) ? i0 : (NN0 - 1);
#pragma unroll
  for (int j = 0; j < DD; ++j) t0r[j] = t0k[i0c * DD + j];
  float lsig = Lmb[k * 9 + 8];
  float acc = 0.f;
  int rb0 = rch * 500;
  for (int rb = 0; rb < 500; rb += 64) {
    __syncthreads();
    for (int idx = threadIdx.x; idx < 64 * DD; idx += 256) {
      int a = rb0 + rb + (idx >> 3);
      if (a > NN - 1) a = NN - 1;
      tsl[idx] = thk[a * DD + (idx & 7)];
    }
    if (threadIdx.x < 64) {
      int rrr = rb + threadIdx.x;
      cs[threadIdx.x] = (rrr < 500) ? cgk[rb0 + rrr] : 0.f;
    }
    __syncthreads();
#pragma unroll 4
    for (int rr = 0; rr < 64; ++rr) {
      float prod = 1.f, sum = 0.f;
#pragma unroll
      for (int j = 0; j < DD; ++j) {
        float s = fabsf(t0r[j] - tsl[rr * DD + j]);
        prod = __fmaf_rn(prod, s, prod);
        sum += s;
      }
      acc = __fmaf_rn(prod * __expf(lsig - sum), cs[rr], acc);
    }
  }
  if (i0 < NN0) Gp[(k * 8 + rch) * 1024 + i0] = acc;
}

// K8b: reduce ghat partials
__global__ void gred_kernel(const float* __restrict__ Gp, float* __restrict__ ghat) {
  int idx = blockIdx.x * 256 + threadIdx.x;
  if (idx >= KAP * NN0) return;
  int k = idx / NN0, i0 = idx - k * NN0;
  float s = 0.f;
  for (int ch = 0; ch < 8; ++ch) s += Gp[(k * 8 + ch) * 1024 + i0];
  ghat[idx] = s;
}

// ---------------------------------------------------------------------------
// K9: fhat = (Phi @ ghat) * Fstd + Fmean
__global__ __launch_bounds__(256) void final_kernel(const float* __restrict__ Phi,
                                                    const float* __restrict__ ghat,
                                                    const float* __restrict__ Fmean,
                                                    const float* __restrict__ Fstd,
                                                    float* __restrict__ out) {
  int it = blockIdx.y, jt = blockIdx.x;
  int i0 = it * 64, j = jt * 256 + threadIdx.x;
  __shared__ float ph[64 * KAP];
  __shared__ float fm[64], fs[64];
  for (int idx = threadIdx.x; idx < 64 * KAP; idx += 256) {
    int i = idx >> 4, kk = idx & 15;
    int ii = i0 + i; if (ii > MMR - 1) ii = MMR - 1;
    ph[idx] = Phi[ii * KAP + kk];
  }
  if (threadIdx.x < 64) {
    int ii = i0 + threadIdx.x; if (ii > MMR - 1) ii = MMR - 1;
    fm[threadIdx.x] = Fmean[ii];
    fs[threadIdx.x] = Fstd[ii];
  }
  float gj[KAP];
#pragma unroll
  for (int kk = 0; kk < KAP; ++kk) gj[kk] = (j < NN0) ? ghat[kk * NN0 + j] : 0.f;
  __syncthreads();
  if (j < NN0) {
    for (int i = 0; i < 64; ++i) {
      int ii = i0 + i;
      if (ii >= MMR) break;
      float s = 0.f;
#pragma unroll
      for (int kk = 0; kk < KAP; ++kk) s = __fmaf_rn(ph[i * KAP + kk], gj[kk], s);
      out[(size_t)ii * NN0 + j] = __fmaf_rn(s, fs[i], fm[i]);
    }
  }
}

// ---------------------------------------------------------------------------
extern "C" void kernel_launch(void* const* d_in, const int* in_sizes, int n_in,
                              void* d_out, int out_size, void* d_ws, size_t ws_size,
                              hipStream_t stream) {
  const float* theta0 = (const float*)d_in[0];
  const float* Lmb    = (const float*)d_in[1];
  // d_in[2] = lsigma2 (unused by reference output)
  const float* Phi    = (const float*)d_in[3];
  const float* theta  = (const float*)d_in[4];
  const float* thetai = (const float*)d_in[5];
  const float* M      = (const float*)d_in[6];
  const float* Fmean  = (const float*)d_in[7];
  const float* Fstd   = (const float*)d_in[8];
  float* out = (float*)d_out;
  float* ws = (float*)d_ws;

  float* ths   = ws + OFF_THS;
  float* thi   = ws + OFF_THI;
  float* th0s  = ws + OFF_TH0S;
  float* Afull = ws + OFF_AFULL;
  float* LT    = ws + OFF_LT;
  float* Xt    = ws + OFF_XT;     // padded XT (stride XPS), in LROW+XB region
  float* dli   = ws + OFF_DLI;
  float* Crh   = ws + OFF_CRH;
  float* Dinv  = ws + OFF_DINV;
  float* Dg    = ws + OFF_DG;
  float* Vv    = ws + OFF_VV;
  float* Wv    = ws + OFF_WV;
  float* Cg    = ws + OFF_CG;
  float* Gpart = ws + OFF_GPART;
  float* ghat  = ws + OFF_GHAT;
  float* Rpart = ws + OFF_RPART;

  // choose syrk K-chunk count by available workspace (16 -> 8 blocks/CU grid)
  size_t need16 = ((size_t)OFF_RPART + (size_t)KAP * 16 * PP * RST) * sizeof(float);
  size_t need8  = ((size_t)OFF_RPART + (size_t)KAP * 8  * PP * RST) * sizeof(float);
  int nch = (ws_size >= need16) ? 16 : ((ws_size >= need8) ? 8 : 4);

  scale_kernel<<<dim3(163, KAP), 256, 0, stream>>>(theta, thetai, theta0, Lmb, ths, thi, th0s);
  buildci_kernel<<<KAP, 256, 0, stream>>>(thi, Lmb, Afull);
  chol_kernel<<<KAP, 1024, 0, stream>>>(Afull, LT, dli);
  linv_kernel<<<dim3(4, KAP), 256, 0, stream>>>(LT, dli, Xt);
  crh_kernel<<<dim3(125, KAP), 256, 0, stream>>>(ths, thi, Lmb, Xt, M, Crh, Dinv, Dg);
  if (nch == 16) {
    syrk_kernel<16><<<dim3(8, 16, KAP), 256, 0, stream>>>(Crh, Dinv, M, Rpart);
    reducer_kernel<16><<<dim3(157, KAP), 256, 0, stream>>>(Rpart, Afull, Vv);
  } else if (nch == 8) {
    syrk_kernel<8><<<dim3(8, 8, KAP), 256, 0, stream>>>(Crh, Dinv, M, Rpart);
    reducer_kernel<8><<<dim3(157, KAP), 256, 0, stream>>>(Rpart, Afull, Vv);
  } else {
    syrk_kernel<4><<<dim3(8, 4, KAP), 256, 0, stream>>>(Crh, Dinv, M, Rpart);
    reducer_kernel<4><<<dim3(157, KAP), 256, 0, stream>>>(Rpart, Afull, Vv);
  }
  chol_kernel<<<KAP, 1024, 0, stream>>>(Afull, LT, dli);        // Cholesky of R
  linv_kernel<<<dim3(4, KAP), 256, 0, stream>>>(LT, dli, Xt);   // X_R = L_R^{-1} (transposed/padded)
  rsolve_kernel<<<KAP, 256, 0, stream>>>(Xt, Vv, Wv);           // w = X^T X v
  cg_kernel<<<dim3(1000, KAP), 256, 0, stream>>>(Crh, Wv, Dinv, Dg, Cg);
  pred_kernel<<<dim3(4, 8, KAP), 256, 0, stream>>>(th0s, ths, Lmb, Cg, Gpart);
  gred_kernel<<<63, 256, 0, stream>>>(Gpart, ghat);
  final_kernel<<<dim3(4, 188), 256, 0, stream>>>(Phi, ghat, Fmean, Fstd, out);
}

// Round 9
// 784.169 us; speedup vs baseline: 1.0208x; 1.0208x over previous
//
#include <hip/hip_runtime.h>

// Problem constants (fixed by setup_inputs)
#define NN   4000
#define PP   200
#define DD   8
#define KAP  16
#define NN0  1000
#define MMR  12000
#define NUGF 1e-6f

// Rpart row stride (200 R cols + 1 v col + pad)
#define RST  204
// linv slab col stride
#define ACST 64
// chol: panel-transpose LDS row stride (floats), tile count of 50x50 lower tri
#define PTS   208
#define NTILE 1275
// crh Bt row stride
#define BTS  260
// XT padded row stride (cols 200..255 zeroed once -> async 64-lane loads safe)
#define XPS  256

// ---- workspace layout (float offsets); RPART last (variable size) ----
#define OFF_THS    0
#define OFF_THI    (OFF_THS   + KAP*NN*DD)
#define OFF_TH0S   (OFF_THI   + KAP*PP*DD)
#define OFF_AFULL  (OFF_TH0S  + KAP*NN0*DD)
#define OFF_LT     (OFF_AFULL + KAP*PP*PP)
#define OFF_LROW   (OFF_LT    + KAP*PP*PP)
#define OFF_XB     (OFF_LROW  + KAP*PP*PP)
#define OFF_DLI    (OFF_XB    + KAP*PP*PP)
#define OFF_CRH    (OFF_DLI   + KAP*PP)
#define OFF_DINV   (OFF_CRH   + KAP*NN*PP)
#define OFF_DG     (OFF_DINV  + KAP*NN)
#define OFF_VV     (OFF_DG    + KAP*NN)
#define OFF_WV     (OFF_VV    + KAP*PP)
#define OFF_CG     (OFF_WV    + KAP*PP)
#define OFF_GPART  (OFF_CG    + KAP*NN)
#define OFF_GHAT   (OFF_GPART + KAP*8*1024)
#define OFF_RPART  (OFF_GHAT  + KAP*NN0)
// XT (padded, KAP*PP*XPS = 819200 floats) lives in the LROW+XB region (1.28M floats)
#define OFF_XT     OFF_LROW
// need(NCH) = OFF_RPART + KAP*NCH*PP*RST floats

// async global->LDS, 16B per lane; LDS base must be wave-uniform
__device__ __forceinline__ void gld_lds16(const float* g, float* l) {
  __builtin_amdgcn_global_load_lds(
      (const __attribute__((address_space(1))) unsigned int*)g,
      (__attribute__((address_space(3))) unsigned int*)l, 16, 0, 0);
}

// ---------------------------------------------------------------------------
// K0: per-k scaled inputs  x / exp(lmb_j)
__global__ void scale_kernel(const float* __restrict__ theta, const float* __restrict__ thetai,
                             const float* __restrict__ theta0, const float* __restrict__ Lmb,
                             float* __restrict__ ths, float* __restrict__ thi, float* __restrict__ th0s) {
  int k = blockIdx.y;
  int idx = blockIdx.x * 256 + threadIdx.x;
  const int total = (NN + PP + NN0) * DD;
  if (idx >= total) return;
  int row = idx >> 3, j = idx & 7;
  float ils = __expf(-Lmb[k * 9 + j]);
  if (row < NN) {
    ths[(k * NN + row) * DD + j] = theta[row * DD + j] * ils;
  } else if (row < NN + PP) {
    int r = row - NN;
    thi[(k * PP + r) * DD + j] = thetai[r * DD + j] * ils;
  } else {
    int r = row - NN - PP;
    th0s[(k * NN0 + r) * DD + j] = theta0[r * DD + j] * ils;
  }
}

// ---------------------------------------------------------------------------
// K0b: build C_i (full symmetric) per k into Afull
__global__ void buildci_kernel(const float* __restrict__ thi, const float* __restrict__ Lmb,
                               float* __restrict__ A) {
  int k = blockIdx.x;
  __shared__ float ti[PP * DD];
  for (int i = threadIdx.x; i < PP * DD; i += 256) ti[i] = thi[k * PP * DD + i];
  __syncthreads();
  float lsig = Lmb[k * 9 + 8];
  float* Ak = A + k * PP * PP;
  for (int idx = threadIdx.x; idx < PP * PP; idx += 256) {
    int i = idx / PP, j = idx - i * PP;
    float prod = 1.f, sum = 0.f;
#pragma unroll
    for (int t = 0; t < DD; ++t) {
      float s = fabsf(ti[i * DD + t] - ti[j * DD + t]);
      prod = __fmaf_rn(prod, s, prod);  // prod *= (1+s)
      sum += s;
    }
    float val = prod * __expf(lsig - sum);
    if (i == j) val += NUGF * __expf(lsig);
    Ak[idx] = val;
  }
}

// ---------------------------------------------------------------------------
// K1/K6: Cholesky of a 200x200 SPD matrix, REGISTER-resident trailing matrix.
// amdgpu_waves_per_eu(4,4): PIN occupancy to 4 waves/EU -> 128-VGPR budget.
__device__ __forceinline__ float rdlane(float v, int l) {
  return __int_as_float(__builtin_amdgcn_readlane(__float_as_int(v), l));
}

__global__ __launch_bounds__(1024) __attribute__((amdgpu_waves_per_eu(4, 4)))
void chol_kernel(const float* __restrict__ Ain,
                 float* __restrict__ LT,
                 float* __restrict__ dli) {
  int k = blockIdx.x;
  Ain += (size_t)k * PP * PP; LT += (size_t)k * PP * PP; dli += (size_t)k * PP;
  __shared__ __align__(16) float Ppre[8 * PTS];  // staged panel, [q][r] absolute r
  __shared__ __align__(16) float Pt[8 * PTS];    // factorized panel, [q][r]
  const int tid = threadIdx.x;

  // ---- decode owned tiles (row-tile-major lower triangle), load to regs ----
  int t_rt[2], t_ct[2];
  bool t_ok[2];
  float4 acc[2][4];
#pragma unroll
  for (int t = 0; t < 2; ++t) {
    int ti = (tid - 64) + t * 960;
    t_ok[t] = (tid >= 64) && (ti < NTILE);
    int tie = t_ok[t] ? ti : 0;
    int rt = (int)((sqrtf(8.0f * (float)tie + 1.0f) - 1.0f) * 0.5f);
    while ((rt + 1) * (rt + 2) / 2 <= tie) ++rt;
    while (rt * (rt + 1) / 2 > tie) --rt;
    int ct = tie - rt * (rt + 1) / 2;
    t_rt[t] = rt; t_ct[t] = ct;
    if (t_ok[t]) {
      const float* src = Ain + (size_t)(4 * rt) * PP + 4 * ct;
#pragma unroll
      for (int i = 0; i < 4; ++i) acc[t][i] = *(const float4*)(src + (size_t)i * PP);
    } else {
#pragma unroll
      for (int i = 0; i < 4; ++i) acc[t][i] = make_float4(0.f, 0.f, 0.f, 0.f);
    }
  }

  float preg[4][8];  // wave-0 panel registers (live across the barrier)
  for (int s = 0; s < 25; ++s) {
    const int jb = 8 * s;
    // ---- owners of the two panel tile-columns stage them to LDS ----
#pragma unroll
    for (int t = 0; t < 2; ++t) {
      if (t_ok[t] && (t_ct[t] >> 1) == s) {
        int q0 = 4 * t_ct[t] - jb;   // 0 or 4
        int r0 = 4 * t_rt[t];
#pragma unroll
        for (int i = 0; i < 4; ++i) {
          Ppre[(q0 + 0) * PTS + r0 + i] = acc[t][i].x;
          Ppre[(q0 + 1) * PTS + r0 + i] = acc[t][i].y;
          Ppre[(q0 + 2) * PTS + r0 + i] = acc[t][i].z;
          Ppre[(q0 + 3) * PTS + r0 + i] = acc[t][i].w;
        }
      }
    }
    __syncthreads();
    const int nrows = PP - jb;
    // ---- wave 0: panel factorization in registers, readlane chain ----
    if (tid < 64) {
      const int L = tid;
#pragma unroll
      for (int u = 0; u < 4; ++u) {
        int rl = L + 64 * u;
#pragma unroll
        for (int c = 0; c < 8; ++c)
          preg[u][c] = (rl < nrows && rl >= c) ? Ppre[c * PTS + jb + rl] : 0.f;
      }
#pragma unroll
      for (int jj = 0; jj < 8; ++jj) {
        float dv = rdlane(preg[0][jj], jj);
        float l = sqrtf(fmaxf(dv, 1e-12f));
        float inv = 1.0f / l;
#pragma unroll
        for (int u = 0; u < 4; ++u)
          if (u > 0 || L > jj) preg[u][jj] *= inv;
        if (L == jj) { preg[0][jj] = l; dli[jb + jj] = inv; }
#pragma unroll
        for (int c = 0; c < 8; ++c) {
          if (c > jj) {
            float pc = rdlane(preg[0][jj], c);
#pragma unroll
            for (int u = 0; u < 4; ++u)
              preg[u][c] = __fmaf_rn(-preg[u][jj], pc, preg[u][c]);
          }
        }
      }
#pragma unroll
      for (int u = 0; u < 4; ++u) {
        int rl = L + 64 * u;
        if (rl < nrows) {
#pragma unroll
          for (int c = 0; c < 8; ++c) Pt[c * PTS + jb + rl] = preg[u][c];
        }
      }
    }
    __syncthreads();
    // ---- wave 0: LT global writes off the critical path (drain overlaps) ----
    if (tid < 64) {
      const int L = tid;
#pragma unroll
      for (int u = 0; u < 4; ++u) {
        int rl = L + 64 * u;
        if (rl < nrows) {
#pragma unroll
          for (int c = 0; c < 8; ++c)
            if (rl >= c) LT[(jb + c) * PP + jb + rl] = preg[u][c];
        }
      }
    }
    // ---- rank-8 trailing update on register tiles ----
    const int ctmin = 2 * s + 2;
#pragma unroll
    for (int t = 0; t < 2; ++t) {
      if (t_ok[t] && t_ct[t] >= ctmin) {
        const float* pr = Pt + 4 * t_rt[t];
        const float* pcl = Pt + 4 * t_ct[t];
#pragma unroll
        for (int q = 0; q < 8; ++q) {
          float4 a = *(const float4*)(pr + q * PTS);   // broadcast within wave
          float4 b = *(const float4*)(pcl + q * PTS);  // consecutive float4s
          acc[t][0].x = __fmaf_rn(-a.x, b.x, acc[t][0].x);
          acc[t][0].y = __fmaf_rn(-a.x, b.y, acc[t][0].y);
          acc[t][0].z = __fmaf_rn(-a.x, b.z, acc[t][0].z);
          acc[t][0].w = __fmaf_rn(-a.x, b.w, acc[t][0].w);
          acc[t][1].x = __fmaf_rn(-a.y, b.x, acc[t][1].x);
          acc[t][1].y = __fmaf_rn(-a.y, b.y, acc[t][1].y);
          acc[t][1].z = __fmaf_rn(-a.y, b.z, acc[t][1].z);
          acc[t][1].w = __fmaf_rn(-a.y, b.w, acc[t][1].w);
          acc[t][2].x = __fmaf_rn(-a.z, b.x, acc[t][2].x);
          acc[t][2].y = __fmaf_rn(-a.z, b.y, acc[t][2].y);
          acc[t][2].z = __fmaf_rn(-a.z, b.z, acc[t][2].z);
          acc[t][2].w = __fmaf_rn(-a.z, b.w, acc[t][2].w);
          acc[t][3].x = __fmaf_rn(-a.w, b.x, acc[t][3].x);
          acc[t][3].y = __fmaf_rn(-a.w, b.y, acc[t][3].y);
          acc[t][3].z = __fmaf_rn(-a.w, b.z, acc[t][3].z);
          acc[t][3].w = __fmaf_rn(-a.w, b.w, acc[t][3].w);
        }
      }
    }
  }
}

// ---------------------------------------------------------------------------
// K2: X = L^{-1}, column-parallel forward substitution. grid (4, KAP).
// Output stored TRANSPOSED + PADDED: XT[c*XPS + t] = X[t][c]; cols t=200..255
// zeroed once (allows unconditional 64-lane global_load_lds in crh).
__global__ __launch_bounds__(256) void linv_kernel(const float* __restrict__ LT,
                                                   const float* __restrict__ dli_g,
                                                   float* __restrict__ XT) {
  int cb = blockIdx.x, k = blockIdx.y;
  LT += (size_t)k * PP * PP; dli_g += k * PP; XT += (size_t)k * PP * XPS;
  __shared__ float acc[PP * ACST];   // 51.2 KB slab: acc[r][i]
  __shared__ float Pn[8 * PP];       // panel: Pn[q][r] = LT[t0+q][r] = L[r][t0+q]
  __shared__ float xf[8 * ACST];
  __shared__ float dl[PP];
  const int tid = threadIdx.x;
  const int i = tid & 63, rg = tid >> 6;
  const int c = cb + 4 * i;          // owned column (valid if c < PP)
  for (int idx = tid; idx < PP * ACST; idx += 256) acc[idx] = 0.f;
  for (int r = tid; r < PP; r += 256) dl[r] = dli_g[r];
  // zero the padded tail (cols 200..255 of each owned row), once
  {
    float4 z4 = make_float4(0.f, 0.f, 0.f, 0.f);
    for (int idx = tid; idx < 50 * 14; idx += 256) {
      int il = idx / 14, f4 = idx - il * 14;
      int c2 = cb + 4 * il;   // < 200 by construction
      *(float4*)&XT[(size_t)c2 * XPS + 200 + 4 * f4] = z4;
    }
  }
  __syncthreads();
  for (int s = 0; s < 25; ++s) {
    const int t0 = 8 * s;
    for (int idx = tid; idx < 8 * PP; idx += 256) Pn[idx] = LT[t0 * PP + idx];
    __syncthreads();
    if (rg == 0) {
      float xq[8];
#pragma unroll
      for (int q = 0; q < 8; ++q) {
        int t = t0 + q;
        float sv = acc[t * ACST + i];
#pragma unroll
        for (int m = 0; m < 8; ++m)
          if (m < q) sv = __fmaf_rn(Pn[m * PP + t], xq[m], sv);
        float xv = (((t == c) ? 1.0f : 0.0f) - sv) * dl[t];
        xq[q] = xv;
        xf[q * ACST + i] = xv;
      }
    }
    __syncthreads();
    // XT store: float4 along t (t0+4*q4 .. +3) for owned columns
    if (tid < 128) {
      int q4 = tid >> 6, il = tid & 63;
      int c2 = cb + 4 * il;
      if (c2 < PP) {
        float4 v4 = make_float4(xf[(q4 * 4 + 0) * ACST + il], xf[(q4 * 4 + 1) * ACST + il],
                                xf[(q4 * 4 + 2) * ACST + il], xf[(q4 * 4 + 3) * ACST + il]);
        *(float4*)&XT[(size_t)c2 * XPS + t0 + 4 * q4] = v4;
      }
    }
    for (int r = t0 + 8 + rg; r < PP; r += 4) {
      float v = acc[r * ACST + i];
#pragma unroll
      for (int q = 0; q < 8; ++q)
        v = __fmaf_rn(Pn[q * PP + r], xf[q * ACST + i], v);
      acc[r * ACST + i] = v;
    }
    __syncthreads();
  }
}

// ---------------------------------------------------------------------------
// K6b: w = R^{-1} v = X^T (X v). X stored transposed/padded (XT[c*XPS+t]);
// summation ORDER identical (bit-identical w).
__global__ __launch_bounds__(256) void rsolve_kernel(const float* __restrict__ XT,
                                                     const float* __restrict__ v,
                                                     float* __restrict__ w) {
  int k = blockIdx.x;
  XT += (size_t)k * PP * XPS; v += k * PP; w += k * PP;
  __shared__ float vl[PP], yl[PP];
  int tid = threadIdx.x, lane = tid & 63, rg = tid >> 6;
  for (int i = tid; i < PP; i += 256) vl[i] = v[i];
  __syncthreads();
  // y = X v ; X[r][c] = XT[c*XPS+r]
  for (int r = rg; r < PP; r += 4) {
    float s = 0.f;
    for (int c = lane; c < PP; c += 64) s = __fmaf_rn(XT[(size_t)c * XPS + r], vl[c], s);
#pragma unroll
    for (int off = 32; off > 0; off >>= 1) s += __shfl_xor(s, off, 64);
    if (lane == 0) yl[r] = s;
  }
  __syncthreads();
  // w = X^T y ; X[r][tid] = XT[tid*XPS+r]
  if (tid < PP) {
    float s = 0.f;
    for (int r = 0; r < PP; ++r) s = __fmaf_rn(XT[(size_t)tid * XPS + r], yl[r], s);
    w[tid] = s;
  }
}

// ---------------------------------------------------------------------------
// K3: Crh = c_fi @ Linv^T, async B-staging; 32-row tiles (grid 125 x KAP
// = 2000 blocks; 6 blocks/CU). Round-7 form: SINGLE-buffered Bt — at 6
// blocks/CU the cross-block TLP already hides the per-step load latency;
// round-8's double-buffer (43KB LDS -> 3 blocks/CU) REGRESSED 120->130us.
// Bit-identical accumulation.
__global__ __launch_bounds__(256) void crh_kernel(const float* __restrict__ ths,
                                                  const float* __restrict__ thi,
                                                  const float* __restrict__ Lmb,
                                                  const float* __restrict__ XT,
                                                  const float* __restrict__ Mg,
                                                  float* __restrict__ Crh,
                                                  float* __restrict__ Dinv,
                                                  float* __restrict__ Dg) {
  int k = blockIdx.y, rt = blockIdx.x, r0 = rt * 32;
  const float* thk = ths + k * NN * DD;
  const float* XTk = XT + (size_t)k * PP * XPS;
  float* Ck = Crh + (size_t)k * NN * PP;
  __shared__ __align__(16) float ts[32 * 9];
  __shared__ __align__(16) float til[PP * DD];   // inducing pts, staged once
  __shared__ __align__(16) float At[16 * 32];
  __shared__ __align__(16) float Bt[16 * BTS];
  int tid = threadIdx.x, tx = tid & 15, ty = tid >> 4;
  const int lr = tid & 63;   // lane in wave
  const int wq = tid >> 6;   // wave id 0..3
  float lsig = Lmb[k * 9 + 8];
  {
    int r = tid >> 3, j = tid & 7;   // tid < 256 = 32*8 exactly
    ts[r * 9 + j] = thk[(r0 + r) * DD + j];
  }
  for (int idx = tid; idx < PP * DD; idx += 256) til[idx] = thi[k * PP * DD + idx];
  float acc[2][16];
#pragma unroll
  for (int i = 0; i < 2; ++i)
#pragma unroll
    for (int q = 0; q < 16; ++q) acc[i][q] = 0.f;

  for (int jb = 0; jb < PP; jb += 16) {
    __syncthreads();   // prior FMA readers done; ts/til visible at jb=0
    // ---- issue async B loads: Bt[kk][lane*4..+3] <- XT[(jb+kk)*XPS + lane*4]
#pragma unroll
    for (int u = 0; u < 4; ++u) {
      int kk = wq + 4 * u;           // wave-uniform
      int row = jb + kk;
      if (row < PP)                  // wave-uniform guard
        gld_lds16(XTk + (size_t)row * XPS + lr * 4, &Bt[kk * BTS]);
      // rows >= PP keep stale data; At[kk]=0 there -> contributes exact 0
    }
    // ---- cov -> At (LDS-only; overlaps the in-flight loads) ----
    for (int idx = tid; idx < 16 * 32; idx += 256) {
      int r = idx & 31, kk = idx >> 5;
      float va = 0.f;
      int kkg = jb + kk;
      if (kkg < PP) {
        float prod = 1.f, sum = 0.f;
#pragma unroll
        for (int t = 0; t < DD; ++t) {
          float s = fabsf(ts[r * 9 + t] - til[kkg * DD + t]);
          prod = __fmaf_rn(prod, s, prod);
          sum += s;
        }
        va = prod * __expf(lsig - sum);
      }
      At[kk * 32 + r] = va;
    }
    __syncthreads();   // drains vmcnt(0): Bt ready
#pragma unroll
    for (int kk = 0; kk < 16; ++kk) {
      float2 a2 = *(const float2*)&At[kk * 32 + ty * 2];
      const float* bp = &Bt[kk * BTS + tx * 4];
      float bv[16];
      *(float4*)&bv[0]  = *(const float4*)(bp);
      *(float4*)&bv[4]  = *(const float4*)(bp + 64);
      *(float4*)&bv[8]  = *(const float4*)(bp + 128);
      *(float4*)&bv[12] = *(const float4*)(bp + 192);
      float av[2] = {a2.x, a2.y};
#pragma unroll
      for (int i = 0; i < 2; ++i)
#pragma unroll
        for (int q = 0; q < 16; ++q)
          acc[i][q] = __fmaf_rn(av[i], bv[q], acc[i][q]);
    }
  }
  // store: thread cols c = tx*4 + 64q (all multiples of 4; c<PP => full float4 valid)
#pragma unroll
  for (int i = 0; i < 2; ++i) {
    int r = r0 + ty * 2 + i;   // < 4000 always
#pragma unroll
    for (int q = 0; q < 4; ++q) {
      int c = tx * 4 + 64 * q;
      if (c < PP) {
        float4 v = make_float4(acc[i][q * 4], acc[i][q * 4 + 1], acc[i][q * 4 + 2], acc[i][q * 4 + 3]);
        *(float4*)&Ck[r * PP + c] = v;
      }
    }
  }
  // ---- fused delta: per-row sumsq (cols >= PP contribute exact zeros) ----
  float ss[2];
#pragma unroll
  for (int i = 0; i < 2; ++i) {
    float s = 0.f;
#pragma unroll
    for (int q = 0; q < 16; ++q) s = __fmaf_rn(acc[i][q], acc[i][q], s);
    ss[i] = s;
  }
#pragma unroll
  for (int off = 1; off <= 8; off <<= 1) {
#pragma unroll
    for (int i = 0; i < 2; ++i) ss[i] += __shfl_xor(ss[i], off);
  }
  if (tx == 0) {
    float sig = __expf(lsig);
#pragma unroll
    for (int i = 0; i < 2; ++i) {
      int r = r0 + ty * 2 + i;
      float delta = fmaxf(sig * (1.f + NUGF) - ss[i], NUGF);
      float di = 1.f / delta;
      Dinv[k * NN + r] = di;
      Dg[k * NN + r] = di * Mg[(size_t)k * NN + r];
    }
  }
}

// ---------------------------------------------------------------------------
// K5: R partials = Crh^T diag(Dinv) [Crh | g] over NCH K-chunks.
// 64x128 tiles; occupancy from NCH=16 (2048 blocks = 8 blocks/CU).
// v3: XCD-GROUPING remap — the 8 tiles of a (k,kch) group read the SAME
// 250-row Crh chunk; default round-robin puts them on 8 DIFFERENT XCDs so
// every per-XCD L2 refetches the chunk (FETCH 156MB vs 51MB unique). Remap
// so all 8 group-tiles have linear ids == r (mod 8) -> same XCD -> chunk
// (200KB << 4MB L2) fetched once. Pure bijective index remap; every tile
// computes bit-identical values. Load stays balanced (32 grp x 8 tiles per
// XCD's 32 CUs).
template <int NCH>
__global__ __launch_bounds__(256) void syrk_kernel(const float* __restrict__ Crh,
                                                   const float* __restrict__ Dinv,
                                                   const float* __restrict__ M,
                                                   float* __restrict__ Rp) {
  const int CH = NN / NCH;
  const int GRP_PER_XCD = (NCH * KAP) / 8;
  int lin = blockIdx.x + 8 * (blockIdx.y + NCH * blockIdx.z);
  int xcd = lin & 7, q = lin >> 3;
  int grp = xcd * GRP_PER_XCD + (q >> 3);
  int tile = q & 7;
  int k = grp / NCH, kch = grp - k * NCH;
  int it = tile >> 1, jc = tile & 1;
  int i0 = it * 64, cb = jc * 128;
  const float* Ck = Crh + (size_t)k * NN * PP;
  float* Rk = Rp + (size_t)(k * NCH + kch) * PP * RST;
  __shared__ __align__(16) float Sc[16 * 64];
  __shared__ __align__(16) float Rw[16 * 128];
  int tid = threadIdx.x, tx = tid & 15, ty = tid >> 4;
  const int kk = ty;            // staging K-row (0..15)
  const int ii4 = tx * 4;       // quad offset
  int rbase0 = kch * CH;
  const float* pA = Ck + (size_t)(rbase0 + kk) * PP + i0 + ii4;
  const float* pB = Ck + (size_t)(rbase0 + kk) * PP + cb + ii4;
  const float* pD = Dinv + (size_t)k * NN + rbase0 + kk;
  const float* pM = M + (size_t)k * NN + rbase0 + kk;
  const bool aok = (i0 + ii4 + 3 < PP);
  const int cg0 = cb + ii4, cg1 = cb + ii4 + 64;
  const bool b0f = (cg0 + 3 < PP);
  const bool b1f = (cg1 + 3 < PP);
  float4 ra, rv0, rv1;
  float acc[4][8];
#pragma unroll
  for (int i = 0; i < 4; ++i)
#pragma unroll
    for (int q2 = 0; q2 < 8; ++q2) acc[i][q2] = 0.f;

  auto stage = [&](int rb) {
    bool rok = (rb + kk < CH);
    float d = rok ? *pD : 0.f;
    if (rok && aok) {
      float4 t = *(const float4*)pA;
      ra = make_float4(t.x * d, t.y * d, t.z * d, t.w * d);
    } else ra = make_float4(0.f, 0.f, 0.f, 0.f);
    if (rok) {
      rv0 = b0f ? *(const float4*)pB : make_float4(0.f, 0.f, 0.f, 0.f);
      if (b1f) rv1 = *(const float4*)(pB + 64);
      else {
        float e[4];
#pragma unroll
        for (int u = 0; u < 4; ++u) {
          int cg = cg1 + u;
          e[u] = (cg < PP) ? pB[64 + u] : ((cg == PP) ? *pM : 0.f);
        }
        rv1 = make_float4(e[0], e[1], e[2], e[3]);
      }
    } else { rv0 = make_float4(0.f, 0.f, 0.f, 0.f); rv1 = rv0; }
    pA += 16 * PP; pB += 16 * PP; pD += 16; pM += 16;
  };
  stage(0);
  for (int rb = 0; rb < CH; rb += 16) {
    __syncthreads();
    *(float4*)&Sc[kk * 64 + ii4] = ra;
    *(float4*)&Rw[kk * 128 + ii4] = rv0;
    *(float4*)&Rw[kk * 128 + ii4 + 64] = rv1;
    __syncthreads();
    stage(rb + 16);   // overlaps with compute below (guards -> 0 past end)
#pragma unroll
    for (int kq = 0; kq < 16; ++kq) {
      float4 a4 = *(const float4*)&Sc[kq * 64 + ty * 4];
      const float* bp = &Rw[kq * 128 + tx * 4];
      float bv[8];
      *(float4*)&bv[0] = *(const float4*)(bp);
      *(float4*)&bv[4] = *(const float4*)(bp + 64);
      float av[4] = {a4.x, a4.y, a4.z, a4.w};
#pragma unroll
      for (int i = 0; i < 4; ++i)
#pragma unroll
        for (int q2 = 0; q2 < 8; ++q2)
          acc[i][q2] = __fmaf_rn(av[i], bv[q2], acc[i][q2]);
    }
  }
#pragma unroll
  for (int i = 0; i < 4; ++i) {
    int r = i0 + ty * 4 + i;
    if (r < PP) {
#pragma unroll
      for (int q2 = 0; q2 < 2; ++q2) {
        int c = cb + tx * 4 + 64 * q2;
        if (c + 3 < PP) {
          float4 v = make_float4(acc[i][q2 * 4], acc[i][q2 * 4 + 1], acc[i][q2 * 4 + 2], acc[i][q2 * 4 + 3]);
          *(float4*)&Rk[r * RST + c] = v;
        } else if (c == PP) {
          Rk[r * RST + c] = acc[i][q2 * 4];   // v column
        }
      }
    }
  }
}

// K5b: R = I + sum partials -> Afull ; v = sum partials col 200 -> Vv
template <int NCH>
__global__ void reducer_kernel(const float* __restrict__ Rp, float* __restrict__ A,
                               float* __restrict__ Vv) {
  int k = blockIdx.y;
  int idx = blockIdx.x * 256 + threadIdx.x;
  if (idx < PP * PP) {
    int i = idx / PP, j = idx - i * PP;
    float s = (i == j) ? 1.0f : 0.0f;
    for (int ch = 0; ch < NCH; ++ch) s += Rp[(size_t)((k * NCH + ch) * PP + i) * RST + j];
    A[k * PP * PP + idx] = s;
  }
  if (idx < PP) {
    float sv = 0.f;
    for (int ch = 0; ch < NCH; ++ch) sv += Rp[(size_t)((k * NCH + ch) * PP + idx) * RST + PP];
    Vv[k * PP + idx] = sv;
  }
}

// ---------------------------------------------------------------------------
// K7: Cinv_g = Dg - Dinv * (Crh @ w)
__global__ void cg_kernel(const float* __restrict__ Crh, const float* __restrict__ w,
                          const float* __restrict__ Dinv, const float* __restrict__ Dg,
                          float* __restrict__ Cg) {
  int k = blockIdx.y;
  __shared__ float ws[PP];
  for (int i = threadIdx.x; i < PP; i += 256) ws[i] = w[k * PP + i];
  __syncthreads();
  int r = blockIdx.x * 4 + (threadIdx.x >> 6);
  int lane = threadIdx.x & 63;
  const float* row = Crh + (size_t)(k * NN + r) * PP;
  float s = 0.f;
  for (int c = lane; c < PP; c += 64) s = __fmaf_rn(row[c], ws[c], s);
#pragma unroll
  for (int off = 32; off > 0; off >>= 1) s += __shfl_xor(s, off, 64);
  if (lane == 0) Cg[k * NN + r] = Dg[k * NN + r] - Dinv[k * NN + r] * s;
}

// ---------------------------------------------------------------------------
// K8: ghat partials = cov(theta0, theta) @ Cinv_g, fused cov+matvec.
// 8 row-chunks of 500 -> grid 512 = 2 blocks/CU.
__global__ __launch_bounds__(256) void pred_kernel(const float* __restrict__ th0s,
                                                   const float* __restrict__ ths,
                                                   const float* __restrict__ Lmb,
                                                   const float* __restrict__ Cg,
                                                   float* __restrict__ Gp) {
  int k = blockIdx.z, rch = blockIdx.y, it = blockIdx.x;
  int i0 = it * 256 + threadIdx.x;
  const float* t0k = th0s + k * NN0 * DD;
  const float* thk = ths + k * NN * DD;
  const float* cgk = Cg + k * NN;
  __shared__ float tsl[64 * DD];
  __shared__ float cs[64];
  float t0r[DD];
  int i0c = (i0 < NN0) ? i0 : (NN0 - 1);
#pragma unroll
  for (int j = 0; j < DD; ++j) t0r[j] = t0k[i0c * DD + j];
  float lsig = Lmb[k * 9 + 8];
  float acc = 0.f;
  int rb0 = rch * 500;
  for (int rb = 0; rb < 500; rb += 64) {
    __syncthreads();
    for (int idx = threadIdx.x; idx < 64 * DD; idx += 256) {
      int a = rb0 + rb + (idx >> 3);
      if (a > NN - 1) a = NN - 1;
      tsl[idx] = thk[a * DD + (idx & 7)];
    }
    if (threadIdx.x < 64) {
      int rrr = rb + threadIdx.x;
      cs[threadIdx.x] = (rrr < 500) ? cgk[rb0 + rrr] : 0.f;
    }
    __syncthreads();
#pragma unroll 4
    for (int rr = 0; rr < 64; ++rr) {
      float prod = 1.f, sum = 0.f;
#pragma unroll
      for (int j = 0; j < DD; ++j) {
        float s = fabsf(t0r[j] - tsl[rr * DD + j]);
        prod = __fmaf_rn(prod, s, prod);
        sum += s;
      }
      acc = __fmaf_rn(prod * __expf(lsig - sum), cs[rr], acc);
    }
  }
  if (i0 < NN0) Gp[(k * 8 + rch) * 1024 + i0] = acc;
}

// K8b: reduce ghat partials
__global__ void gred_kernel(const float* __restrict__ Gp, float* __restrict__ ghat) {
  int idx = blockIdx.x * 256 + threadIdx.x;
  if (idx >= KAP * NN0) return;
  int k = idx / NN0, i0 = idx - k * NN0;
  float s = 0.f;
  for (int ch = 0; ch < 8; ++ch) s += Gp[(k * 8 + ch) * 1024 + i0];
  ghat[idx] = s;
}

// ---------------------------------------------------------------------------
// K9: fhat = (Phi @ ghat) * Fstd + Fmean
__global__ __launch_bounds__(256) void final_kernel(const float* __restrict__ Phi,
                                                    const float* __restrict__ ghat,
                                                    const float* __restrict__ Fmean,
                                                    const float* __restrict__ Fstd,
                                                    float* __restrict__ out) {
  int it = blockIdx.y, jt = blockIdx.x;
  int i0 = it * 64, j = jt * 256 + threadIdx.x;
  __shared__ float ph[64 * KAP];
  __shared__ float fm[64], fs[64];
  for (int idx = threadIdx.x; idx < 64 * KAP; idx += 256) {
    int i = idx >> 4, kk = idx & 15;
    int ii = i0 + i; if (ii > MMR - 1) ii = MMR - 1;
    ph[idx] = Phi[ii * KAP + kk];
  }
  if (threadIdx.x < 64) {
    int ii = i0 + threadIdx.x; if (ii > MMR - 1) ii = MMR - 1;
    fm[threadIdx.x] = Fmean[ii];
    fs[threadIdx.x] = Fstd[ii];
  }
  float gj[KAP];
#pragma unroll
  for (int kk = 0; kk < KAP; ++kk) gj[kk] = (j < NN0) ? ghat[kk * NN0 + j] : 0.f;
  __syncthreads();
  if (j < NN0) {
    for (int i = 0; i < 64; ++i) {
      int ii = i0 + i;
      if (ii >= MMR) break;
      float s = 0.f;
#pragma unroll
      for (int kk = 0; kk < KAP; ++kk) s = __fmaf_rn(ph[i * KAP + kk], gj[kk], s);
      out[(size_t)ii * NN0 + j] = __fmaf_rn(s, fs[i], fm[i]);
    }
  }
}

// ---------------------------------------------------------------------------
extern "C" void kernel_launch(void* const* d_in, const int* in_sizes, int n_in,
                              void* d_out, int out_size, void* d_ws, size_t ws_size,
                              hipStream_t stream) {
  const float* theta0 = (const float*)d_in[0];
  const float* Lmb    = (const float*)d_in[1];
  // d_in[2] = lsigma2 (unused by reference output)
  const float* Phi    = (const float*)d_in[3];
  const float* theta  = (const float*)d_in[4];
  const float* thetai = (const float*)d_in[5];
  const float* M      = (const float*)d_in[6];
  const float* Fmean  = (const float*)d_in[7];
  const float* Fstd   = (const float*)d_in[8];
  float* out = (float*)d_out;
  float* ws = (float*)d_ws;

  float* ths   = ws + OFF_THS;
  float* thi   = ws + OFF_THI;
  float* th0s  = ws + OFF_TH0S;
  float* Afull = ws + OFF_AFULL;
  float* LT    = ws + OFF_LT;
  float* Xt    = ws + OFF_XT;     // padded XT (stride XPS), in LROW+XB region
  float* dli   = ws + OFF_DLI;
  float* Crh   = ws + OFF_CRH;
  float* Dinv  = ws + OFF_DINV;
  float* Dg    = ws + OFF_DG;
  float* Vv    = ws + OFF_VV;
  float* Wv    = ws + OFF_WV;
  float* Cg    = ws + OFF_CG;
  float* Gpart = ws + OFF_GPART;
  float* ghat  = ws + OFF_GHAT;
  float* Rpart = ws + OFF_RPART;

  // choose syrk K-chunk count by available workspace (16 -> 8 blocks/CU grid)
  size_t need16 = ((size_t)OFF_RPART + (size_t)KAP * 16 * PP * RST) * sizeof(float);
  size_t need8  = ((size_t)OFF_RPART + (size_t)KAP * 8  * PP * RST) * sizeof(float);
  int nch = (ws_size >= need16) ? 16 : ((ws_size >= need8) ? 8 : 4);

  scale_kernel<<<dim3(163, KAP), 256, 0, stream>>>(theta, thetai, theta0, Lmb, ths, thi, th0s);
  buildci_kernel<<<KAP, 256, 0, stream>>>(thi, Lmb, Afull);
  chol_kernel<<<KAP, 1024, 0, stream>>>(Afull, LT, dli);
  linv_kernel<<<dim3(4, KAP), 256, 0, stream>>>(LT, dli, Xt);
  crh_kernel<<<dim3(125, KAP), 256, 0, stream>>>(ths, thi, Lmb, Xt, M, Crh, Dinv, Dg);
  if (nch == 16) {
    syrk_kernel<16><<<dim3(8, 16, KAP), 256, 0, stream>>>(Crh, Dinv, M, Rpart);
    reducer_kernel<16><<<dim3(157, KAP), 256, 0, stream>>>(Rpart, Afull, Vv);
  } else if (nch == 8) {
    syrk_kernel<8><<<dim3(8, 8, KAP), 256, 0, stream>>>(Crh, Dinv, M, Rpart);
    reducer_kernel<8><<<dim3(157, KAP), 256, 0, stream>>>(Rpart, Afull, Vv);
  } else {
    syrk_kernel<4><<<dim3(8, 4, KAP), 256, 0, stream>>>(Crh, Dinv, M, Rpart);
    reducer_kernel<4><<<dim3(157, KAP), 256, 0, stream>>>(Rpart, Afull, Vv);
  }
  chol_kernel<<<KAP, 1024, 0, stream>>>(Afull, LT, dli);        // Cholesky of R
  linv_kernel<<<dim3(4, KAP), 256, 0, stream>>>(LT, dli, Xt);   // X_R = L_R^{-1} (transposed/padded)
  rsolve_kernel<<<KAP, 256, 0, stream>>>(Xt, Vv, Wv);           // w = X^T X v
  cg_kernel<<<dim3(1000, KAP), 256, 0, stream>>>(Crh, Wv, Dinv, Dg, Cg);
  pred_kernel<<<dim3(4, 8, KAP), 256, 0, stream>>>(th0s, ths, Lmb, Cg, Gpart);
  gred_kernel<<<63, 256, 0, stream>>>(Gpart, ghat);
  final_kernel<<<dim3(4, 188), 256, 0, stream>>>(Phi, ghat, Fmean, Fstd, out);
}

// Round 10
// 774.548 us; speedup vs baseline: 1.0335x; 1.0124x over previous
//
#include <hip/hip_runtime.h>

// Problem constants (fixed by setup_inputs)
#define NN   4000
#define PP   200
#define DD   8
#define KAP  16
#define NN0  1000
#define MMR  12000
#define NUGF 1e-6f

// Rpart row stride (200 R cols + 1 v col + pad)
#define RST  204
// linv slab col stride
#define ACST 64
// chol: panel-transpose LDS row stride (floats), tile count of 50x50 lower tri
#define PTS   208
#define NTILE 1275
// crh Bt row stride
#define BTS  260
// XT padded row stride (cols 200..255 zeroed once -> async 64-lane loads safe)
#define XPS  256

// ---- workspace layout (float offsets); RPART last (variable size) ----
#define OFF_THS    0
#define OFF_THI    (OFF_THS   + KAP*NN*DD)
#define OFF_TH0S   (OFF_THI   + KAP*PP*DD)
#define OFF_AFULL  (OFF_TH0S  + KAP*NN0*DD)
#define OFF_LT     (OFF_AFULL + KAP*PP*PP)
#define OFF_LROW   (OFF_LT    + KAP*PP*PP)
#define OFF_XB     (OFF_LROW  + KAP*PP*PP)
#define OFF_DLI    (OFF_XB    + KAP*PP*PP)
#define OFF_CRH    (OFF_DLI   + KAP*PP)
#define OFF_DINV   (OFF_CRH   + KAP*NN*PP)
#define OFF_DG     (OFF_DINV  + KAP*NN)
#define OFF_VV     (OFF_DG    + KAP*NN)
#define OFF_WV     (OFF_VV    + KAP*PP)
#define OFF_CG     (OFF_WV    + KAP*PP)
#define OFF_GPART  (OFF_CG    + KAP*NN)
#define OFF_GHAT   (OFF_GPART + KAP*8*1024)
#define OFF_RPART  (OFF_GHAT  + KAP*NN0)
// XT (padded, KAP*PP*XPS = 819200 floats) lives in the LROW+XB region (1.28M floats)
#define OFF_XT     OFF_LROW
// need(NCH) = OFF_RPART + KAP*NCH*PP*RST floats

// async global->LDS, 16B per lane; LDS base must be wave-uniform
__device__ __forceinline__ void gld_lds16(const float* g, float* l) {
  __builtin_amdgcn_global_load_lds(
      (const __attribute__((address_space(1))) unsigned int*)g,
      (__attribute__((address_space(3))) unsigned int*)l, 16, 0, 0);
}

// ---------------------------------------------------------------------------
// K0: per-k scaled inputs  x / exp(lmb_j)
__global__ void scale_kernel(const float* __restrict__ theta, const float* __restrict__ thetai,
                             const float* __restrict__ theta0, const float* __restrict__ Lmb,
                             float* __restrict__ ths, float* __restrict__ thi, float* __restrict__ th0s) {
  int k = blockIdx.y;
  int idx = blockIdx.x * 256 + threadIdx.x;
  const int total = (NN + PP + NN0) * DD;
  if (idx >= total) return;
  int row = idx >> 3, j = idx & 7;
  float ils = __expf(-Lmb[k * 9 + j]);
  if (row < NN) {
    ths[(k * NN + row) * DD + j] = theta[row * DD + j] * ils;
  } else if (row < NN + PP) {
    int r = row - NN;
    thi[(k * PP + r) * DD + j] = thetai[r * DD + j] * ils;
  } else {
    int r = row - NN - PP;
    th0s[(k * NN0 + r) * DD + j] = theta0[r * DD + j] * ils;
  }
}

// ---------------------------------------------------------------------------
// K0b: build C_i (full symmetric) per k into Afull
__global__ void buildci_kernel(const float* __restrict__ thi, const float* __restrict__ Lmb,
                               float* __restrict__ A) {
  int k = blockIdx.x;
  __shared__ float ti[PP * DD];
  for (int i = threadIdx.x; i < PP * DD; i += 256) ti[i] = thi[k * PP * DD + i];
  __syncthreads();
  float lsig = Lmb[k * 9 + 8];
  float* Ak = A + k * PP * PP;
  for (int idx = threadIdx.x; idx < PP * PP; idx += 256) {
    int i = idx / PP, j = idx - i * PP;
    float prod = 1.f, sum = 0.f;
#pragma unroll
    for (int t = 0; t < DD; ++t) {
      float s = fabsf(ti[i * DD + t] - ti[j * DD + t]);
      prod = __fmaf_rn(prod, s, prod);  // prod *= (1+s)
      sum += s;
    }
    float val = prod * __expf(lsig - sum);
    if (i == j) val += NUGF * __expf(lsig);
    Ak[idx] = val;
  }
}

// ---------------------------------------------------------------------------
// K1/K6: Cholesky of a 200x200 SPD matrix, REGISTER-resident trailing matrix.
// amdgpu_waves_per_eu(4,4): PIN occupancy to 4 waves/EU -> 128-VGPR budget.
__device__ __forceinline__ float rdlane(float v, int l) {
  return __int_as_float(__builtin_amdgcn_readlane(__float_as_int(v), l));
}

__global__ __launch_bounds__(1024) __attribute__((amdgpu_waves_per_eu(4, 4)))
void chol_kernel(const float* __restrict__ Ain,
                 float* __restrict__ LT,
                 float* __restrict__ dli) {
  int k = blockIdx.x;
  Ain += (size_t)k * PP * PP; LT += (size_t)k * PP * PP; dli += (size_t)k * PP;
  __shared__ __align__(16) float Ppre[8 * PTS];  // staged panel, [q][r] absolute r
  __shared__ __align__(16) float Pt[8 * PTS];    // factorized panel, [q][r]
  const int tid = threadIdx.x;

  // ---- decode owned tiles (row-tile-major lower triangle), load to regs ----
  int t_rt[2], t_ct[2];
  bool t_ok[2];
  float4 acc[2][4];
#pragma unroll
  for (int t = 0; t < 2; ++t) {
    int ti = (tid - 64) + t * 960;
    t_ok[t] = (tid >= 64) && (ti < NTILE);
    int tie = t_ok[t] ? ti : 0;
    int rt = (int)((sqrtf(8.0f * (float)tie + 1.0f) - 1.0f) * 0.5f);
    while ((rt + 1) * (rt + 2) / 2 <= tie) ++rt;
    while (rt * (rt + 1) / 2 > tie) --rt;
    int ct = tie - rt * (rt + 1) / 2;
    t_rt[t] = rt; t_ct[t] = ct;
    if (t_ok[t]) {
      const float* src = Ain + (size_t)(4 * rt) * PP + 4 * ct;
#pragma unroll
      for (int i = 0; i < 4; ++i) acc[t][i] = *(const float4*)(src + (size_t)i * PP);
    } else {
#pragma unroll
      for (int i = 0; i < 4; ++i) acc[t][i] = make_float4(0.f, 0.f, 0.f, 0.f);
    }
  }

  float preg[4][8];  // wave-0 panel registers (live across the barrier)
  for (int s = 0; s < 25; ++s) {
    const int jb = 8 * s;
    // ---- owners of the two panel tile-columns stage them to LDS ----
#pragma unroll
    for (int t = 0; t < 2; ++t) {
      if (t_ok[t] && (t_ct[t] >> 1) == s) {
        int q0 = 4 * t_ct[t] - jb;   // 0 or 4
        int r0 = 4 * t_rt[t];
#pragma unroll
        for (int i = 0; i < 4; ++i) {
          Ppre[(q0 + 0) * PTS + r0 + i] = acc[t][i].x;
          Ppre[(q0 + 1) * PTS + r0 + i] = acc[t][i].y;
          Ppre[(q0 + 2) * PTS + r0 + i] = acc[t][i].z;
          Ppre[(q0 + 3) * PTS + r0 + i] = acc[t][i].w;
        }
      }
    }
    __syncthreads();
    const int nrows = PP - jb;
    // ---- wave 0: panel factorization in registers, readlane chain ----
    if (tid < 64) {
      const int L = tid;
#pragma unroll
      for (int u = 0; u < 4; ++u) {
        int rl = L + 64 * u;
#pragma unroll
        for (int c = 0; c < 8; ++c)
          preg[u][c] = (rl < nrows && rl >= c) ? Ppre[c * PTS + jb + rl] : 0.f;
      }
#pragma unroll
      for (int jj = 0; jj < 8; ++jj) {
        float dv = rdlane(preg[0][jj], jj);
        float l = sqrtf(fmaxf(dv, 1e-12f));
        float inv = 1.0f / l;
#pragma unroll
        for (int u = 0; u < 4; ++u)
          if (u > 0 || L > jj) preg[u][jj] *= inv;
        if (L == jj) { preg[0][jj] = l; dli[jb + jj] = inv; }
#pragma unroll
        for (int c = 0; c < 8; ++c) {
          if (c > jj) {
            float pc = rdlane(preg[0][jj], c);
#pragma unroll
            for (int u = 0; u < 4; ++u)
              preg[u][c] = __fmaf_rn(-preg[u][jj], pc, preg[u][c]);
          }
        }
      }
#pragma unroll
      for (int u = 0; u < 4; ++u) {
        int rl = L + 64 * u;
        if (rl < nrows) {
#pragma unroll
          for (int c = 0; c < 8; ++c) Pt[c * PTS + jb + rl] = preg[u][c];
        }
      }
    }
    __syncthreads();
    // ---- wave 0: LT global writes off the critical path (drain overlaps) ----
    if (tid < 64) {
      const int L = tid;
#pragma unroll
      for (int u = 0; u < 4; ++u) {
        int rl = L + 64 * u;
        if (rl < nrows) {
#pragma unroll
          for (int c = 0; c < 8; ++c)
            if (rl >= c) LT[(jb + c) * PP + jb + rl] = preg[u][c];
        }
      }
    }
    // ---- rank-8 trailing update on register tiles ----
    const int ctmin = 2 * s + 2;
#pragma unroll
    for (int t = 0; t < 2; ++t) {
      if (t_ok[t] && t_ct[t] >= ctmin) {
        const float* pr = Pt + 4 * t_rt[t];
        const float* pcl = Pt + 4 * t_ct[t];
#pragma unroll
        for (int q = 0; q < 8; ++q) {
          float4 a = *(const float4*)(pr + q * PTS);   // broadcast within wave
          float4 b = *(const float4*)(pcl + q * PTS);  // consecutive float4s
          acc[t][0].x = __fmaf_rn(-a.x, b.x, acc[t][0].x);
          acc[t][0].y = __fmaf_rn(-a.x, b.y, acc[t][0].y);
          acc[t][0].z = __fmaf_rn(-a.x, b.z, acc[t][0].z);
          acc[t][0].w = __fmaf_rn(-a.x, b.w, acc[t][0].w);
          acc[t][1].x = __fmaf_rn(-a.y, b.x, acc[t][1].x);
          acc[t][1].y = __fmaf_rn(-a.y, b.y, acc[t][1].y);
          acc[t][1].z = __fmaf_rn(-a.y, b.z, acc[t][1].z);
          acc[t][1].w = __fmaf_rn(-a.y, b.w, acc[t][1].w);
          acc[t][2].x = __fmaf_rn(-a.z, b.x, acc[t][2].x);
          acc[t][2].y = __fmaf_rn(-a.z, b.y, acc[t][2].y);
          acc[t][2].z = __fmaf_rn(-a.z, b.z, acc[t][2].z);
          acc[t][2].w = __fmaf_rn(-a.z, b.w, acc[t][2].w);
          acc[t][3].x = __fmaf_rn(-a.w, b.x, acc[t][3].x);
          acc[t][3].y = __fmaf_rn(-a.w, b.y, acc[t][3].y);
          acc[t][3].z = __fmaf_rn(-a.w, b.z, acc[t][3].z);
          acc[t][3].w = __fmaf_rn(-a.w, b.w, acc[t][3].w);
        }
      }
    }
  }
}

// ---------------------------------------------------------------------------
// K2: X = L^{-1}, column-parallel forward substitution. grid (4, KAP).
// Output stored TRANSPOSED + PADDED: XT[c*XPS + t] = X[t][c]; cols t=200..255
// zeroed once (allows unconditional 64-lane global_load_lds in crh).
__global__ __launch_bounds__(256) void linv_kernel(const float* __restrict__ LT,
                                                   const float* __restrict__ dli_g,
                                                   float* __restrict__ XT) {
  int cb = blockIdx.x, k = blockIdx.y;
  LT += (size_t)k * PP * PP; dli_g += k * PP; XT += (size_t)k * PP * XPS;
  __shared__ float acc[PP * ACST];   // 51.2 KB slab: acc[r][i]
  __shared__ float Pn[8 * PP];       // panel: Pn[q][r] = LT[t0+q][r] = L[r][t0+q]
  __shared__ float xf[8 * ACST];
  __shared__ float dl[PP];
  const int tid = threadIdx.x;
  const int i = tid & 63, rg = tid >> 6;
  const int c = cb + 4 * i;          // owned column (valid if c < PP)
  for (int idx = tid; idx < PP * ACST; idx += 256) acc[idx] = 0.f;
  for (int r = tid; r < PP; r += 256) dl[r] = dli_g[r];
  // zero the padded tail (cols 200..255 of each owned row), once
  {
    float4 z4 = make_float4(0.f, 0.f, 0.f, 0.f);
    for (int idx = tid; idx < 50 * 14; idx += 256) {
      int il = idx / 14, f4 = idx - il * 14;
      int c2 = cb + 4 * il;   // < 200 by construction
      *(float4*)&XT[(size_t)c2 * XPS + 200 + 4 * f4] = z4;
    }
  }
  __syncthreads();
  for (int s = 0; s < 25; ++s) {
    const int t0 = 8 * s;
    for (int idx = tid; idx < 8 * PP; idx += 256) Pn[idx] = LT[t0 * PP + idx];
    __syncthreads();
    if (rg == 0) {
      float xq[8];
#pragma unroll
      for (int q = 0; q < 8; ++q) {
        int t = t0 + q;
        float sv = acc[t * ACST + i];
#pragma unroll
        for (int m = 0; m < 8; ++m)
          if (m < q) sv = __fmaf_rn(Pn[m * PP + t], xq[m], sv);
        float xv = (((t == c) ? 1.0f : 0.0f) - sv) * dl[t];
        xq[q] = xv;
        xf[q * ACST + i] = xv;
      }
    }
    __syncthreads();
    // XT store: float4 along t (t0+4*q4 .. +3) for owned columns
    if (tid < 128) {
      int q4 = tid >> 6, il = tid & 63;
      int c2 = cb + 4 * il;
      if (c2 < PP) {
        float4 v4 = make_float4(xf[(q4 * 4 + 0) * ACST + il], xf[(q4 * 4 + 1) * ACST + il],
                                xf[(q4 * 4 + 2) * ACST + il], xf[(q4 * 4 + 3) * ACST + il]);
        *(float4*)&XT[(size_t)c2 * XPS + t0 + 4 * q4] = v4;
      }
    }
    for (int r = t0 + 8 + rg; r < PP; r += 4) {
      float v = acc[r * ACST + i];
#pragma unroll
      for (int q = 0; q < 8; ++q)
        v = __fmaf_rn(Pn[q * PP + r], xf[q * ACST + i], v);
      acc[r * ACST + i] = v;
    }
    __syncthreads();
  }
}

// ---------------------------------------------------------------------------
// K6b: w = R^{-1} v = X^T (X v). X stored transposed/padded (XT[c*XPS+t]);
// summation ORDER identical (bit-identical w).
__global__ __launch_bounds__(256) void rsolve_kernel(const float* __restrict__ XT,
                                                     const float* __restrict__ v,
                                                     float* __restrict__ w) {
  int k = blockIdx.x;
  XT += (size_t)k * PP * XPS; v += k * PP; w += k * PP;
  __shared__ float vl[PP], yl[PP];
  int tid = threadIdx.x, lane = tid & 63, rg = tid >> 6;
  for (int i = tid; i < PP; i += 256) vl[i] = v[i];
  __syncthreads();
  // y = X v ; X[r][c] = XT[c*XPS+r]
  for (int r = rg; r < PP; r += 4) {
    float s = 0.f;
    for (int c = lane; c < PP; c += 64) s = __fmaf_rn(XT[(size_t)c * XPS + r], vl[c], s);
#pragma unroll
    for (int off = 32; off > 0; off >>= 1) s += __shfl_xor(s, off, 64);
    if (lane == 0) yl[r] = s;
  }
  __syncthreads();
  // w = X^T y ; X[r][tid] = XT[tid*XPS+r]
  if (tid < PP) {
    float s = 0.f;
    for (int r = 0; r < PP; ++r) s = __fmaf_rn(XT[(size_t)tid * XPS + r], yl[r], s);
    w[tid] = s;
  }
}

// ---------------------------------------------------------------------------
// K3: Crh = c_fi @ Linv^T, async B-staging; v7: 64-ROW register tiles
// (acc[4][16], grid 63 x KAP). crh is LDS-READ-throughput bound (round-9
// analysis: 2.25 B/FMA at 32-row = ~120us floor = measured); 64-row tiles
// read one b128 a-operand per 64 FMAs and halve total B-traffic per output
// -> LDS floor ~70-85us. Same tile size as round-4 (which measured 138us
// with SYNCHRONOUS staging) but now with the async gld_lds staging round 5
// proved; register profile matches round-4's 80-VGPR no-spill build (no
// cross-phase data registers). Per-output FMA chains, cov values, delta
// reduction element-wise identical -> same absmax.
__global__ __launch_bounds__(256) void crh_kernel(const float* __restrict__ ths,
                                                  const float* __restrict__ thi,
                                                  const float* __restrict__ Lmb,
                                                  const float* __restrict__ XT,
                                                  const float* __restrict__ Mg,
                                                  float* __restrict__ Crh,
                                                  float* __restrict__ Dinv,
                                                  float* __restrict__ Dg) {
  int k = blockIdx.y, rt = blockIdx.x, r0 = rt * 64;
  const float* thk = ths + k * NN * DD;
  const float* XTk = XT + (size_t)k * PP * XPS;
  float* Ck = Crh + (size_t)k * NN * PP;
  __shared__ __align__(16) float ts[64 * 9];
  __shared__ __align__(16) float til[PP * DD];   // inducing pts, staged once
  __shared__ __align__(16) float At[16 * 64];
  __shared__ __align__(16) float Bt[16 * BTS];
  int tid = threadIdx.x, tx = tid & 15, ty = tid >> 4;
  const int lr = tid & 63;   // lane in wave
  const int wq = tid >> 6;   // wave id 0..3
  float lsig = Lmb[k * 9 + 8];
  for (int idx = tid; idx < 64 * DD; idx += 256) {
    int r = idx >> 3, j = idx & 7;
    int rr = r0 + r; if (rr > NN - 1) rr = NN - 1;
    ts[r * 9 + j] = thk[rr * DD + j];
  }
  for (int idx = tid; idx < PP * DD; idx += 256) til[idx] = thi[k * PP * DD + idx];
  float acc[4][16];
#pragma unroll
  for (int i = 0; i < 4; ++i)
#pragma unroll
    for (int q = 0; q < 16; ++q) acc[i][q] = 0.f;

  for (int jb = 0; jb < PP; jb += 16) {
    __syncthreads();   // prior FMA readers done; ts/til visible at jb=0
    // ---- issue async B loads: Bt[kk][lane*4..+3] <- XT[(jb+kk)*XPS + lane*4]
#pragma unroll
    for (int u = 0; u < 4; ++u) {
      int kk = wq + 4 * u;           // wave-uniform
      int row = jb + kk;
      if (row < PP)                  // wave-uniform guard
        gld_lds16(XTk + (size_t)row * XPS + lr * 4, &Bt[kk * BTS]);
      // rows >= PP keep stale data; At[kk]=0 there -> contributes exact 0
    }
    // ---- cov -> At (LDS-only; overlaps the in-flight loads) ----
    for (int idx = tid; idx < 16 * 64; idx += 256) {
      int r = idx & 63, kk = idx >> 6;
      float va = 0.f;
      int kkg = jb + kk;
      if (kkg < PP) {
        float prod = 1.f, sum = 0.f;
#pragma unroll
        for (int t = 0; t < DD; ++t) {
          float s = fabsf(ts[r * 9 + t] - til[kkg * DD + t]);
          prod = __fmaf_rn(prod, s, prod);
          sum += s;
        }
        va = prod * __expf(lsig - sum);
      }
      At[kk * 64 + r] = va;
    }
    __syncthreads();   // drains vmcnt(0): Bt ready
#pragma unroll
    for (int kk = 0; kk < 16; ++kk) {
      float4 a4 = *(const float4*)&At[kk * 64 + ty * 4];
      const float* bp = &Bt[kk * BTS + tx * 4];
      float bv[16];
      *(float4*)&bv[0]  = *(const float4*)(bp);
      *(float4*)&bv[4]  = *(const float4*)(bp + 64);
      *(float4*)&bv[8]  = *(const float4*)(bp + 128);
      *(float4*)&bv[12] = *(const float4*)(bp + 192);
      float av[4] = {a4.x, a4.y, a4.z, a4.w};
#pragma unroll
      for (int i = 0; i < 4; ++i)
#pragma unroll
        for (int q = 0; q < 16; ++q)
          acc[i][q] = __fmaf_rn(av[i], bv[q], acc[i][q]);
    }
  }
  // store: thread cols c = tx*4 + 64q (all multiples of 4; c<PP => full float4 valid)
#pragma unroll
  for (int i = 0; i < 4; ++i) {
    int r = r0 + ty * 4 + i;
    if (r < NN) {
#pragma unroll
      for (int q = 0; q < 4; ++q) {
        int c = tx * 4 + 64 * q;
        if (c < PP) {
          float4 v = make_float4(acc[i][q * 4], acc[i][q * 4 + 1], acc[i][q * 4 + 2], acc[i][q * 4 + 3]);
          *(float4*)&Ck[r * PP + c] = v;
        }
      }
    }
  }
  // ---- fused delta: per-row sumsq (cols >= PP contribute exact zeros) ----
  float ss[4];
#pragma unroll
  for (int i = 0; i < 4; ++i) {
    float s = 0.f;
#pragma unroll
    for (int q = 0; q < 16; ++q) s = __fmaf_rn(acc[i][q], acc[i][q], s);
    ss[i] = s;
  }
#pragma unroll
  for (int off = 1; off <= 8; off <<= 1) {
#pragma unroll
    for (int i = 0; i < 4; ++i) ss[i] += __shfl_xor(ss[i], off);
  }
  if (tx == 0) {
    float sig = __expf(lsig);
#pragma unroll
    for (int i = 0; i < 4; ++i) {
      int r = r0 + ty * 4 + i;
      if (r < NN) {
        float delta = fmaxf(sig * (1.f + NUGF) - ss[i], NUGF);
        float di = 1.f / delta;
        Dinv[k * NN + r] = di;
        Dg[k * NN + r] = di * Mg[(size_t)k * NN + r];
      }
    }
  }
}

// ---------------------------------------------------------------------------
// K5: R partials = Crh^T diag(Dinv) [Crh | g] over NCH K-chunks.
// 64x128 tiles; occupancy from NCH=16 (2048 blocks = 8 blocks/CU).
// XCD-GROUPING remap: all 8 tiles of a (k,kch) group land on one XCD so the
// shared 250-row Crh chunk is fetched into that XCD's L2 once (was 3x HBM
// over-fetch with round-robin). Pure bijective remap; bit-identical.
template <int NCH>
__global__ __launch_bounds__(256) void syrk_kernel(const float* __restrict__ Crh,
                                                   const float* __restrict__ Dinv,
                                                   const float* __restrict__ M,
                                                   float* __restrict__ Rp) {
  const int CH = NN / NCH;
  const int GRP_PER_XCD = (NCH * KAP) / 8;
  int lin = blockIdx.x + 8 * (blockIdx.y + NCH * blockIdx.z);
  int xcd = lin & 7, q = lin >> 3;
  int grp = xcd * GRP_PER_XCD + (q >> 3);
  int tile = q & 7;
  int k = grp / NCH, kch = grp - k * NCH;
  int it = tile >> 1, jc = tile & 1;
  int i0 = it * 64, cb = jc * 128;
  const float* Ck = Crh + (size_t)k * NN * PP;
  float* Rk = Rp + (size_t)(k * NCH + kch) * PP * RST;
  __shared__ __align__(16) float Sc[16 * 64];
  __shared__ __align__(16) float Rw[16 * 128];
  int tid = threadIdx.x, tx = tid & 15, ty = tid >> 4;
  const int kk = ty;            // staging K-row (0..15)
  const int ii4 = tx * 4;       // quad offset
  int rbase0 = kch * CH;
  const float* pA = Ck + (size_t)(rbase0 + kk) * PP + i0 + ii4;
  const float* pB = Ck + (size_t)(rbase0 + kk) * PP + cb + ii4;
  const float* pD = Dinv + (size_t)k * NN + rbase0 + kk;
  const float* pM = M + (size_t)k * NN + rbase0 + kk;
  const bool aok = (i0 + ii4 + 3 < PP);
  const int cg0 = cb + ii4, cg1 = cb + ii4 + 64;
  const bool b0f = (cg0 + 3 < PP);
  const bool b1f = (cg1 + 3 < PP);
  float4 ra, rv0, rv1;
  float acc[4][8];
#pragma unroll
  for (int i = 0; i < 4; ++i)
#pragma unroll
    for (int q2 = 0; q2 < 8; ++q2) acc[i][q2] = 0.f;

  auto stage = [&](int rb) {
    bool rok = (rb + kk < CH);
    float d = rok ? *pD : 0.f;
    if (rok && aok) {
      float4 t = *(const float4*)pA;
      ra = make_float4(t.x * d, t.y * d, t.z * d, t.w * d);
    } else ra = make_float4(0.f, 0.f, 0.f, 0.f);
    if (rok) {
      rv0 = b0f ? *(const float4*)pB : make_float4(0.f, 0.f, 0.f, 0.f);
      if (b1f) rv1 = *(const float4*)(pB + 64);
      else {
        float e[4];
#pragma unroll
        for (int u = 0; u < 4; ++u) {
          int cg = cg1 + u;
          e[u] = (cg < PP) ? pB[64 + u] : ((cg == PP) ? *pM : 0.f);
        }
        rv1 = make_float4(e[0], e[1], e[2], e[3]);
      }
    } else { rv0 = make_float4(0.f, 0.f, 0.f, 0.f); rv1 = rv0; }
    pA += 16 * PP; pB += 16 * PP; pD += 16; pM += 16;
  };
  stage(0);
  for (int rb = 0; rb < CH; rb += 16) {
    __syncthreads();
    *(float4*)&Sc[kk * 64 + ii4] = ra;
    *(float4*)&Rw[kk * 128 + ii4] = rv0;
    *(float4*)&Rw[kk * 128 + ii4 + 64] = rv1;
    __syncthreads();
    stage(rb + 16);   // overlaps with compute below (guards -> 0 past end)
#pragma unroll
    for (int kq = 0; kq < 16; ++kq) {
      float4 a4 = *(const float4*)&Sc[kq * 64 + ty * 4];
      const float* bp = &Rw[kq * 128 + tx * 4];
      float bv[8];
      *(float4*)&bv[0] = *(const float4*)(bp);
      *(float4*)&bv[4] = *(const float4*)(bp + 64);
      float av[4] = {a4.x, a4.y, a4.z, a4.w};
#pragma unroll
      for (int i = 0; i < 4; ++i)
#pragma unroll
        for (int q2 = 0; q2 < 8; ++q2)
          acc[i][q2] = __fmaf_rn(av[i], bv[q2], acc[i][q2]);
    }
  }
#pragma unroll
  for (int i = 0; i < 4; ++i) {
    int r = i0 + ty * 4 + i;
    if (r < PP) {
#pragma unroll
      for (int q2 = 0; q2 < 2; ++q2) {
        int c = cb + tx * 4 + 64 * q2;
        if (c + 3 < PP) {
          float4 v = make_float4(acc[i][q2 * 4], acc[i][q2 * 4 + 1], acc[i][q2 * 4 + 2], acc[i][q2 * 4 + 3]);
          *(float4*)&Rk[r * RST + c] = v;
        } else if (c == PP) {
          Rk[r * RST + c] = acc[i][q2 * 4];   // v column
        }
      }
    }
  }
}

// K5b: R = I + sum partials -> Afull ; v = sum partials col 200 -> Vv
template <int NCH>
__global__ void reducer_kernel(const float* __restrict__ Rp, float* __restrict__ A,
                               float* __restrict__ Vv) {
  int k = blockIdx.y;
  int idx = blockIdx.x * 256 + threadIdx.x;
  if (idx < PP * PP) {
    int i = idx / PP, j = idx - i * PP;
    float s = (i == j) ? 1.0f : 0.0f;
    for (int ch = 0; ch < NCH; ++ch) s += Rp[(size_t)((k * NCH + ch) * PP + i) * RST + j];
    A[k * PP * PP + idx] = s;
  }
  if (idx < PP) {
    float sv = 0.f;
    for (int ch = 0; ch < NCH; ++ch) sv += Rp[(size_t)((k * NCH + ch) * PP + idx) * RST + PP];
    Vv[k * PP + idx] = sv;
  }
}

// ---------------------------------------------------------------------------
// K7: Cinv_g = Dg - Dinv * (Crh @ w)
__global__ void cg_kernel(const float* __restrict__ Crh, const float* __restrict__ w,
                          const float* __restrict__ Dinv, const float* __restrict__ Dg,
                          float* __restrict__ Cg) {
  int k = blockIdx.y;
  __shared__ float ws[PP];
  for (int i = threadIdx.x; i < PP; i += 256) ws[i] = w[k * PP + i];
  __syncthreads();
  int r = blockIdx.x * 4 + (threadIdx.x >> 6);
  int lane = threadIdx.x & 63;
  const float* row = Crh + (size_t)(k * NN + r) * PP;
  float s = 0.f;
  for (int c = lane; c < PP; c += 64) s = __fmaf_rn(row[c], ws[c], s);
#pragma unroll
  for (int off = 32; off > 0; off >>= 1) s += __shfl_xor(s, off, 64);
  if (lane == 0) Cg[k * NN + r] = Dg[k * NN + r] - Dinv[k * NN + r] * s;
}

// ---------------------------------------------------------------------------
// K8: ghat partials = cov(theta0, theta) @ Cinv_g, fused cov+matvec.
// 8 row-chunks of 500 -> grid 512 = 2 blocks/CU.
__global__ __launch_bounds__(256) void pred_kernel(const float* __restrict__ th0s,
                                                   const float* __restrict__ ths,
                                                   const float* __restrict__ Lmb,
                                                   const float* __restrict__ Cg,
                                                   float* __restrict__ Gp) {
  int k = blockIdx.z, rch = blockIdx.y, it = blockIdx.x;
  int i0 = it * 256 + threadIdx.x;
  const float* t0k = th0s + k * NN0 * DD;
  const float* thk = ths + k * NN * DD;
  const float* cgk = Cg + k * NN;
  __shared__ float tsl[64 * DD];
  __shared__ float cs[64];
  float t0r[DD];
  int i0c = (i0 < NN0) ? i0 : (NN0 - 1);
#pragma unroll
  for (int j = 0; j < DD; ++j) t0r[j] = t0k[i0c * DD + j];
  float lsig = Lmb[k * 9 + 8];
  float acc = 0.f;
  int rb0 = rch * 500;
  for (int rb = 0; rb < 500; rb += 64) {
    __syncthreads();
    for (int idx = threadIdx.x; idx < 64 * DD; idx += 256) {
      int a = rb0 + rb + (idx >> 3);
      if (a > NN - 1) a = NN - 1;
      tsl[idx] = thk[a * DD + (idx & 7)];
    }
    if (threadIdx.x < 64) {
      int rrr = rb + threadIdx.x;
      cs[threadIdx.x] = (rrr < 500) ? cgk[rb0 + rrr] : 0.f;
    }
    __syncthreads();
#pragma unroll 4
    for (int rr = 0; rr < 64; ++rr) {
      float prod = 1.f, sum = 0.f;
#pragma unroll
      for (int j = 0; j < DD; ++j) {
        float s = fabsf(t0r[j] - tsl[rr * DD + j]);
        prod = __fmaf_rn(prod, s, prod);
        sum += s;
      }
      acc = __fmaf_rn(prod * __expf(lsig - sum), cs[rr], acc);
    }
  }
  if (i0 < NN0) Gp[(k * 8 + rch) * 1024 + i0] = acc;
}

// K8b: reduce ghat partials
__global__ void gred_kernel(const float* __restrict__ Gp, float* __restrict__ ghat) {
  int idx = blockIdx.x * 256 + threadIdx.x;
  if (idx >= KAP * NN0) return;
  int k = idx / NN0, i0 = idx - k * NN0;
  float s = 0.f;
  for (int ch = 0; ch < 8; ++ch) s += Gp[(k * 8 + ch) * 1024 + i0];
  ghat[idx] = s;
}

// ---------------------------------------------------------------------------
// K9: fhat = (Phi @ ghat) * Fstd + Fmean
__global__ __launch_bounds__(256) void final_kernel(const float* __restrict__ Phi,
                                                    const float* __restrict__ ghat,
                                                    const float* __restrict__ Fmean,
                                                    const float* __restrict__ Fstd,
                                                    float* __restrict__ out) {
  int it = blockIdx.y, jt = blockIdx.x;
  int i0 = it * 64, j = jt * 256 + threadIdx.x;
  __shared__ float ph[64 * KAP];
  __shared__ float fm[64], fs[64];
  for (int idx = threadIdx.x; idx < 64 * KAP; idx += 256) {
    int i = idx >> 4, kk = idx & 15;
    int ii = i0 + i; if (ii > MMR - 1) ii = MMR - 1;
    ph[idx] = Phi[ii * KAP + kk];
  }
  if (threadIdx.x < 64) {
    int ii = i0 + threadIdx.x; if (ii > MMR - 1) ii = MMR - 1;
    fm[threadIdx.x] = Fmean[ii];
    fs[threadIdx.x] = Fstd[ii];
  }
  float gj[KAP];
#pragma unroll
  for (int kk = 0; kk < KAP; ++kk) gj[kk] = (j < NN0) ? ghat[kk * NN0 + j] : 0.f;
  __syncthreads();
  if (j < NN0) {
    for (int i = 0; i < 64; ++i) {
      int ii = i0 + i;
      if (ii >= MMR) break;
      float s = 0.f;
#pragma unroll
      for (int kk = 0; kk < KAP; ++kk) s = __fmaf_rn(ph[i * KAP + kk], gj[kk], s);
      out[(size_t)ii * NN0 + j] = __fmaf_rn(s, fs[i], fm[i]);
    }
  }
}

// ---------------------------------------------------------------------------
extern "C" void kernel_launch(void* const* d_in, const int* in_sizes, int n_in,
                              void* d_out, int out_size, void* d_ws, size_t ws_size,
                              hipStream_t stream) {
  const float* theta0 = (const float*)d_in[0];
  const float* Lmb    = (const float*)d_in[1];
  // d_in[2] = lsigma2 (unused by reference output)
  const float* Phi    = (const float*)d_in[3];
  const float* theta  = (const float*)d_in[4];
  const float* thetai = (const float*)d_in[5];
  const float* M      = (const float*)d_in[6];
  const float* Fmean  = (const float*)d_in[7];
  const float* Fstd   = (const float*)d_in[8];
  float* out = (float*)d_out;
  float* ws = (float*)d_ws;

  float* ths   = ws + OFF_THS;
  float* thi   = ws + OFF_THI;
  float* th0s  = ws + OFF_TH0S;
  float* Afull = ws + OFF_AFULL;
  float* LT    = ws + OFF_LT;
  float* Xt    = ws + OFF_XT;     // padded XT (stride XPS), in LROW+XB region
  float* dli   = ws + OFF_DLI;
  float* Crh   = ws + OFF_CRH;
  float* Dinv  = ws + OFF_DINV;
  float* Dg    = ws + OFF_DG;
  float* Vv    = ws + OFF_VV;
  float* Wv    = ws + OFF_WV;
  float* Cg    = ws + OFF_CG;
  float* Gpart = ws + OFF_GPART;
  float* ghat  = ws + OFF_GHAT;
  float* Rpart = ws + OFF_RPART;

  // choose syrk K-chunk count by available workspace (16 -> 8 blocks/CU grid)
  size_t need16 = ((size_t)OFF_RPART + (size_t)KAP * 16 * PP * RST) * sizeof(float);
  size_t need8  = ((size_t)OFF_RPART + (size_t)KAP * 8  * PP * RST) * sizeof(float);
  int nch = (ws_size >= need16) ? 16 : ((ws_size >= need8) ? 8 : 4);

  scale_kernel<<<dim3(163, KAP), 256, 0, stream>>>(theta, thetai, theta0, Lmb, ths, thi, th0s);
  buildci_kernel<<<KAP, 256, 0, stream>>>(thi, Lmb, Afull);
  chol_kernel<<<KAP, 1024, 0, stream>>>(Afull, LT, dli);
  linv_kernel<<<dim3(4, KAP), 256, 0, stream>>>(LT, dli, Xt);
  crh_kernel<<<dim3(63, KAP), 256, 0, stream>>>(ths, thi, Lmb, Xt, M, Crh, Dinv, Dg);
  if (nch == 16) {
    syrk_kernel<16><<<dim3(8, 16, KAP), 256, 0, stream>>>(Crh, Dinv, M, Rpart);
    reducer_kernel<16><<<dim3(157, KAP), 256, 0, stream>>>(Rpart, Afull, Vv);
  } else if (nch == 8) {
    syrk_kernel<8><<<dim3(8, 8, KAP), 256, 0, stream>>>(Crh, Dinv, M, Rpart);
    reducer_kernel<8><<<dim3(157, KAP), 256, 0, stream>>>(Rpart, Afull, Vv);
  } else {
    syrk_kernel<4><<<dim3(8, 4, KAP), 256, 0, stream>>>(Crh, Dinv, M, Rpart);
    reducer_kernel<4><<<dim3(157, KAP), 256, 0, stream>>>(Rpart, Afull, Vv);
  }
  chol_kernel<<<KAP, 1024, 0, stream>>>(Afull, LT, dli);        // Cholesky of R
  linv_kernel<<<dim3(4, KAP), 256, 0, stream>>>(LT, dli, Xt);   // X_R = L_R^{-1} (transposed/padded)
  rsolve_kernel<<<KAP, 256, 0, stream>>>(Xt, Vv, Wv);           // w = X^T X v
  cg_kernel<<<dim3(1000, KAP), 256, 0, stream>>>(Crh, Wv, Dinv, Dg, Cg);
  pred_kernel<<<dim3(4, 8, KAP), 256, 0, stream>>>(th0s, ths, Lmb, Cg, Gpart);
  gred_kernel<<<63, 256, 0, stream>>>(Gpart, ghat);
  final_kernel<<<dim3(4, 188), 256, 0, stream>>>(Phi, ghat, Fmean, Fstd, out);
}

// Round 11
// 707.797 us; speedup vs baseline: 1.1309x; 1.0943x over previous
//
#include <hip/hip_runtime.h>

// Problem constants (fixed by setup_inputs)
#define NN   4000
#define PP   200
#define DD   8
#define KAP  16
#define NN0  1000
#define MMR  12000
#define NUGF 1e-6f

// Rpart row stride (200 R cols + 1 v col + pad)
#define RST  204
// linv slab col stride
#define ACST 64
// chol: panel-transpose LDS row stride (floats), tile count of 50x50 lower tri
#define PTS   208
#define NTILE 1275
// crh Bt row stride
#define BTS  260
// XT padded row stride (cols 200..255 zeroed once -> async 64-lane loads safe)
#define XPS  256

// ---- workspace layout (float offsets); RPART last (variable size) ----
#define OFF_THS    0
#define OFF_THI    (OFF_THS   + KAP*NN*DD)
#define OFF_TH0S   (OFF_THI   + KAP*PP*DD)
#define OFF_AFULL  (OFF_TH0S  + KAP*NN0*DD)
#define OFF_LT     (OFF_AFULL + KAP*PP*PP)
#define OFF_LROW   (OFF_LT    + KAP*PP*PP)
#define OFF_XB     (OFF_LROW  + KAP*PP*PP)
#define OFF_DLI    (OFF_XB    + KAP*PP*PP)
#define OFF_CRH    (OFF_DLI   + KAP*PP)
#define OFF_DINV   (OFF_CRH   + KAP*NN*PP)
#define OFF_DG     (OFF_DINV  + KAP*NN)
#define OFF_VV     (OFF_DG    + KAP*NN)
#define OFF_WV     (OFF_VV    + KAP*PP)
#define OFF_CG     (OFF_WV    + KAP*PP)
#define OFF_GPART  (OFF_CG    + KAP*NN)
#define OFF_GHAT   (OFF_GPART + KAP*8*1024)
#define OFF_RPART  (OFF_GHAT  + KAP*NN0)
// XT (padded, KAP*PP*XPS = 819200 floats) lives in the LROW+XB region (1.28M floats)
#define OFF_XT     OFF_LROW
// need(NCH) = OFF_RPART + KAP*NCH*PP*RST floats

// async global->LDS, 16B per lane; LDS base must be wave-uniform
__device__ __forceinline__ void gld_lds16(const float* g, float* l) {
  __builtin_amdgcn_global_load_lds(
      (const __attribute__((address_space(1))) unsigned int*)g,
      (__attribute__((address_space(3))) unsigned int*)l, 16, 0, 0);
}

// ---------------------------------------------------------------------------
// K0: per-k scaled inputs  x / exp(lmb_j)
__global__ void scale_kernel(const float* __restrict__ theta, const float* __restrict__ thetai,
                             const float* __restrict__ theta0, const float* __restrict__ Lmb,
                             float* __restrict__ ths, float* __restrict__ thi, float* __restrict__ th0s) {
  int k = blockIdx.y;
  int idx = blockIdx.x * 256 + threadIdx.x;
  const int total = (NN + PP + NN0) * DD;
  if (idx >= total) return;
  int row = idx >> 3, j = idx & 7;
  float ils = __expf(-Lmb[k * 9 + j]);
  if (row < NN) {
    ths[(k * NN + row) * DD + j] = theta[row * DD + j] * ils;
  } else if (row < NN + PP) {
    int r = row - NN;
    thi[(k * PP + r) * DD + j] = thetai[r * DD + j] * ils;
  } else {
    int r = row - NN - PP;
    th0s[(k * NN0 + r) * DD + j] = theta0[r * DD + j] * ils;
  }
}

// ---------------------------------------------------------------------------
// K0b: build C_i (full symmetric) per k into Afull
__global__ void buildci_kernel(const float* __restrict__ thi, const float* __restrict__ Lmb,
                               float* __restrict__ A) {
  int k = blockIdx.x;
  __shared__ float ti[PP * DD];
  for (int i = threadIdx.x; i < PP * DD; i += 256) ti[i] = thi[k * PP * DD + i];
  __syncthreads();
  float lsig = Lmb[k * 9 + 8];
  float* Ak = A + k * PP * PP;
  for (int idx = threadIdx.x; idx < PP * PP; idx += 256) {
    int i = idx / PP, j = idx - i * PP;
    float prod = 1.f, sum = 0.f;
#pragma unroll
    for (int t = 0; t < DD; ++t) {
      float s = fabsf(ti[i * DD + t] - ti[j * DD + t]);
      prod = __fmaf_rn(prod, s, prod);  // prod *= (1+s)
      sum += s;
    }
    float val = prod * __expf(lsig - sum);
    if (i == j) val += NUGF * __expf(lsig);
    Ak[idx] = val;
  }
}

// ---------------------------------------------------------------------------
// K1/K6: Cholesky of a 200x200 SPD matrix, REGISTER-resident trailing matrix.
// v3: SPILL-PROOF panel factorization. Rounds 6-10 counters proved the old
// preg[4][8] (32 regs live across a barrier) + acc (32 regs) spilled at the
// allocator's 64-VGPR target regardless of hints (VGPR_Count=64, VALUBusy 1%,
// 115us/launch). New structure: (1) lanes 0-7 factorize the 8x8 diagonal
// block in 8 registers (rdlane chain, same fmaf order), publish factor l8 +
// invs to LDS; (2) panel BODY rows are thread-parallel (1 row/thread, 8 regs)
// forward-solved against the LDS factor -- value/order identical to the old
// per-lane chain -> bit-identical LT/dli. preg deleted: peak live ~50 regs
// fits under 64 at ANY occupancy target; also parallelizes the old serial
// wave-0 body work.
__device__ __forceinline__ float rdlane(float v, int l) {
  return __int_as_float(__builtin_amdgcn_readlane(__float_as_int(v), l));
}

__global__ __launch_bounds__(1024)
void chol_kernel(const float* __restrict__ Ain,
                 float* __restrict__ LT,
                 float* __restrict__ dli) {
  int k = blockIdx.x;
  Ain += (size_t)k * PP * PP; LT += (size_t)k * PP * PP; dli += (size_t)k * PP;
  __shared__ __align__(16) float Ppre[8 * PTS];  // staged panel, [q][r] absolute r
  __shared__ __align__(16) float Pt[8 * PTS];    // factorized panel, [q][r]
  __shared__ float l8[64];                        // 8x8 diag factor, l8[r*8+c]
  __shared__ float invs[8];                       // 1/diag for this panel
  const int tid = threadIdx.x;

  // ---- decode owned tiles (row-tile-major lower triangle), load to regs ----
  int t_rt[2], t_ct[2];
  bool t_ok[2];
  float4 acc[2][4];
#pragma unroll
  for (int t = 0; t < 2; ++t) {
    int ti = (tid - 64) + t * 960;
    t_ok[t] = (tid >= 64) && (ti < NTILE);
    int tie = t_ok[t] ? ti : 0;
    int rt = (int)((sqrtf(8.0f * (float)tie + 1.0f) - 1.0f) * 0.5f);
    while ((rt + 1) * (rt + 2) / 2 <= tie) ++rt;
    while (rt * (rt + 1) / 2 > tie) --rt;
    int ct = tie - rt * (rt + 1) / 2;
    t_rt[t] = rt; t_ct[t] = ct;
    if (t_ok[t]) {
      const float* src = Ain + (size_t)(4 * rt) * PP + 4 * ct;
#pragma unroll
      for (int i = 0; i < 4; ++i) acc[t][i] = *(const float4*)(src + (size_t)i * PP);
    } else {
#pragma unroll
      for (int i = 0; i < 4; ++i) acc[t][i] = make_float4(0.f, 0.f, 0.f, 0.f);
    }
  }

  for (int s = 0; s < 25; ++s) {
    const int jb = 8 * s;
    // ---- owners of the two panel tile-columns stage them to LDS ----
#pragma unroll
    for (int t = 0; t < 2; ++t) {
      if (t_ok[t] && (t_ct[t] >> 1) == s) {
        int q0 = 4 * t_ct[t] - jb;   // 0 or 4
        int r0 = 4 * t_rt[t];
#pragma unroll
        for (int i = 0; i < 4; ++i) {
          Ppre[(q0 + 0) * PTS + r0 + i] = acc[t][i].x;
          Ppre[(q0 + 1) * PTS + r0 + i] = acc[t][i].y;
          Ppre[(q0 + 2) * PTS + r0 + i] = acc[t][i].z;
          Ppre[(q0 + 3) * PTS + r0 + i] = acc[t][i].w;
        }
      }
    }
    __syncthreads();
    const int nrows = PP - jb;
    // ---- lanes 0-7: factorize the 8x8 diagonal block (8 regs, rdlane) ----
    if (tid < 8) {
      const int r = tid;
      float e[8];
#pragma unroll
      for (int c = 0; c < 8; ++c)
        e[c] = (r >= c) ? Ppre[c * PTS + jb + r] : 0.f;
#pragma unroll
      for (int jj = 0; jj < 8; ++jj) {
        float dv = rdlane(e[jj], jj);
        float l = sqrtf(fmaxf(dv, 1e-12f));
        float inv = 1.0f / l;
        if (r > jj) e[jj] *= inv;
        if (r == jj) { e[jj] = l; dli[jb + jj] = inv; invs[jj] = inv; }
#pragma unroll
        for (int c = jj + 1; c < 8; ++c) {
          float pc = rdlane(e[jj], c);
          e[c] = __fmaf_rn(-e[jj], pc, e[c]);
        }
      }
      // publish factor + diag-block LT
#pragma unroll
      for (int c = 0; c < 8; ++c) {
        l8[r * 8 + c] = e[c];
        if (r >= c) LT[(jb + c) * PP + jb + r] = e[c];
      }
    }
    __syncthreads();
    // ---- body rows (thread-parallel): forward-solve vs the 8x8 factor ----
    {
      int rl = 8 + tid;
      if (tid < nrows - 8) {
        float row[8];
#pragma unroll
        for (int c = 0; c < 8; ++c) row[c] = Ppre[c * PTS + jb + rl];
#pragma unroll
        for (int jj = 0; jj < 8; ++jj) {
          float v = row[jj] * invs[jj];
          row[jj] = v;
#pragma unroll
          for (int c = jj + 1; c < 8; ++c)
            row[c] = __fmaf_rn(-v, l8[c * 8 + jj], row[c]);
        }
#pragma unroll
        for (int c = 0; c < 8; ++c) {
          Pt[c * PTS + jb + rl] = row[c];
          LT[(jb + c) * PP + jb + rl] = row[c];
        }
      }
    }
    __syncthreads();
    // ---- rank-8 trailing update on register tiles (reads Pt rows >= jb+8) --
    const int ctmin = 2 * s + 2;
#pragma unroll
    for (int t = 0; t < 2; ++t) {
      if (t_ok[t] && t_ct[t] >= ctmin) {
        const float* pr = Pt + 4 * t_rt[t];
        const float* pcl = Pt + 4 * t_ct[t];
#pragma unroll
        for (int q = 0; q < 8; ++q) {
          float4 a = *(const float4*)(pr + q * PTS);   // broadcast within wave
          float4 b = *(const float4*)(pcl + q * PTS);  // consecutive float4s
          acc[t][0].x = __fmaf_rn(-a.x, b.x, acc[t][0].x);
          acc[t][0].y = __fmaf_rn(-a.x, b.y, acc[t][0].y);
          acc[t][0].z = __fmaf_rn(-a.x, b.z, acc[t][0].z);
          acc[t][0].w = __fmaf_rn(-a.x, b.w, acc[t][0].w);
          acc[t][1].x = __fmaf_rn(-a.y, b.x, acc[t][1].x);
          acc[t][1].y = __fmaf_rn(-a.y, b.y, acc[t][1].y);
          acc[t][1].z = __fmaf_rn(-a.y, b.z, acc[t][1].z);
          acc[t][1].w = __fmaf_rn(-a.y, b.w, acc[t][1].w);
          acc[t][2].x = __fmaf_rn(-a.z, b.x, acc[t][2].x);
          acc[t][2].y = __fmaf_rn(-a.z, b.y, acc[t][2].y);
          acc[t][2].z = __fmaf_rn(-a.z, b.z, acc[t][2].z);
          acc[t][2].w = __fmaf_rn(-a.z, b.w, acc[t][2].w);
          acc[t][3].x = __fmaf_rn(-a.w, b.x, acc[t][3].x);
          acc[t][3].y = __fmaf_rn(-a.w, b.y, acc[t][3].y);
          acc[t][3].z = __fmaf_rn(-a.w, b.z, acc[t][3].z);
          acc[t][3].w = __fmaf_rn(-a.w, b.w, acc[t][3].w);
        }
      }
    }
  }
}

// ---------------------------------------------------------------------------
// K2: X = L^{-1}, column-parallel forward substitution. grid (4, KAP).
// Output stored TRANSPOSED + PADDED: XT[c*XPS + t] = X[t][c]; cols t=200..255
// zeroed once (allows unconditional 64-lane global_load_lds in crh).
__global__ __launch_bounds__(256) void linv_kernel(const float* __restrict__ LT,
                                                   const float* __restrict__ dli_g,
                                                   float* __restrict__ XT) {
  int cb = blockIdx.x, k = blockIdx.y;
  LT += (size_t)k * PP * PP; dli_g += k * PP; XT += (size_t)k * PP * XPS;
  __shared__ float acc[PP * ACST];   // 51.2 KB slab: acc[r][i]
  __shared__ float Pn[8 * PP];       // panel: Pn[q][r] = LT[t0+q][r] = L[r][t0+q]
  __shared__ float xf[8 * ACST];
  __shared__ float dl[PP];
  const int tid = threadIdx.x;
  const int i = tid & 63, rg = tid >> 6;
  const int c = cb + 4 * i;          // owned column (valid if c < PP)
  for (int idx = tid; idx < PP * ACST; idx += 256) acc[idx] = 0.f;
  for (int r = tid; r < PP; r += 256) dl[r] = dli_g[r];
  // zero the padded tail (cols 200..255 of each owned row), once
  {
    float4 z4 = make_float4(0.f, 0.f, 0.f, 0.f);
    for (int idx = tid; idx < 50 * 14; idx += 256) {
      int il = idx / 14, f4 = idx - il * 14;
      int c2 = cb + 4 * il;   // < 200 by construction
      *(float4*)&XT[(size_t)c2 * XPS + 200 + 4 * f4] = z4;
    }
  }
  __syncthreads();
  for (int s = 0; s < 25; ++s) {
    const int t0 = 8 * s;
    for (int idx = tid; idx < 8 * PP; idx += 256) Pn[idx] = LT[t0 * PP + idx];
    __syncthreads();
    if (rg == 0) {
      float xq[8];
#pragma unroll
      for (int q = 0; q < 8; ++q) {
        int t = t0 + q;
        float sv = acc[t * ACST + i];
#pragma unroll
        for (int m = 0; m < 8; ++m)
          if (m < q) sv = __fmaf_rn(Pn[m * PP + t], xq[m], sv);
        float xv = (((t == c) ? 1.0f : 0.0f) - sv) * dl[t];
        xq[q] = xv;
        xf[q * ACST + i] = xv;
      }
    }
    __syncthreads();
    // XT store: float4 along t (t0+4*q4 .. +3) for owned columns
    if (tid < 128) {
      int q4 = tid >> 6, il = tid & 63;
      int c2 = cb + 4 * il;
      if (c2 < PP) {
        float4 v4 = make_float4(xf[(q4 * 4 + 0) * ACST + il], xf[(q4 * 4 + 1) * ACST + il],
                                xf[(q4 * 4 + 2) * ACST + il], xf[(q4 * 4 + 3) * ACST + il]);
        *(float4*)&XT[(size_t)c2 * XPS + t0 + 4 * q4] = v4;
      }
    }
    for (int r = t0 + 8 + rg; r < PP; r += 4) {
      float v = acc[r * ACST + i];
#pragma unroll
      for (int q = 0; q < 8; ++q)
        v = __fmaf_rn(Pn[q * PP + r], xf[q * ACST + i], v);
      acc[r * ACST + i] = v;
    }
    __syncthreads();
  }
}

// ---------------------------------------------------------------------------
// K6b: w = R^{-1} v = X^T (X v). X stored transposed/padded (XT[c*XPS+t]);
// summation ORDER identical (bit-identical w).
__global__ __launch_bounds__(256) void rsolve_kernel(const float* __restrict__ XT,
                                                     const float* __restrict__ v,
                                                     float* __restrict__ w) {
  int k = blockIdx.x;
  XT += (size_t)k * PP * XPS; v += k * PP; w += k * PP;
  __shared__ float vl[PP], yl[PP];
  int tid = threadIdx.x, lane = tid & 63, rg = tid >> 6;
  for (int i = tid; i < PP; i += 256) vl[i] = v[i];
  __syncthreads();
  // y = X v ; X[r][c] = XT[c*XPS+r]
  for (int r = rg; r < PP; r += 4) {
    float s = 0.f;
    for (int c = lane; c < PP; c += 64) s = __fmaf_rn(XT[(size_t)c * XPS + r], vl[c], s);
#pragma unroll
    for (int off = 32; off > 0; off >>= 1) s += __shfl_xor(s, off, 64);
    if (lane == 0) yl[r] = s;
  }
  __syncthreads();
  // w = X^T y ; X[r][tid] = XT[tid*XPS+r]
  if (tid < PP) {
    float s = 0.f;
    for (int r = 0; r < PP; ++r) s = __fmaf_rn(XT[(size_t)tid * XPS + r], yl[r], s);
    w[tid] = s;
  }
}

// ---------------------------------------------------------------------------
// K3: Crh = c_fi @ Linv^T, async B-staging; 64-row register tiles
// (acc[4][16], grid 63 x KAP) — LDS-read-throughput-bound; one b128
// a-operand feeds 64 FMAs. Bit-identical accumulation.
__global__ __launch_bounds__(256) void crh_kernel(const float* __restrict__ ths,
                                                  const float* __restrict__ thi,
                                                  const float* __restrict__ Lmb,
                                                  const float* __restrict__ XT,
                                                  const float* __restrict__ Mg,
                                                  float* __restrict__ Crh,
                                                  float* __restrict__ Dinv,
                                                  float* __restrict__ Dg) {
  int k = blockIdx.y, rt = blockIdx.x, r0 = rt * 64;
  const float* thk = ths + k * NN * DD;
  const float* XTk = XT + (size_t)k * PP * XPS;
  float* Ck = Crh + (size_t)k * NN * PP;
  __shared__ __align__(16) float ts[64 * 9];
  __shared__ __align__(16) float til[PP * DD];   // inducing pts, staged once
  __shared__ __align__(16) float At[16 * 64];
  __shared__ __align__(16) float Bt[16 * BTS];
  int tid = threadIdx.x, tx = tid & 15, ty = tid >> 4;
  const int lr = tid & 63;   // lane in wave
  const int wq = tid >> 6;   // wave id 0..3
  float lsig = Lmb[k * 9 + 8];
  for (int idx = tid; idx < 64 * DD; idx += 256) {
    int r = idx >> 3, j = idx & 7;
    int rr = r0 + r; if (rr > NN - 1) rr = NN - 1;
    ts[r * 9 + j] = thk[rr * DD + j];
  }
  for (int idx = tid; idx < PP * DD; idx += 256) til[idx] = thi[k * PP * DD + idx];
  float acc[4][16];
#pragma unroll
  for (int i = 0; i < 4; ++i)
#pragma unroll
    for (int q = 0; q < 16; ++q) acc[i][q] = 0.f;

  for (int jb = 0; jb < PP; jb += 16) {
    __syncthreads();   // prior FMA readers done; ts/til visible at jb=0
    // ---- issue async B loads: Bt[kk][lane*4..+3] <- XT[(jb+kk)*XPS + lane*4]
#pragma unroll
    for (int u = 0; u < 4; ++u) {
      int kk = wq + 4 * u;           // wave-uniform
      int row = jb + kk;
      if (row < PP)                  // wave-uniform guard
        gld_lds16(XTk + (size_t)row * XPS + lr * 4, &Bt[kk * BTS]);
      // rows >= PP keep stale data; At[kk]=0 there -> contributes exact 0
    }
    // ---- cov -> At (LDS-only; overlaps the in-flight loads) ----
    for (int idx = tid; idx < 16 * 64; idx += 256) {
      int r = idx & 63, kk = idx >> 6;
      float va = 0.f;
      int kkg = jb + kk;
      if (kkg < PP) {
        float prod = 1.f, sum = 0.f;
#pragma unroll
        for (int t = 0; t < DD; ++t) {
          float s = fabsf(ts[r * 9 + t] - til[kkg * DD + t]);
          prod = __fmaf_rn(prod, s, prod);
          sum += s;
        }
        va = prod * __expf(lsig - sum);
      }
      At[kk * 64 + r] = va;
    }
    __syncthreads();   // drains vmcnt(0): Bt ready
#pragma unroll
    for (int kk = 0; kk < 16; ++kk) {
      float4 a4 = *(const float4*)&At[kk * 64 + ty * 4];
      const float* bp = &Bt[kk * BTS + tx * 4];
      float bv[16];
      *(float4*)&bv[0]  = *(const float4*)(bp);
      *(float4*)&bv[4]  = *(const float4*)(bp + 64);
      *(float4*)&bv[8]  = *(const float4*)(bp + 128);
      *(float4*)&bv[12] = *(const float4*)(bp + 192);
      float av[4] = {a4.x, a4.y, a4.z, a4.w};
#pragma unroll
      for (int i = 0; i < 4; ++i)
#pragma unroll
        for (int q = 0; q < 16; ++q)
          acc[i][q] = __fmaf_rn(av[i], bv[q], acc[i][q]);
    }
  }
  // store: thread cols c = tx*4 + 64q (all multiples of 4; c<PP => full float4 valid)
#pragma unroll
  for (int i = 0; i < 4; ++i) {
    int r = r0 + ty * 4 + i;
    if (r < NN) {
#pragma unroll
      for (int q = 0; q < 4; ++q) {
        int c = tx * 4 + 64 * q;
        if (c < PP) {
          float4 v = make_float4(acc[i][q * 4], acc[i][q * 4 + 1], acc[i][q * 4 + 2], acc[i][q * 4 + 3]);
          *(float4*)&Ck[r * PP + c] = v;
        }
      }
    }
  }
  // ---- fused delta: per-row sumsq (cols >= PP contribute exact zeros) ----
  float ss[4];
#pragma unroll
  for (int i = 0; i < 4; ++i) {
    float s = 0.f;
#pragma unroll
    for (int q = 0; q < 16; ++q) s = __fmaf_rn(acc[i][q], acc[i][q], s);
    ss[i] = s;
  }
#pragma unroll
  for (int off = 1; off <= 8; off <<= 1) {
#pragma unroll
    for (int i = 0; i < 4; ++i) ss[i] += __shfl_xor(ss[i], off);
  }
  if (tx == 0) {
    float sig = __expf(lsig);
#pragma unroll
    for (int i = 0; i < 4; ++i) {
      int r = r0 + ty * 4 + i;
      if (r < NN) {
        float delta = fmaxf(sig * (1.f + NUGF) - ss[i], NUGF);
        float di = 1.f / delta;
        Dinv[k * NN + r] = di;
        Dg[k * NN + r] = di * Mg[(size_t)k * NN + r];
      }
    }
  }
}

// ---------------------------------------------------------------------------
// K5: R partials = Crh^T diag(Dinv) [Crh | g] over NCH K-chunks.
// 64x128 tiles; occupancy from NCH=16 (2048 blocks = 8 blocks/CU).
// XCD-GROUPING remap: all 8 tiles of a (k,kch) group land on one XCD so the
// shared 250-row Crh chunk is fetched into that XCD's L2 once. Bijective
// remap; bit-identical.
template <int NCH>
__global__ __launch_bounds__(256) void syrk_kernel(const float* __restrict__ Crh,
                                                   const float* __restrict__ Dinv,
                                                   const float* __restrict__ M,
                                                   float* __restrict__ Rp) {
  const int CH = NN / NCH;
  const int GRP_PER_XCD = (NCH * KAP) / 8;
  int lin = blockIdx.x + 8 * (blockIdx.y + NCH * blockIdx.z);
  int xcd = lin & 7, q = lin >> 3;
  int grp = xcd * GRP_PER_XCD + (q >> 3);
  int tile = q & 7;
  int k = grp / NCH, kch = grp - k * NCH;
  int it = tile >> 1, jc = tile & 1;
  int i0 = it * 64, cb = jc * 128;
  const float* Ck = Crh + (size_t)k * NN * PP;
  float* Rk = Rp + (size_t)(k * NCH + kch) * PP * RST;
  __shared__ __align__(16) float Sc[16 * 64];
  __shared__ __align__(16) float Rw[16 * 128];
  int tid = threadIdx.x, tx = tid & 15, ty = tid >> 4;
  const int kk = ty;            // staging K-row (0..15)
  const int ii4 = tx * 4;       // quad offset
  int rbase0 = kch * CH;
  const float* pA = Ck + (size_t)(rbase0 + kk) * PP + i0 + ii4;
  const float* pB = Ck + (size_t)(rbase0 + kk) * PP + cb + ii4;
  const float* pD = Dinv + (size_t)k * NN + rbase0 + kk;
  const float* pM = M + (size_t)k * NN + rbase0 + kk;
  const bool aok = (i0 + ii4 + 3 < PP);
  const int cg0 = cb + ii4, cg1 = cb + ii4 + 64;
  const bool b0f = (cg0 + 3 < PP);
  const bool b1f = (cg1 + 3 < PP);
  float4 ra, rv0, rv1;
  float acc[4][8];
#pragma unroll
  for (int i = 0; i < 4; ++i)
#pragma unroll
    for (int q2 = 0; q2 < 8; ++q2) acc[i][q2] = 0.f;

  auto stage = [&](int rb) {
    bool rok = (rb + kk < CH);
    float d = rok ? *pD : 0.f;
    if (rok && aok) {
      float4 t = *(const float4*)pA;
      ra = make_float4(t.x * d, t.y * d, t.z * d, t.w * d);
    } else ra = make_float4(0.f, 0.f, 0.f, 0.f);
    if (rok) {
      rv0 = b0f ? *(const float4*)pB : make_float4(0.f, 0.f, 0.f, 0.f);
      if (b1f) rv1 = *(const float4*)(pB + 64);
      else {
        float e[4];
#pragma unroll
        for (int u = 0; u < 4; ++u) {
          int cg = cg1 + u;
          e[u] = (cg < PP) ? pB[64 + u] : ((cg == PP) ? *pM : 0.f);
        }
        rv1 = make_float4(e[0], e[1], e[2], e[3]);
      }
    } else { rv0 = make_float4(0.f, 0.f, 0.f, 0.f); rv1 = rv0; }
    pA += 16 * PP; pB += 16 * PP; pD += 16; pM += 16;
  };
  stage(0);
  for (int rb = 0; rb < CH; rb += 16) {
    __syncthreads();
    *(float4*)&Sc[kk * 64 + ii4] = ra;
    *(float4*)&Rw[kk * 128 + ii4] = rv0;
    *(float4*)&Rw[kk * 128 + ii4 + 64] = rv1;
    __syncthreads();
    stage(rb + 16);   // overlaps with compute below (guards -> 0 past end)
#pragma unroll
    for (int kq = 0; kq < 16; ++kq) {
      float4 a4 = *(const float4*)&Sc[kq * 64 + ty * 4];
      const float* bp = &Rw[kq * 128 + tx * 4];
      float bv[8];
      *(float4*)&bv[0] = *(const float4*)(bp);
      *(float4*)&bv[4] = *(const float4*)(bp + 64);
      float av[4] = {a4.x, a4.y, a4.z, a4.w};
#pragma unroll
      for (int i = 0; i < 4; ++i)
#pragma unroll
        for (int q2 = 0; q2 < 8; ++q2)
          acc[i][q2] = __fmaf_rn(av[i], bv[q2], acc[i][q2]);
    }
  }
#pragma unroll
  for (int i = 0; i < 4; ++i) {
    int r = i0 + ty * 4 + i;
    if (r < PP) {
#pragma unroll
      for (int q2 = 0; q2 < 2; ++q2) {
        int c = cb + tx * 4 + 64 * q2;
        if (c + 3 < PP) {
          float4 v = make_float4(acc[i][q2 * 4], acc[i][q2 * 4 + 1], acc[i][q2 * 4 + 2], acc[i][q2 * 4 + 3]);
          *(float4*)&Rk[r * RST + c] = v;
        } else if (c == PP) {
          Rk[r * RST + c] = acc[i][q2 * 4];   // v column
        }
      }
    }
  }
}

// K5b: R = I + sum partials -> Afull ; v = sum partials col 200 -> Vv
template <int NCH>
__global__ void reducer_kernel(const float* __restrict__ Rp, float* __restrict__ A,
                               float* __restrict__ Vv) {
  int k = blockIdx.y;
  int idx = blockIdx.x * 256 + threadIdx.x;
  if (idx < PP * PP) {
    int i = idx / PP, j = idx - i * PP;
    float s = (i == j) ? 1.0f : 0.0f;
    for (int ch = 0; ch < NCH; ++ch) s += Rp[(size_t)((k * NCH + ch) * PP + i) * RST + j];
    A[k * PP * PP + idx] = s;
  }
  if (idx < PP) {
    float sv = 0.f;
    for (int ch = 0; ch < NCH; ++ch) sv += Rp[(size_t)((k * NCH + ch) * PP + idx) * RST + PP];
    Vv[k * PP + idx] = sv;
  }
}

// ---------------------------------------------------------------------------
// K7: Cinv_g = Dg - Dinv * (Crh @ w)
__global__ void cg_kernel(const float* __restrict__ Crh, const float* __restrict__ w,
                          const float* __restrict__ Dinv, const float* __restrict__ Dg,
                          float* __restrict__ Cg) {
  int k = blockIdx.y;
  __shared__ float ws[PP];
  for (int i = threadIdx.x; i < PP; i += 256) ws[i] = w[k * PP + i];
  __syncthreads();
  int r = blockIdx.x * 4 + (threadIdx.x >> 6);
  int lane = threadIdx.x & 63;
  const float* row = Crh + (size_t)(k * NN + r) * PP;
  float s = 0.f;
  for (int c = lane; c < PP; c += 64) s = __fmaf_rn(row[c], ws[c], s);
#pragma unroll
  for (int off = 32; off > 0; off >>= 1) s += __shfl_xor(s, off, 64);
  if (lane == 0) Cg[k * NN + r] = Dg[k * NN + r] - Dinv[k * NN + r] * s;
}

// ---------------------------------------------------------------------------
// K8: ghat partials = cov(theta0, theta) @ Cinv_g, fused cov+matvec.
// 8 row-chunks of 500 -> grid 512 = 2 blocks/CU.
__global__ __launch_bounds__(256) void pred_kernel(const float* __restrict__ th0s,
                                                   const float* __restrict__ ths,
                                                   const float* __restrict__ Lmb,
                                                   const float* __restrict__ Cg,
                                                   float* __restrict__ Gp) {
  int k = blockIdx.z, rch = blockIdx.y, it = blockIdx.x;
  int i0 = it * 256 + threadIdx.x;
  const float* t0k = th0s + k * NN0 * DD;
  const float* thk = ths + k * NN * DD;
  const float* cgk = Cg + k * NN;
  __shared__ float tsl[64 * DD];
  __shared__ float cs[64];
  float t0r[DD];
  int i0c = (i0 < NN0) ? i0 : (NN0 - 1);
#pragma unroll
  for (int j = 0; j < DD; ++j) t0r[j] = t0k[i0c * DD + j];
  float lsig = Lmb[k * 9 + 8];
  float acc = 0.f;
  int rb0 = rch * 500;
  for (int rb = 0; rb < 500; rb += 64) {
    __syncthreads();
    for (int idx = threadIdx.x; idx < 64 * DD; idx += 256) {
      int a = rb0 + rb + (idx >> 3);
      if (a > NN - 1) a = NN - 1;
      tsl[idx] = thk[a * DD + (idx & 7)];
    }
    if (threadIdx.x < 64) {
      int rrr = rb + threadIdx.x;
      cs[threadIdx.x] = (rrr < 500) ? cgk[rb0 + rrr] : 0.f;
    }
    __syncthreads();
#pragma unroll 4
    for (int rr = 0; rr < 64; ++rr) {
      float prod = 1.f, sum = 0.f;
#pragma unroll
      for (int j = 0; j < DD; ++j) {
        float s = fabsf(t0r[j] - tsl[rr * DD + j]);
        prod = __fmaf_rn(prod, s, prod);
        sum += s;
      }
      acc = __fmaf_rn(prod * __expf(lsig - sum), cs[rr], acc);
    }
  }
  if (i0 < NN0) Gp[(k * 8 + rch) * 1024 + i0] = acc;
}

// K8b: reduce ghat partials
__global__ void gred_kernel(const float* __restrict__ Gp, float* __restrict__ ghat) {
  int idx = blockIdx.x * 256 + threadIdx.x;
  if (idx >= KAP * NN0) return;
  int k = idx / NN0, i0 = idx - k * NN0;
  float s = 0.f;
  for (int ch = 0; ch < 8; ++ch) s += Gp[(k * 8 + ch) * 1024 + i0];
  ghat[idx] = s;
}

// ---------------------------------------------------------------------------
// K9: fhat = (Phi @ ghat) * Fstd + Fmean
__global__ __launch_bounds__(256) void final_kernel(const float* __restrict__ Phi,
                                                    const float* __restrict__ ghat,
                                                    const float* __restrict__ Fmean,
                                                    const float* __restrict__ Fstd,
                                                    float* __restrict__ out) {
  int it = blockIdx.y, jt = blockIdx.x;
  int i0 = it * 64, j = jt * 256 + threadIdx.x;
  __shared__ float ph[64 * KAP];
  __shared__ float fm[64], fs[64];
  for (int idx = threadIdx.x; idx < 64 * KAP; idx += 256) {
    int i = idx >> 4, kk = idx & 15;
    int ii = i0 + i; if (ii > MMR - 1) ii = MMR - 1;
    ph[idx] = Phi[ii * KAP + kk];
  }
  if (threadIdx.x < 64) {
    int ii = i0 + threadIdx.x; if (ii > MMR - 1) ii = MMR - 1;
    fm[threadIdx.x] = Fmean[ii];
    fs[threadIdx.x] = Fstd[ii];
  }
  float gj[KAP];
#pragma unroll
  for (int kk = 0; kk < KAP; ++kk) gj[kk] = (j < NN0) ? ghat[kk * NN0 + j] : 0.f;
  __syncthreads();
  if (j < NN0) {
    for (int i = 0; i < 64; ++i) {
      int ii = i0 + i;
      if (ii >= MMR) break;
      float s = 0.f;
#pragma unroll
      for (int kk = 0; kk < KAP; ++kk) s = __fmaf_rn(ph[i * KAP + kk], gj[kk], s);
      out[(size_t)ii * NN0 + j] = __fmaf_rn(s, fs[i], fm[i]);
    }
  }
}

// ---------------------------------------------------------------------------
extern "C" void kernel_launch(void* const* d_in, const int* in_sizes, int n_in,
                              void* d_out, int out_size, void* d_ws, size_t ws_size,
                              hipStream_t stream) {
  const float* theta0 = (const float*)d_in[0];
  const float* Lmb    = (const float*)d_in[1];
  // d_in[2] = lsigma2 (unused by reference output)
  const float* Phi    = (const float*)d_in[3];
  const float* theta  = (const float*)d_in[4];
  const float* thetai = (const float*)d_in[5];
  const float* M      = (const float*)d_in[6];
  const float* Fmean  = (const float*)d_in[7];
  const float* Fstd   = (const float*)d_in[8];
  float* out = (float*)d_out;
  float* ws = (float*)d_ws;

  float* ths   = ws + OFF_THS;
  float* thi   = ws + OFF_THI;
  float* th0s  = ws + OFF_TH0S;
  float* Afull = ws + OFF_AFULL;
  float* LT    = ws + OFF_LT;
  float* Xt    = ws + OFF_XT;     // padded XT (stride XPS), in LROW+XB region
  float* dli   = ws + OFF_DLI;
  float* Crh   = ws + OFF_CRH;
  float* Dinv  = ws + OFF_DINV;
  float* Dg    = ws + OFF_DG;
  float* Vv    = ws + OFF_VV;
  float* Wv    = ws + OFF_WV;
  float* Cg    = ws + OFF_CG;
  float* Gpart = ws + OFF_GPART;
  float* ghat  = ws + OFF_GHAT;
  float* Rpart = ws + OFF_RPART;

  // choose syrk K-chunk count by available workspace (16 -> 8 blocks/CU grid)
  size_t need16 = ((size_t)OFF_RPART + (size_t)KAP * 16 * PP * RST) * sizeof(float);
  size_t need8  = ((size_t)OFF_RPART + (size_t)KAP * 8  * PP * RST) * sizeof(float);
  int nch = (ws_size >= need16) ? 16 : ((ws_size >= need8) ? 8 : 4);

  scale_kernel<<<dim3(163, KAP), 256, 0, stream>>>(theta, thetai, theta0, Lmb, ths, thi, th0s);
  buildci_kernel<<<KAP, 256, 0, stream>>>(thi, Lmb, Afull);
  chol_kernel<<<KAP, 1024, 0, stream>>>(Afull, LT, dli);
  linv_kernel<<<dim3(4, KAP), 256, 0, stream>>>(LT, dli, Xt);
  crh_kernel<<<dim3(63, KAP), 256, 0, stream>>>(ths, thi, Lmb, Xt, M, Crh, Dinv, Dg);
  if (nch == 16) {
    syrk_kernel<16><<<dim3(8, 16, KAP), 256, 0, stream>>>(Crh, Dinv, M, Rpart);
    reducer_kernel<16><<<dim3(157, KAP), 256, 0, stream>>>(Rpart, Afull, Vv);
  } else if (nch == 8) {
    syrk_kernel<8><<<dim3(8, 8, KAP), 256, 0, stream>>>(Crh, Dinv, M, Rpart);
    reducer_kernel<8><<<dim3(157, KAP), 256, 0, stream>>>(Rpart, Afull, Vv);
  } else {
    syrk_kernel<4><<<dim3(8, 4, KAP), 256, 0, stream>>>(Crh, Dinv, M, Rpart);
    reducer_kernel<4><<<dim3(157, KAP), 256, 0, stream>>>(Rpart, Afull, Vv);
  }
  chol_kernel<<<KAP, 1024, 0, stream>>>(Afull, LT, dli);        // Cholesky of R
  linv_kernel<<<dim3(4, KAP), 256, 0, stream>>>(LT, dli, Xt);   // X_R = L_R^{-1} (transposed/padded)
  rsolve_kernel<<<KAP, 256, 0, stream>>>(Xt, Vv, Wv);           // w = X^T X v
  cg_kernel<<<dim3(1000, KAP), 256, 0, stream>>>(Crh, Wv, Dinv, Dg, Cg);
  pred_kernel<<<dim3(4, 8, KAP), 256, 0, stream>>>(th0s, ths, Lmb, Cg, Gpart);
  gred_kernel<<<63, 256, 0, stream>>>(Gpart, ghat);
  final_kernel<<<dim3(4, 188), 256, 0, stream>>>(Phi, ghat, Fmean, Fstd, out);
}

// Round 12
// 704.933 us; speedup vs baseline: 1.1355x; 1.0041x over previous
//
#include <hip/hip_runtime.h>

// Problem constants (fixed by setup_inputs)
#define NN   4000
#define PP   200
#define DD   8
#define KAP  16
#define NN0  1000
#define MMR  12000
#define NUGF 1e-6f

// Rpart row stride (200 R cols + 1 v col + pad)
#define RST  204
// linv slab col stride
#define ACST 64
// chol: panel-transpose LDS row stride (floats), tile count of 50x50 lower tri
#define PTS   208
#define NTILE 1275
// crh Bt row stride
#define BTS  260
// XT padded row stride (cols 200..255 zeroed once -> async 64-lane loads safe)
#define XPS  256

// ---- workspace layout (float offsets); RPART last (variable size) ----
#define OFF_THS    0
#define OFF_THI    (OFF_THS   + KAP*NN*DD)
#define OFF_TH0S   (OFF_THI   + KAP*PP*DD)
#define OFF_AFULL  (OFF_TH0S  + KAP*NN0*DD)
#define OFF_LT     (OFF_AFULL + KAP*PP*PP)
#define OFF_LROW   (OFF_LT    + KAP*PP*PP)
#define OFF_XB     (OFF_LROW  + KAP*PP*PP)
#define OFF_DLI    (OFF_XB    + KAP*PP*PP)
#define OFF_CRH    (OFF_DLI   + KAP*PP)
#define OFF_DINV   (OFF_CRH   + KAP*NN*PP)
#define OFF_DG     (OFF_DINV  + KAP*NN)
#define OFF_VV     (OFF_DG    + KAP*NN)
#define OFF_WV     (OFF_VV    + KAP*PP)
#define OFF_CG     (OFF_WV    + KAP*PP)
#define OFF_GPART  (OFF_CG    + KAP*NN)
#define OFF_GHAT   (OFF_GPART + KAP*8*1024)
#define OFF_RPART  (OFF_GHAT  + KAP*NN0)
// XT (padded, KAP*PP*XPS = 819200 floats) lives in the LROW+XB region (1.28M floats)
#define OFF_XT     OFF_LROW
// need(NCH) = OFF_RPART + KAP*NCH*PP*RST floats

// async global->LDS, 16B per lane; LDS base must be wave-uniform
__device__ __forceinline__ void gld_lds16(const float* g, float* l) {
  __builtin_amdgcn_global_load_lds(
      (const __attribute__((address_space(1))) unsigned int*)g,
      (__attribute__((address_space(3))) unsigned int*)l, 16, 0, 0);
}

// ---------------------------------------------------------------------------
// K0: per-k scaled inputs  x / exp(lmb_j)
__global__ void scale_kernel(const float* __restrict__ theta, const float* __restrict__ thetai,
                             const float* __restrict__ theta0, const float* __restrict__ Lmb,
                             float* __restrict__ ths, float* __restrict__ thi, float* __restrict__ th0s) {
  int k = blockIdx.y;
  int idx = blockIdx.x * 256 + threadIdx.x;
  const int total = (NN + PP + NN0) * DD;
  if (idx >= total) return;
  int row = idx >> 3, j = idx & 7;
  float ils = __expf(-Lmb[k * 9 + j]);
  if (row < NN) {
    ths[(k * NN + row) * DD + j] = theta[row * DD + j] * ils;
  } else if (row < NN + PP) {
    int r = row - NN;
    thi[(k * PP + r) * DD + j] = thetai[r * DD + j] * ils;
  } else {
    int r = row - NN - PP;
    th0s[(k * NN0 + r) * DD + j] = theta0[r * DD + j] * ils;
  }
}

// ---------------------------------------------------------------------------
// K0b: build C_i (full symmetric) per k into Afull
__global__ void buildci_kernel(const float* __restrict__ thi, const float* __restrict__ Lmb,
                               float* __restrict__ A) {
  int k = blockIdx.x;
  __shared__ float ti[PP * DD];
  for (int i = threadIdx.x; i < PP * DD; i += 256) ti[i] = thi[k * PP * DD + i];
  __syncthreads();
  float lsig = Lmb[k * 9 + 8];
  float* Ak = A + k * PP * PP;
  for (int idx = threadIdx.x; idx < PP * PP; idx += 256) {
    int i = idx / PP, j = idx - i * PP;
    float prod = 1.f, sum = 0.f;
#pragma unroll
    for (int t = 0; t < DD; ++t) {
      float s = fabsf(ti[i * DD + t] - ti[j * DD + t]);
      prod = __fmaf_rn(prod, s, prod);  // prod *= (1+s)
      sum += s;
    }
    float val = prod * __expf(lsig - sum);
    if (i == j) val += NUGF * __expf(lsig);
    Ak[idx] = val;
  }
}

// ---------------------------------------------------------------------------
// K1/K6: Cholesky of a 200x200 SPD matrix, REGISTER-resident trailing matrix.
// v3: SPILL-PROOF panel factorization (8x8 diag in 8 regs by lanes 0-7, body
// rows thread-parallel vs LDS factor). Bit-identical LT/dli.
__device__ __forceinline__ float rdlane(float v, int l) {
  return __int_as_float(__builtin_amdgcn_readlane(__float_as_int(v), l));
}

__global__ __launch_bounds__(1024)
void chol_kernel(const float* __restrict__ Ain,
                 float* __restrict__ LT,
                 float* __restrict__ dli) {
  int k = blockIdx.x;
  Ain += (size_t)k * PP * PP; LT += (size_t)k * PP * PP; dli += (size_t)k * PP;
  __shared__ __align__(16) float Ppre[8 * PTS];  // staged panel, [q][r] absolute r
  __shared__ __align__(16) float Pt[8 * PTS];    // factorized panel, [q][r]
  __shared__ float l8[64];                        // 8x8 diag factor, l8[r*8+c]
  __shared__ float invs[8];                       // 1/diag for this panel
  const int tid = threadIdx.x;

  // ---- decode owned tiles (row-tile-major lower triangle), load to regs ----
  int t_rt[2], t_ct[2];
  bool t_ok[2];
  float4 acc[2][4];
#pragma unroll
  for (int t = 0; t < 2; ++t) {
    int ti = (tid - 64) + t * 960;
    t_ok[t] = (tid >= 64) && (ti < NTILE);
    int tie = t_ok[t] ? ti : 0;
    int rt = (int)((sqrtf(8.0f * (float)tie + 1.0f) - 1.0f) * 0.5f);
    while ((rt + 1) * (rt + 2) / 2 <= tie) ++rt;
    while (rt * (rt + 1) / 2 > tie) --rt;
    int ct = tie - rt * (rt + 1) / 2;
    t_rt[t] = rt; t_ct[t] = ct;
    if (t_ok[t]) {
      const float* src = Ain + (size_t)(4 * rt) * PP + 4 * ct;
#pragma unroll
      for (int i = 0; i < 4; ++i) acc[t][i] = *(const float4*)(src + (size_t)i * PP);
    } else {
#pragma unroll
      for (int i = 0; i < 4; ++i) acc[t][i] = make_float4(0.f, 0.f, 0.f, 0.f);
    }
  }

  for (int s = 0; s < 25; ++s) {
    const int jb = 8 * s;
    // ---- owners of the two panel tile-columns stage them to LDS ----
#pragma unroll
    for (int t = 0; t < 2; ++t) {
      if (t_ok[t] && (t_ct[t] >> 1) == s) {
        int q0 = 4 * t_ct[t] - jb;   // 0 or 4
        int r0 = 4 * t_rt[t];
#pragma unroll
        for (int i = 0; i < 4; ++i) {
          Ppre[(q0 + 0) * PTS + r0 + i] = acc[t][i].x;
          Ppre[(q0 + 1) * PTS + r0 + i] = acc[t][i].y;
          Ppre[(q0 + 2) * PTS + r0 + i] = acc[t][i].z;
          Ppre[(q0 + 3) * PTS + r0 + i] = acc[t][i].w;
        }
      }
    }
    __syncthreads();
    const int nrows = PP - jb;
    // ---- lanes 0-7: factorize the 8x8 diagonal block (8 regs, rdlane) ----
    if (tid < 8) {
      const int r = tid;
      float e[8];
#pragma unroll
      for (int c = 0; c < 8; ++c)
        e[c] = (r >= c) ? Ppre[c * PTS + jb + r] : 0.f;
#pragma unroll
      for (int jj = 0; jj < 8; ++jj) {
        float dv = rdlane(e[jj], jj);
        float l = sqrtf(fmaxf(dv, 1e-12f));
        float inv = 1.0f / l;
        if (r > jj) e[jj] *= inv;
        if (r == jj) { e[jj] = l; dli[jb + jj] = inv; invs[jj] = inv; }
#pragma unroll
        for (int c = jj + 1; c < 8; ++c) {
          float pc = rdlane(e[jj], c);
          e[c] = __fmaf_rn(-e[jj], pc, e[c]);
        }
      }
      // publish factor + diag-block LT
#pragma unroll
      for (int c = 0; c < 8; ++c) {
        l8[r * 8 + c] = e[c];
        if (r >= c) LT[(jb + c) * PP + jb + r] = e[c];
      }
    }
    __syncthreads();
    // ---- body rows (thread-parallel): forward-solve vs the 8x8 factor ----
    {
      int rl = 8 + tid;
      if (tid < nrows - 8) {
        float row[8];
#pragma unroll
        for (int c = 0; c < 8; ++c) row[c] = Ppre[c * PTS + jb + rl];
#pragma unroll
        for (int jj = 0; jj < 8; ++jj) {
          float v = row[jj] * invs[jj];
          row[jj] = v;
#pragma unroll
          for (int c = jj + 1; c < 8; ++c)
            row[c] = __fmaf_rn(-v, l8[c * 8 + jj], row[c]);
        }
#pragma unroll
        for (int c = 0; c < 8; ++c) {
          Pt[c * PTS + jb + rl] = row[c];
          LT[(jb + c) * PP + jb + rl] = row[c];
        }
      }
    }
    __syncthreads();
    // ---- rank-8 trailing update on register tiles (reads Pt rows >= jb+8) --
    const int ctmin = 2 * s + 2;
#pragma unroll
    for (int t = 0; t < 2; ++t) {
      if (t_ok[t] && t_ct[t] >= ctmin) {
        const float* pr = Pt + 4 * t_rt[t];
        const float* pcl = Pt + 4 * t_ct[t];
#pragma unroll
        for (int q = 0; q < 8; ++q) {
          float4 a = *(const float4*)(pr + q * PTS);   // broadcast within wave
          float4 b = *(const float4*)(pcl + q * PTS);  // consecutive float4s
          acc[t][0].x = __fmaf_rn(-a.x, b.x, acc[t][0].x);
          acc[t][0].y = __fmaf_rn(-a.x, b.y, acc[t][0].y);
          acc[t][0].z = __fmaf_rn(-a.x, b.z, acc[t][0].z);
          acc[t][0].w = __fmaf_rn(-a.x, b.w, acc[t][0].w);
          acc[t][1].x = __fmaf_rn(-a.y, b.x, acc[t][1].x);
          acc[t][1].y = __fmaf_rn(-a.y, b.y, acc[t][1].y);
          acc[t][1].z = __fmaf_rn(-a.y, b.z, acc[t][1].z);
          acc[t][1].w = __fmaf_rn(-a.y, b.w, acc[t][1].w);
          acc[t][2].x = __fmaf_rn(-a.z, b.x, acc[t][2].x);
          acc[t][2].y = __fmaf_rn(-a.z, b.y, acc[t][2].y);
          acc[t][2].z = __fmaf_rn(-a.z, b.z, acc[t][2].z);
          acc[t][2].w = __fmaf_rn(-a.z, b.w, acc[t][2].w);
          acc[t][3].x = __fmaf_rn(-a.w, b.x, acc[t][3].x);
          acc[t][3].y = __fmaf_rn(-a.w, b.y, acc[t][3].y);
          acc[t][3].z = __fmaf_rn(-a.w, b.z, acc[t][3].z);
          acc[t][3].w = __fmaf_rn(-a.w, b.w, acc[t][3].w);
        }
      }
    }
  }
}

// ---------------------------------------------------------------------------
// K2: X = L^{-1}, column-parallel forward substitution. grid (4, KAP).
// Output stored TRANSPOSED + PADDED: XT[c*XPS + t] = X[t][c].
// v3: LDS-INSTRUCTION-COUNT cut (round-11 model: 18 LDS ops/row in the
// trailing update = 10K LDS-pipe cycles/step = the measured 114us at
// 1 block/CU). (1) Panel staged TRANSPOSED Pn2[r][8] (global reads stay
// 32B-contiguous per 8-lane group) -> per-row Pn access = 2 uniform
// ds_read_b128 (was 8 scalar); (2) xf hoisted to 8 regs once per step
// (was 8 reads/row); (3) acc prefetched ahead of the serial xq chain.
// Per-row LDS ops 18 -> 4. Values & FMA order unchanged (Pn[m*PP+t] ==
// Pn2[t*8+m]) -> bit-identical X.
__global__ __launch_bounds__(256) void linv_kernel(const float* __restrict__ LT,
                                                   const float* __restrict__ dli_g,
                                                   float* __restrict__ XT) {
  int cb = blockIdx.x, k = blockIdx.y;
  LT += (size_t)k * PP * PP; dli_g += k * PP; XT += (size_t)k * PP * XPS;
  __shared__ float acc[PP * ACST];            // 51.2 KB slab: acc[r][i]
  __shared__ __align__(16) float Pn2[PP * 8]; // panel transposed: Pn2[r*8+q] = L[r][t0+q]
  __shared__ float xf[8 * ACST];
  __shared__ float dl[PP];
  const int tid = threadIdx.x;
  const int i = tid & 63, rg = tid >> 6;
  const int c = cb + 4 * i;          // owned column (valid if c < PP)
  for (int idx = tid; idx < PP * ACST; idx += 256) acc[idx] = 0.f;
  for (int r = tid; r < PP; r += 256) dl[r] = dli_g[r];
  // zero the padded tail (cols 200..255 of each owned row), once
  {
    float4 z4 = make_float4(0.f, 0.f, 0.f, 0.f);
    for (int idx = tid; idx < 50 * 14; idx += 256) {
      int il = idx / 14, f4 = idx - il * 14;
      int c2 = cb + 4 * il;   // < 200 by construction
      *(float4*)&XT[(size_t)c2 * XPS + 200 + 4 * f4] = z4;
    }
  }
  __syncthreads();
  for (int s = 0; s < 25; ++s) {
    const int t0 = 8 * s;
    // stage transposed: Pn2[r*8+q] = LT[(t0+q)*PP + r]
    // (8-lane groups read 32B-contiguous r-runs of one row -> good segments)
    for (int idx = tid; idx < 8 * PP; idx += 256) {
      int r = idx >> 3, q = idx & 7;
      Pn2[idx] = LT[(t0 + q) * PP + r];
    }
    __syncthreads();
    if (rg == 0) {
      float sv0[8];
#pragma unroll
      for (int q = 0; q < 8; ++q) sv0[q] = acc[(t0 + q) * ACST + i];
      float xq[8];
#pragma unroll
      for (int q = 0; q < 8; ++q) {
        int t = t0 + q;
        float pn[8];
        *(float4*)&pn[0] = *(const float4*)&Pn2[t * 8];
        *(float4*)&pn[4] = *(const float4*)&Pn2[t * 8 + 4];
        float sv = sv0[q];
#pragma unroll
        for (int m = 0; m < 8; ++m)
          if (m < q) sv = __fmaf_rn(pn[m], xq[m], sv);
        float xv = (((t == c) ? 1.0f : 0.0f) - sv) * dl[t];
        xq[q] = xv;
        xf[q * ACST + i] = xv;
      }
    }
    __syncthreads();
    // XT store: float4 along t (t0+4*q4 .. +3) for owned columns
    if (tid < 128) {
      int q4 = tid >> 6, il = tid & 63;
      int c2 = cb + 4 * il;
      if (c2 < PP) {
        float4 v4 = make_float4(xf[(q4 * 4 + 0) * ACST + il], xf[(q4 * 4 + 1) * ACST + il],
                                xf[(q4 * 4 + 2) * ACST + il], xf[(q4 * 4 + 3) * ACST + il]);
        *(float4*)&XT[(size_t)c2 * XPS + t0 + 4 * q4] = v4;
      }
    }
    // trailing: xf hoisted; per row 2 uniform b128 + acc r/w
    {
      float xr[8];
#pragma unroll
      for (int q = 0; q < 8; ++q) xr[q] = xf[q * ACST + i];
      for (int r = t0 + 8 + rg; r < PP; r += 4) {
        float pn[8];
        *(float4*)&pn[0] = *(const float4*)&Pn2[r * 8];
        *(float4*)&pn[4] = *(const float4*)&Pn2[r * 8 + 4];
        float v = acc[r * ACST + i];
#pragma unroll
        for (int q = 0; q < 8; ++q)
          v = __fmaf_rn(pn[q], xr[q], v);
        acc[r * ACST + i] = v;
      }
    }
    __syncthreads();
  }
}

// ---------------------------------------------------------------------------
// K6b: w = R^{-1} v = X^T (X v). X stored transposed/padded (XT[c*XPS+t]);
// summation ORDER identical (bit-identical w).
__global__ __launch_bounds__(256) void rsolve_kernel(const float* __restrict__ XT,
                                                     const float* __restrict__ v,
                                                     float* __restrict__ w) {
  int k = blockIdx.x;
  XT += (size_t)k * PP * XPS; v += k * PP; w += k * PP;
  __shared__ float vl[PP], yl[PP];
  int tid = threadIdx.x, lane = tid & 63, rg = tid >> 6;
  for (int i = tid; i < PP; i += 256) vl[i] = v[i];
  __syncthreads();
  // y = X v ; X[r][c] = XT[c*XPS+r]
  for (int r = rg; r < PP; r += 4) {
    float s = 0.f;
    for (int c = lane; c < PP; c += 64) s = __fmaf_rn(XT[(size_t)c * XPS + r], vl[c], s);
#pragma unroll
    for (int off = 32; off > 0; off >>= 1) s += __shfl_xor(s, off, 64);
    if (lane == 0) yl[r] = s;
  }
  __syncthreads();
  // w = X^T y ; X[r][tid] = XT[tid*XPS+r]
  if (tid < PP) {
    float s = 0.f;
    for (int r = 0; r < PP; ++r) s = __fmaf_rn(XT[(size_t)tid * XPS + r], yl[r], s);
    w[tid] = s;
  }
}

// ---------------------------------------------------------------------------
// K3: Crh = c_fi @ Linv^T, async B-staging; 64-row register tiles
// (acc[4][16], grid 63 x KAP) — LDS-read-throughput-bound; one b128
// a-operand feeds 64 FMAs. Bit-identical accumulation.
__global__ __launch_bounds__(256) void crh_kernel(const float* __restrict__ ths,
                                                  const float* __restrict__ thi,
                                                  const float* __restrict__ Lmb,
                                                  const float* __restrict__ XT,
                                                  const float* __restrict__ Mg,
                                                  float* __restrict__ Crh,
                                                  float* __restrict__ Dinv,
                                                  float* __restrict__ Dg) {
  int k = blockIdx.y, rt = blockIdx.x, r0 = rt * 64;
  const float* thk = ths + k * NN * DD;
  const float* XTk = XT + (size_t)k * PP * XPS;
  float* Ck = Crh + (size_t)k * NN * PP;
  __shared__ __align__(16) float ts[64 * 9];
  __shared__ __align__(16) float til[PP * DD];   // inducing pts, staged once
  __shared__ __align__(16) float At[16 * 64];
  __shared__ __align__(16) float Bt[16 * BTS];
  int tid = threadIdx.x, tx = tid & 15, ty = tid >> 4;
  const int lr = tid & 63;   // lane in wave
  const int wq = tid >> 6;   // wave id 0..3
  float lsig = Lmb[k * 9 + 8];
  for (int idx = tid; idx < 64 * DD; idx += 256) {
    int r = idx >> 3, j = idx & 7;
    int rr = r0 + r; if (rr > NN - 1) rr = NN - 1;
    ts[r * 9 + j] = thk[rr * DD + j];
  }
  for (int idx = tid; idx < PP * DD; idx += 256) til[idx] = thi[k * PP * DD + idx];
  float acc[4][16];
#pragma unroll
  for (int i = 0; i < 4; ++i)
#pragma unroll
    for (int q = 0; q < 16; ++q) acc[i][q] = 0.f;

  for (int jb = 0; jb < PP; jb += 16) {
    __syncthreads();   // prior FMA readers done; ts/til visible at jb=0
    // ---- issue async B loads: Bt[kk][lane*4..+3] <- XT[(jb+kk)*XPS + lane*4]
#pragma unroll
    for (int u = 0; u < 4; ++u) {
      int kk = wq + 4 * u;           // wave-uniform
      int row = jb + kk;
      if (row < PP)                  // wave-uniform guard
        gld_lds16(XTk + (size_t)row * XPS + lr * 4, &Bt[kk * BTS]);
      // rows >= PP keep stale data; At[kk]=0 there -> contributes exact 0
    }
    // ---- cov -> At (LDS-only; overlaps the in-flight loads) ----
    for (int idx = tid; idx < 16 * 64; idx += 256) {
      int r = idx & 63, kk = idx >> 6;
      float va = 0.f;
      int kkg = jb + kk;
      if (kkg < PP) {
        float prod = 1.f, sum = 0.f;
#pragma unroll
        for (int t = 0; t < DD; ++t) {
          float s = fabsf(ts[r * 9 + t] - til[kkg * DD + t]);
          prod = __fmaf_rn(prod, s, prod);
          sum += s;
        }
        va = prod * __expf(lsig - sum);
      }
      At[kk * 64 + r] = va;
    }
    __syncthreads();   // drains vmcnt(0): Bt ready
#pragma unroll
    for (int kk = 0; kk < 16; ++kk) {
      float4 a4 = *(const float4*)&At[kk * 64 + ty * 4];
      const float* bp = &Bt[kk * BTS + tx * 4];
      float bv[16];
      *(float4*)&bv[0]  = *(const float4*)(bp);
      *(float4*)&bv[4]  = *(const float4*)(bp + 64);
      *(float4*)&bv[8]  = *(const float4*)(bp + 128);
      *(float4*)&bv[12] = *(const float4*)(bp + 192);
      float av[4] = {a4.x, a4.y, a4.z, a4.w};
#pragma unroll
      for (int i = 0; i < 4; ++i)
#pragma unroll
        for (int q = 0; q < 16; ++q)
          acc[i][q] = __fmaf_rn(av[i], bv[q], acc[i][q]);
    }
  }
  // store: thread cols c = tx*4 + 64q (all multiples of 4; c<PP => full float4 valid)
#pragma unroll
  for (int i = 0; i < 4; ++i) {
    int r = r0 + ty * 4 + i;
    if (r < NN) {
#pragma unroll
      for (int q = 0; q < 4; ++q) {
        int c = tx * 4 + 64 * q;
        if (c < PP) {
          float4 v = make_float4(acc[i][q * 4], acc[i][q * 4 + 1], acc[i][q * 4 + 2], acc[i][q * 4 + 3]);
          *(float4*)&Ck[r * PP + c] = v;
        }
      }
    }
  }
  // ---- fused delta: per-row sumsq (cols >= PP contribute exact zeros) ----
  float ss[4];
#pragma unroll
  for (int i = 0; i < 4; ++i) {
    float s = 0.f;
#pragma unroll
    for (int q = 0; q < 16; ++q) s = __fmaf_rn(acc[i][q], acc[i][q], s);
    ss[i] = s;
  }
#pragma unroll
  for (int off = 1; off <= 8; off <<= 1) {
#pragma unroll
    for (int i = 0; i < 4; ++i) ss[i] += __shfl_xor(ss[i], off);
  }
  if (tx == 0) {
    float sig = __expf(lsig);
#pragma unroll
    for (int i = 0; i < 4; ++i) {
      int r = r0 + ty * 4 + i;
      if (r < NN) {
        float delta = fmaxf(sig * (1.f + NUGF) - ss[i], NUGF);
        float di = 1.f / delta;
        Dinv[k * NN + r] = di;
        Dg[k * NN + r] = di * Mg[(size_t)k * NN + r];
      }
    }
  }
}

// ---------------------------------------------------------------------------
// K5: R partials = Crh^T diag(Dinv) [Crh | g] over NCH K-chunks.
// 64x128 tiles; occupancy from NCH=16 (2048 blocks = 8 blocks/CU).
// XCD-GROUPING remap: all 8 tiles of a (k,kch) group land on one XCD so the
// shared 250-row Crh chunk is fetched into that XCD's L2 once. Bijective
// remap; bit-identical.
template <int NCH>
__global__ __launch_bounds__(256) void syrk_kernel(const float* __restrict__ Crh,
                                                   const float* __restrict__ Dinv,
                                                   const float* __restrict__ M,
                                                   float* __restrict__ Rp) {
  const int CH = NN / NCH;
  const int GRP_PER_XCD = (NCH * KAP) / 8;
  int lin = blockIdx.x + 8 * (blockIdx.y + NCH * blockIdx.z);
  int xcd = lin & 7, q = lin >> 3;
  int grp = xcd * GRP_PER_XCD + (q >> 3);
  int tile = q & 7;
  int k = grp / NCH, kch = grp - k * NCH;
  int it = tile >> 1, jc = tile & 1;
  int i0 = it * 64, cb = jc * 128;
  const float* Ck = Crh + (size_t)k * NN * PP;
  float* Rk = Rp + (size_t)(k * NCH + kch) * PP * RST;
  __shared__ __align__(16) float Sc[16 * 64];
  __shared__ __align__(16) float Rw[16 * 128];
  int tid = threadIdx.x, tx = tid & 15, ty = tid >> 4;
  const int kk = ty;            // staging K-row (0..15)
  const int ii4 = tx * 4;       // quad offset
  int rbase0 = kch * CH;
  const float* pA = Ck + (size_t)(rbase0 + kk) * PP + i0 + ii4;
  const float* pB = Ck + (size_t)(rbase0 + kk) * PP + cb + ii4;
  const float* pD = Dinv + (size_t)k * NN + rbase0 + kk;
  const float* pM = M + (size_t)k * NN + rbase0 + kk;
  const bool aok = (i0 + ii4 + 3 < PP);
  const int cg0 = cb + ii4, cg1 = cb + ii4 + 64;
  const bool b0f = (cg0 + 3 < PP);
  const bool b1f = (cg1 + 3 < PP);
  float4 ra, rv0, rv1;
  float acc[4][8];
#pragma unroll
  for (int i = 0; i < 4; ++i)
#pragma unroll
    for (int q2 = 0; q2 < 8; ++q2) acc[i][q2] = 0.f;

  auto stage = [&](int rb) {
    bool rok = (rb + kk < CH);
    float d = rok ? *pD : 0.f;
    if (rok && aok) {
      float4 t = *(const float4*)pA;
      ra = make_float4(t.x * d, t.y * d, t.z * d, t.w * d);
    } else ra = make_float4(0.f, 0.f, 0.f, 0.f);
    if (rok) {
      rv0 = b0f ? *(const float4*)pB : make_float4(0.f, 0.f, 0.f, 0.f);
      if (b1f) rv1 = *(const float4*)(pB + 64);
      else {
        float e[4];
#pragma unroll
        for (int u = 0; u < 4; ++u) {
          int cg = cg1 + u;
          e[u] = (cg < PP) ? pB[64 + u] : ((cg == PP) ? *pM : 0.f);
        }
        rv1 = make_float4(e[0], e[1], e[2], e[3]);
      }
    } else { rv0 = make_float4(0.f, 0.f, 0.f, 0.f); rv1 = rv0; }
    pA += 16 * PP; pB += 16 * PP; pD += 16; pM += 16;
  };
  stage(0);
  for (int rb = 0; rb < CH; rb += 16) {
    __syncthreads();
    *(float4*)&Sc[kk * 64 + ii4] = ra;
    *(float4*)&Rw[kk * 128 + ii4] = rv0;
    *(float4*)&Rw[kk * 128 + ii4 + 64] = rv1;
    __syncthreads();
    stage(rb + 16);   // overlaps with compute below (guards -> 0 past end)
#pragma unroll
    for (int kq = 0; kq < 16; ++kq) {
      float4 a4 = *(const float4*)&Sc[kq * 64 + ty * 4];
      const float* bp = &Rw[kq * 128 + tx * 4];
      float bv[8];
      *(float4*)&bv[0] = *(const float4*)(bp);
      *(float4*)&bv[4] = *(const float4*)(bp + 64);
      float av[4] = {a4.x, a4.y, a4.z, a4.w};
#pragma unroll
      for (int i = 0; i < 4; ++i)
#pragma unroll
        for (int q2 = 0; q2 < 8; ++q2)
          acc[i][q2] = __fmaf_rn(av[i], bv[q2], acc[i][q2]);
    }
  }
#pragma unroll
  for (int i = 0; i < 4; ++i) {
    int r = i0 + ty * 4 + i;
    if (r < PP) {
#pragma unroll
      for (int q2 = 0; q2 < 2; ++q2) {
        int c = cb + tx * 4 + 64 * q2;
        if (c + 3 < PP) {
          float4 v = make_float4(acc[i][q2 * 4], acc[i][q2 * 4 + 1], acc[i][q2 * 4 + 2], acc[i][q2 * 4 + 3]);
          *(float4*)&Rk[r * RST + c] = v;
        } else if (c == PP) {
          Rk[r * RST + c] = acc[i][q2 * 4];   // v column
        }
      }
    }
  }
}

// K5b: R = I + sum partials -> Afull ; v = sum partials col 200 -> Vv
template <int NCH>
__global__ void reducer_kernel(const float* __restrict__ Rp, float* __restrict__ A,
                               float* __restrict__ Vv) {
  int k = blockIdx.y;
  int idx = blockIdx.x * 256 + threadIdx.x;
  if (idx < PP * PP) {
    int i = idx / PP, j = idx - i * PP;
    float s = (i == j) ? 1.0f : 0.0f;
    for (int ch = 0; ch < NCH; ++ch) s += Rp[(size_t)((k * NCH + ch) * PP + i) * RST + j];
    A[k * PP * PP + idx] = s;
  }
  if (idx < PP) {
    float sv = 0.f;
    for (int ch = 0; ch < NCH; ++ch) sv += Rp[(size_t)((k * NCH + ch) * PP + idx) * RST + PP];
    Vv[k * PP + idx] = sv;
  }
}

// ---------------------------------------------------------------------------
// K7: Cinv_g = Dg - Dinv * (Crh @ w)
__global__ void cg_kernel(const float* __restrict__ Crh, const float* __restrict__ w,
                          const float* __restrict__ Dinv, const float* __restrict__ Dg,
                          float* __restrict__ Cg) {
  int k = blockIdx.y;
  __shared__ float ws[PP];
  for (int i = threadIdx.x; i < PP; i += 256) ws[i] = w[k * PP + i];
  __syncthreads();
  int r = blockIdx.x * 4 + (threadIdx.x >> 6);
  int lane = threadIdx.x & 63;
  const float* row = Crh + (size_t)(k * NN + r) * PP;
  float s = 0.f;
  for (int c = lane; c < PP; c += 64) s = __fmaf_rn(row[c], ws[c], s);
#pragma unroll
  for (int off = 32; off > 0; off >>= 1) s += __shfl_xor(s, off, 64);
  if (lane == 0) Cg[k * NN + r] = Dg[k * NN + r] - Dinv[k * NN + r] * s;
}

// ---------------------------------------------------------------------------
// K8: ghat partials = cov(theta0, theta) @ Cinv_g, fused cov+matvec.
// 8 row-chunks of 500 -> grid 512 = 2 blocks/CU.
__global__ __launch_bounds__(256) void pred_kernel(const float* __restrict__ th0s,
                                                   const float* __restrict__ ths,
                                                   const float* __restrict__ Lmb,
                                                   const float* __restrict__ Cg,
                                                   float* __restrict__ Gp) {
  int k = blockIdx.z, rch = blockIdx.y, it = blockIdx.x;
  int i0 = it * 256 + threadIdx.x;
  const float* t0k = th0s + k * NN0 * DD;
  const float* thk = ths + k * NN * DD;
  const float* cgk = Cg + k * NN;
  __shared__ float tsl[64 * DD];
  __shared__ float cs[64];
  float t0r[DD];
  int i0c = (i0 < NN0) ? i0 : (NN0 - 1);
#pragma unroll
  for (int j = 0; j < DD; ++j) t0r[j] = t0k[i0c * DD + j];
  float lsig = Lmb[k * 9 + 8];
  float acc = 0.f;
  int rb0 = rch * 500;
  for (int rb = 0; rb < 500; rb += 64) {
    __syncthreads();
    for (int idx = threadIdx.x; idx < 64 * DD; idx += 256) {
      int a = rb0 + rb + (idx >> 3);
      if (a > NN - 1) a = NN - 1;
      tsl[idx] = thk[a * DD + (idx & 7)];
    }
    if (threadIdx.x < 64) {
      int rrr = rb + threadIdx.x;
      cs[threadIdx.x] = (rrr < 500) ? cgk[rb0 + rrr] : 0.f;
    }
    __syncthreads();
#pragma unroll 4
    for (int rr = 0; rr < 64; ++rr) {
      float prod = 1.f, sum = 0.f;
#pragma unroll
      for (int j = 0; j < DD; ++j) {
        float s = fabsf(t0r[j] - tsl[rr * DD + j]);
        prod = __fmaf_rn(prod, s, prod);
        sum += s;
      }
      acc = __fmaf_rn(prod * __expf(lsig - sum), cs[rr], acc);
    }
  }
  if (i0 < NN0) Gp[(k * 8 + rch) * 1024 + i0] = acc;
}

// K8b: reduce ghat partials
__global__ void gred_kernel(const float* __restrict__ Gp, float* __restrict__ ghat) {
  int idx = blockIdx.x * 256 + threadIdx.x;
  if (idx >= KAP * NN0) return;
  int k = idx / NN0, i0 = idx - k * NN0;
  float s = 0.f;
  for (int ch = 0; ch < 8; ++ch) s += Gp[(k * 8 + ch) * 1024 + i0];
  ghat[idx] = s;
}

// ---------------------------------------------------------------------------
// K9: fhat = (Phi @ ghat) * Fstd + Fmean
__global__ __launch_bounds__(256) void final_kernel(const float* __restrict__ Phi,
                                                    const float* __restrict__ ghat,
                                                    const float* __restrict__ Fmean,
                                                    const float* __restrict__ Fstd,
                                                    float* __restrict__ out) {
  int it = blockIdx.y, jt = blockIdx.x;
  int i0 = it * 64, j = jt * 256 + threadIdx.x;
  __shared__ float ph[64 * KAP];
  __shared__ float fm[64], fs[64];
  for (int idx = threadIdx.x; idx < 64 * KAP; idx += 256) {
    int i = idx >> 4, kk = idx & 15;
    int ii = i0 + i; if (ii > MMR - 1) ii = MMR - 1;
    ph[idx] = Phi[ii * KAP + kk];
  }
  if (threadIdx.x < 64) {
    int ii = i0 + threadIdx.x; if (ii > MMR - 1) ii = MMR - 1;
    fm[threadIdx.x] = Fmean[ii];
    fs[threadIdx.x] = Fstd[ii];
  }
  float gj[KAP];
#pragma unroll
  for (int kk = 0; kk < KAP; ++kk) gj[kk] = (j < NN0) ? ghat[kk * NN0 + j] : 0.f;
  __syncthreads();
  if (j < NN0) {
    for (int i = 0; i < 64; ++i) {
      int ii = i0 + i;
      if (ii >= MMR) break;
      float s = 0.f;
#pragma unroll
      for (int kk = 0; kk < KAP; ++kk) s = __fmaf_rn(ph[i * KAP + kk], gj[kk], s);
      out[(size_t)ii * NN0 + j] = __fmaf_rn(s, fs[i], fm[i]);
    }
  }
}

// ---------------------------------------------------------------------------
extern "C" void kernel_launch(void* const* d_in, const int* in_sizes, int n_in,
                              void* d_out, int out_size, void* d_ws, size_t ws_size,
                              hipStream_t stream) {
  const float* theta0 = (const float*)d_in[0];
  const float* Lmb    = (const float*)d_in[1];
  // d_in[2] = lsigma2 (unused by reference output)
  const float* Phi    = (const float*)d_in[3];
  const float* theta  = (const float*)d_in[4];
  const float* thetai = (const float*)d_in[5];
  const float* M      = (const float*)d_in[6];
  const float* Fmean  = (const float*)d_in[7];
  const float* Fstd   = (const float*)d_in[8];
  float* out = (float*)d_out;
  float* ws = (float*)d_ws;

  float* ths   = ws + OFF_THS;
  float* thi   = ws + OFF_THI;
  float* th0s  = ws + OFF_TH0S;
  float* Afull = ws + OFF_AFULL;
  float* LT    = ws + OFF_LT;
  float* Xt    = ws + OFF_XT;     // padded XT (stride XPS), in LROW+XB region
  float* dli   = ws + OFF_DLI;
  float* Crh   = ws + OFF_CRH;
  float* Dinv  = ws + OFF_DINV;
  float* Dg    = ws + OFF_DG;
  float* Vv    = ws + OFF_VV;
  float* Wv    = ws + OFF_WV;
  float* Cg    = ws + OFF_CG;
  float* Gpart = ws + OFF_GPART;
  float* ghat  = ws + OFF_GHAT;
  float* Rpart = ws + OFF_RPART;

  // choose syrk K-chunk count by available workspace (16 -> 8 blocks/CU grid)
  size_t need16 = ((size_t)OFF_RPART + (size_t)KAP * 16 * PP * RST) * sizeof(float);
  size_t need8  = ((size_t)OFF_RPART + (size_t)KAP * 8  * PP * RST) * sizeof(float);
  int nch = (ws_size >= need16) ? 16 : ((ws_size >= need8) ? 8 : 4);

  scale_kernel<<<dim3(163, KAP), 256, 0, stream>>>(theta, thetai, theta0, Lmb, ths, thi, th0s);
  buildci_kernel<<<KAP, 256, 0, stream>>>(thi, Lmb, Afull);
  chol_kernel<<<KAP, 1024, 0, stream>>>(Afull, LT, dli);
  linv_kernel<<<dim3(4, KAP), 256, 0, stream>>>(LT, dli, Xt);
  crh_kernel<<<dim3(63, KAP), 256, 0, stream>>>(ths, thi, Lmb, Xt, M, Crh, Dinv, Dg);
  if (nch == 16) {
    syrk_kernel<16><<<dim3(8, 16, KAP), 256, 0, stream>>>(Crh, Dinv, M, Rpart);
    reducer_kernel<16><<<dim3(157, KAP), 256, 0, stream>>>(Rpart, Afull, Vv);
  } else if (nch == 8) {
    syrk_kernel<8><<<dim3(8, 8, KAP), 256, 0, stream>>>(Crh, Dinv, M, Rpart);
    reducer_kernel<8><<<dim3(157, KAP), 256, 0, stream>>>(Rpart, Afull, Vv);
  } else {
    syrk_kernel<4><<<dim3(8, 4, KAP), 256, 0, stream>>>(Crh, Dinv, M, Rpart);
    reducer_kernel<4><<<dim3(157, KAP), 256, 0, stream>>>(Rpart, Afull, Vv);
  }
  chol_kernel<<<KAP, 1024, 0, stream>>>(Afull, LT, dli);        // Cholesky of R
  linv_kernel<<<dim3(4, KAP), 256, 0, stream>>>(LT, dli, Xt);   // X_R = L_R^{-1} (transposed/padded)
  rsolve_kernel<<<KAP, 256, 0, stream>>>(Xt, Vv, Wv);           // w = X^T X v
  cg_kernel<<<dim3(1000, KAP), 256, 0, stream>>>(Crh, Wv, Dinv, Dg, Cg);
  pred_kernel<<<dim3(4, 8, KAP), 256, 0, stream>>>(th0s, ths, Lmb, Cg, Gpart);
  gred_kernel<<<63, 256, 0, stream>>>(Gpart, ghat);
  final_kernel<<<dim3(4, 188), 256, 0, stream>>>(Phi, ghat, Fmean, Fstd, out);
}

// Round 13
// 701.115 us; speedup vs baseline: 1.1417x; 1.0054x over previous
//
#include <hip/hip_runtime.h>

// Problem constants (fixed by setup_inputs)
#define NN   4000
#define PP   200
#define DD   8
#define KAP  16
#define NN0  1000
#define MMR  12000
#define NUGF 1e-6f

// Rpart row stride (200 R cols + 1 v col + pad)
#define RST  204
// linv slab col stride
#define ACST 64
// chol: panel-transpose LDS row stride (floats), tile count of 50x50 lower tri
#define PTS   208
#define NTILE 1275
// crh Bt row stride
#define BTS  260
// XT padded row stride (cols 200..255 zeroed once -> async 64-lane loads safe)
#define XPS  256

// ---- workspace layout (float offsets); RPART last (variable size) ----
#define OFF_THS    0
#define OFF_THI    (OFF_THS   + KAP*NN*DD)
#define OFF_TH0S   (OFF_THI   + KAP*PP*DD)
#define OFF_AFULL  (OFF_TH0S  + KAP*NN0*DD)
#define OFF_LT     (OFF_AFULL + KAP*PP*PP)
#define OFF_LROW   (OFF_LT    + KAP*PP*PP)
#define OFF_XB     (OFF_LROW  + KAP*PP*PP)
#define OFF_DLI    (OFF_XB    + KAP*PP*PP)
#define OFF_CRH    (OFF_DLI   + KAP*PP)
#define OFF_DINV   (OFF_CRH   + KAP*NN*PP)
#define OFF_DG     (OFF_DINV  + KAP*NN)
#define OFF_VV     (OFF_DG    + KAP*NN)
#define OFF_WV     (OFF_VV    + KAP*PP)
#define OFF_CG     (OFF_WV    + KAP*PP)
#define OFF_GPART  (OFF_CG    + KAP*NN)
#define OFF_GHAT   (OFF_GPART + KAP*8*1024)
#define OFF_RPART  (OFF_GHAT  + KAP*NN0)
// XT (padded, KAP*PP*XPS = 819200 floats) lives in the LROW+XB region (1.28M floats)
#define OFF_XT     OFF_LROW
// need(NCH) = OFF_RPART + KAP*NCH*PP*RST floats

// async global->LDS, 16B per lane; LDS base must be wave-uniform
__device__ __forceinline__ void gld_lds16(const float* g, float* l) {
  __builtin_amdgcn_global_load_lds(
      (const __attribute__((address_space(1))) unsigned int*)g,
      (__attribute__((address_space(3))) unsigned int*)l, 16, 0, 0);
}

// ---------------------------------------------------------------------------
// K0: per-k scaled inputs  x / exp(lmb_j)
__global__ void scale_kernel(const float* __restrict__ theta, const float* __restrict__ thetai,
                             const float* __restrict__ theta0, const float* __restrict__ Lmb,
                             float* __restrict__ ths, float* __restrict__ thi, float* __restrict__ th0s) {
  int k = blockIdx.y;
  int idx = blockIdx.x * 256 + threadIdx.x;
  const int total = (NN + PP + NN0) * DD;
  if (idx >= total) return;
  int row = idx >> 3, j = idx & 7;
  float ils = __expf(-Lmb[k * 9 + j]);
  if (row < NN) {
    ths[(k * NN + row) * DD + j] = theta[row * DD + j] * ils;
  } else if (row < NN + PP) {
    int r = row - NN;
    thi[(k * PP + r) * DD + j] = thetai[r * DD + j] * ils;
  } else {
    int r = row - NN - PP;
    th0s[(k * NN0 + r) * DD + j] = theta0[r * DD + j] * ils;
  }
}

// ---------------------------------------------------------------------------
// K0b: build C_i (full symmetric) per k into Afull
__global__ void buildci_kernel(const float* __restrict__ thi, const float* __restrict__ Lmb,
                               float* __restrict__ A) {
  int k = blockIdx.x;
  __shared__ float ti[PP * DD];
  for (int i = threadIdx.x; i < PP * DD; i += 256) ti[i] = thi[k * PP * DD + i];
  __syncthreads();
  float lsig = Lmb[k * 9 + 8];
  float* Ak = A + k * PP * PP;
  for (int idx = threadIdx.x; idx < PP * PP; idx += 256) {
    int i = idx / PP, j = idx - i * PP;
    float prod = 1.f, sum = 0.f;
#pragma unroll
    for (int t = 0; t < DD; ++t) {
      float s = fabsf(ti[i * DD + t] - ti[j * DD + t]);
      prod = __fmaf_rn(prod, s, prod);  // prod *= (1+s)
      sum += s;
    }
    float val = prod * __expf(lsig - sum);
    if (i == j) val += NUGF * __expf(lsig);
    Ak[idx] = val;
  }
}

// ---------------------------------------------------------------------------
// K1/K6: Cholesky of a 200x200 SPD matrix, REGISTER-resident trailing matrix.
// v3: SPILL-PROOF panel factorization (8x8 diag in 8 regs by lanes 0-7, body
// rows thread-parallel vs LDS factor). Bit-identical LT/dli.
__device__ __forceinline__ float rdlane(float v, int l) {
  return __int_as_float(__builtin_amdgcn_readlane(__float_as_int(v), l));
}

__global__ __launch_bounds__(1024)
void chol_kernel(const float* __restrict__ Ain,
                 float* __restrict__ LT,
                 float* __restrict__ dli) {
  int k = blockIdx.x;
  Ain += (size_t)k * PP * PP; LT += (size_t)k * PP * PP; dli += (size_t)k * PP;
  __shared__ __align__(16) float Ppre[8 * PTS];  // staged panel, [q][r] absolute r
  __shared__ __align__(16) float Pt[8 * PTS];    // factorized panel, [q][r]
  __shared__ float l8[64];                        // 8x8 diag factor, l8[r*8+c]
  __shared__ float invs[8];                       // 1/diag for this panel
  const int tid = threadIdx.x;

  // ---- decode owned tiles (row-tile-major lower triangle), load to regs ----
  int t_rt[2], t_ct[2];
  bool t_ok[2];
  float4 acc[2][4];
#pragma unroll
  for (int t = 0; t < 2; ++t) {
    int ti = (tid - 64) + t * 960;
    t_ok[t] = (tid >= 64) && (ti < NTILE);
    int tie = t_ok[t] ? ti : 0;
    int rt = (int)((sqrtf(8.0f * (float)tie + 1.0f) - 1.0f) * 0.5f);
    while ((rt + 1) * (rt + 2) / 2 <= tie) ++rt;
    while (rt * (rt + 1) / 2 > tie) --rt;
    int ct = tie - rt * (rt + 1) / 2;
    t_rt[t] = rt; t_ct[t] = ct;
    if (t_ok[t]) {
      const float* src = Ain + (size_t)(4 * rt) * PP + 4 * ct;
#pragma unroll
      for (int i = 0; i < 4; ++i) acc[t][i] = *(const float4*)(src + (size_t)i * PP);
    } else {
#pragma unroll
      for (int i = 0; i < 4; ++i) acc[t][i] = make_float4(0.f, 0.f, 0.f, 0.f);
    }
  }

  for (int s = 0; s < 25; ++s) {
    const int jb = 8 * s;
    // ---- owners of the two panel tile-columns stage them to LDS ----
#pragma unroll
    for (int t = 0; t < 2; ++t) {
      if (t_ok[t] && (t_ct[t] >> 1) == s) {
        int q0 = 4 * t_ct[t] - jb;   // 0 or 4
        int r0 = 4 * t_rt[t];
#pragma unroll
        for (int i = 0; i < 4; ++i) {
          Ppre[(q0 + 0) * PTS + r0 + i] = acc[t][i].x;
          Ppre[(q0 + 1) * PTS + r0 + i] = acc[t][i].y;
          Ppre[(q0 + 2) * PTS + r0 + i] = acc[t][i].z;
          Ppre[(q0 + 3) * PTS + r0 + i] = acc[t][i].w;
        }
      }
    }
    __syncthreads();
    const int nrows = PP - jb;
    // ---- lanes 0-7: factorize the 8x8 diagonal block (8 regs, rdlane) ----
    if (tid < 8) {
      const int r = tid;
      float e[8];
#pragma unroll
      for (int c = 0; c < 8; ++c)
        e[c] = (r >= c) ? Ppre[c * PTS + jb + r] : 0.f;
#pragma unroll
      for (int jj = 0; jj < 8; ++jj) {
        float dv = rdlane(e[jj], jj);
        float l = sqrtf(fmaxf(dv, 1e-12f));
        float inv = 1.0f / l;
        if (r > jj) e[jj] *= inv;
        if (r == jj) { e[jj] = l; dli[jb + jj] = inv; invs[jj] = inv; }
#pragma unroll
        for (int c = jj + 1; c < 8; ++c) {
          float pc = rdlane(e[jj], c);
          e[c] = __fmaf_rn(-e[jj], pc, e[c]);
        }
      }
      // publish factor + diag-block LT
#pragma unroll
      for (int c = 0; c < 8; ++c) {
        l8[r * 8 + c] = e[c];
        if (r >= c) LT[(jb + c) * PP + jb + r] = e[c];
      }
    }
    __syncthreads();
    // ---- body rows (thread-parallel): forward-solve vs the 8x8 factor ----
    {
      int rl = 8 + tid;
      if (tid < nrows - 8) {
        float row[8];
#pragma unroll
        for (int c = 0; c < 8; ++c) row[c] = Ppre[c * PTS + jb + rl];
#pragma unroll
        for (int jj = 0; jj < 8; ++jj) {
          float v = row[jj] * invs[jj];
          row[jj] = v;
#pragma unroll
          for (int c = jj + 1; c < 8; ++c)
            row[c] = __fmaf_rn(-v, l8[c * 8 + jj], row[c]);
        }
#pragma unroll
        for (int c = 0; c < 8; ++c) {
          Pt[c * PTS + jb + rl] = row[c];
          LT[(jb + c) * PP + jb + rl] = row[c];
        }
      }
    }
    __syncthreads();
    // ---- rank-8 trailing update on register tiles (reads Pt rows >= jb+8) --
    const int ctmin = 2 * s + 2;
#pragma unroll
    for (int t = 0; t < 2; ++t) {
      if (t_ok[t] && t_ct[t] >= ctmin) {
        const float* pr = Pt + 4 * t_rt[t];
        const float* pcl = Pt + 4 * t_ct[t];
#pragma unroll
        for (int q = 0; q < 8; ++q) {
          float4 a = *(const float4*)(pr + q * PTS);   // broadcast within wave
          float4 b = *(const float4*)(pcl + q * PTS);  // consecutive float4s
          acc[t][0].x = __fmaf_rn(-a.x, b.x, acc[t][0].x);
          acc[t][0].y = __fmaf_rn(-a.x, b.y, acc[t][0].y);
          acc[t][0].z = __fmaf_rn(-a.x, b.z, acc[t][0].z);
          acc[t][0].w = __fmaf_rn(-a.x, b.w, acc[t][0].w);
          acc[t][1].x = __fmaf_rn(-a.y, b.x, acc[t][1].x);
          acc[t][1].y = __fmaf_rn(-a.y, b.y, acc[t][1].y);
          acc[t][1].z = __fmaf_rn(-a.y, b.z, acc[t][1].z);
          acc[t][1].w = __fmaf_rn(-a.y, b.w, acc[t][1].w);
          acc[t][2].x = __fmaf_rn(-a.z, b.x, acc[t][2].x);
          acc[t][2].y = __fmaf_rn(-a.z, b.y, acc[t][2].y);
          acc[t][2].z = __fmaf_rn(-a.z, b.z, acc[t][2].z);
          acc[t][2].w = __fmaf_rn(-a.z, b.w, acc[t][2].w);
          acc[t][3].x = __fmaf_rn(-a.w, b.x, acc[t][3].x);
          acc[t][3].y = __fmaf_rn(-a.w, b.y, acc[t][3].y);
          acc[t][3].z = __fmaf_rn(-a.w, b.z, acc[t][3].z);
          acc[t][3].w = __fmaf_rn(-a.w, b.w, acc[t][3].w);
        }
      }
    }
  }
}

// ---------------------------------------------------------------------------
// K2: X = L^{-1}, column-parallel forward substitution. grid (4, KAP).
// Output stored TRANSPOSED + PADDED: XT[c*XPS + t] = X[t][c].
// v3: transposed-panel staging (Pn2), xf hoisted, acc prefetch; per-row LDS
// ops 18 -> 4. Bit-identical X.
__global__ __launch_bounds__(256) void linv_kernel(const float* __restrict__ LT,
                                                   const float* __restrict__ dli_g,
                                                   float* __restrict__ XT) {
  int cb = blockIdx.x, k = blockIdx.y;
  LT += (size_t)k * PP * PP; dli_g += k * PP; XT += (size_t)k * PP * XPS;
  __shared__ float acc[PP * ACST];            // 51.2 KB slab: acc[r][i]
  __shared__ __align__(16) float Pn2[PP * 8]; // panel transposed: Pn2[r*8+q] = L[r][t0+q]
  __shared__ float xf[8 * ACST];
  __shared__ float dl[PP];
  const int tid = threadIdx.x;
  const int i = tid & 63, rg = tid >> 6;
  const int c = cb + 4 * i;          // owned column (valid if c < PP)
  for (int idx = tid; idx < PP * ACST; idx += 256) acc[idx] = 0.f;
  for (int r = tid; r < PP; r += 256) dl[r] = dli_g[r];
  // zero the padded tail (cols 200..255 of each owned row), once
  {
    float4 z4 = make_float4(0.f, 0.f, 0.f, 0.f);
    for (int idx = tid; idx < 50 * 14; idx += 256) {
      int il = idx / 14, f4 = idx - il * 14;
      int c2 = cb + 4 * il;   // < 200 by construction
      *(float4*)&XT[(size_t)c2 * XPS + 200 + 4 * f4] = z4;
    }
  }
  __syncthreads();
  for (int s = 0; s < 25; ++s) {
    const int t0 = 8 * s;
    // stage transposed: Pn2[r*8+q] = LT[(t0+q)*PP + r]
    for (int idx = tid; idx < 8 * PP; idx += 256) {
      int r = idx >> 3, q = idx & 7;
      Pn2[idx] = LT[(t0 + q) * PP + r];
    }
    __syncthreads();
    if (rg == 0) {
      float sv0[8];
#pragma unroll
      for (int q = 0; q < 8; ++q) sv0[q] = acc[(t0 + q) * ACST + i];
      float xq[8];
#pragma unroll
      for (int q = 0; q < 8; ++q) {
        int t = t0 + q;
        float pn[8];
        *(float4*)&pn[0] = *(const float4*)&Pn2[t * 8];
        *(float4*)&pn[4] = *(const float4*)&Pn2[t * 8 + 4];
        float sv = sv0[q];
#pragma unroll
        for (int m = 0; m < 8; ++m)
          if (m < q) sv = __fmaf_rn(pn[m], xq[m], sv);
        float xv = (((t == c) ? 1.0f : 0.0f) - sv) * dl[t];
        xq[q] = xv;
        xf[q * ACST + i] = xv;
      }
    }
    __syncthreads();
    // XT store: float4 along t (t0+4*q4 .. +3) for owned columns
    if (tid < 128) {
      int q4 = tid >> 6, il = tid & 63;
      int c2 = cb + 4 * il;
      if (c2 < PP) {
        float4 v4 = make_float4(xf[(q4 * 4 + 0) * ACST + il], xf[(q4 * 4 + 1) * ACST + il],
                                xf[(q4 * 4 + 2) * ACST + il], xf[(q4 * 4 + 3) * ACST + il]);
        *(float4*)&XT[(size_t)c2 * XPS + t0 + 4 * q4] = v4;
      }
    }
    // trailing: xf hoisted; per row 2 uniform b128 + acc r/w
    {
      float xr[8];
#pragma unroll
      for (int q = 0; q < 8; ++q) xr[q] = xf[q * ACST + i];
      for (int r = t0 + 8 + rg; r < PP; r += 4) {
        float pn[8];
        *(float4*)&pn[0] = *(const float4*)&Pn2[r * 8];
        *(float4*)&pn[4] = *(const float4*)&Pn2[r * 8 + 4];
        float v = acc[r * ACST + i];
#pragma unroll
        for (int q = 0; q < 8; ++q)
          v = __fmaf_rn(pn[q], xr[q], v);
        acc[r * ACST + i] = v;
      }
    }
    __syncthreads();
  }
}

// ---------------------------------------------------------------------------
// K6b: w = R^{-1} v = X^T (X v). X stored transposed/padded (XT[c*XPS+t]);
// summation ORDER identical (bit-identical w).
__global__ __launch_bounds__(256) void rsolve_kernel(const float* __restrict__ XT,
                                                     const float* __restrict__ v,
                                                     float* __restrict__ w) {
  int k = blockIdx.x;
  XT += (size_t)k * PP * XPS; v += k * PP; w += k * PP;
  __shared__ float vl[PP], yl[PP];
  int tid = threadIdx.x, lane = tid & 63, rg = tid >> 6;
  for (int i = tid; i < PP; i += 256) vl[i] = v[i];
  __syncthreads();
  // y = X v ; X[r][c] = XT[c*XPS+r]
  for (int r = rg; r < PP; r += 4) {
    float s = 0.f;
    for (int c = lane; c < PP; c += 64) s = __fmaf_rn(XT[(size_t)c * XPS + r], vl[c], s);
#pragma unroll
    for (int off = 32; off > 0; off >>= 1) s += __shfl_xor(s, off, 64);
    if (lane == 0) yl[r] = s;
  }
  __syncthreads();
  // w = X^T y ; X[r][tid] = XT[tid*XPS+r]
  if (tid < PP) {
    float s = 0.f;
    for (int r = 0; r < PP; ++r) s = __fmaf_rn(XT[(size_t)tid * XPS + r], yl[r], s);
    w[tid] = s;
  }
}

// ---------------------------------------------------------------------------
// K3: Crh = c_fi @ Linv^T, async B-staging; 64-row register tiles.
// v8: cov phase de-LDS'd. r = tid&63 is THREAD-INVARIANT across the cov
// loop's 4 iterations -> the theta row lives in 8 registers loaded once
// from global (ts LDS deleted); til rows read as 2 uniform ds_read_b128
// (32B-aligned, kkg wave-uniform -> broadcast). Cov LDS 64 scalar ->
// 8 b128 per wave per jb (~370 -> ~96 cyc; round-12 model: cov was ~20%
// of the LDS-pipe bound). Element order lo.x..hi.w == t=0..7 -> identical
// fabsf/fma/add sequence -> bit-identical At/Crh/Dinv/Dg.
__global__ __launch_bounds__(256) void crh_kernel(const float* __restrict__ ths,
                                                  const float* __restrict__ thi,
                                                  const float* __restrict__ Lmb,
                                                  const float* __restrict__ XT,
                                                  const float* __restrict__ Mg,
                                                  float* __restrict__ Crh,
                                                  float* __restrict__ Dinv,
                                                  float* __restrict__ Dg) {
  int k = blockIdx.y, rt = blockIdx.x, r0 = rt * 64;
  const float* thk = ths + k * NN * DD;
  const float* XTk = XT + (size_t)k * PP * XPS;
  float* Ck = Crh + (size_t)k * NN * PP;
  __shared__ __align__(16) float til[PP * DD];   // inducing pts, staged once
  __shared__ __align__(16) float At[16 * 64];
  __shared__ __align__(16) float Bt[16 * BTS];
  int tid = threadIdx.x, tx = tid & 15, ty = tid >> 4;
  const int lr = tid & 63;   // lane in wave (also: this thread's cov row)
  const int wq = tid >> 6;   // wave id 0..3
  float lsig = Lmb[k * 9 + 8];
  for (int idx = tid; idx < PP * DD; idx += 256) til[idx] = thi[k * PP * DD + idx];
  // this thread's theta row, once, in registers (coalesced 32B/lane)
  float t0r[8];
  {
    int rr = r0 + lr; if (rr > NN - 1) rr = NN - 1;
    *(float4*)&t0r[0] = *(const float4*)&thk[rr * DD];
    *(float4*)&t0r[4] = *(const float4*)&thk[rr * DD + 4];
  }
  float acc[4][16];
#pragma unroll
  for (int i = 0; i < 4; ++i)
#pragma unroll
    for (int q = 0; q < 16; ++q) acc[i][q] = 0.f;

  for (int jb = 0; jb < PP; jb += 16) {
    __syncthreads();   // prior FMA readers done; til visible at jb=0
    // ---- issue async B loads: Bt[kk][lane*4..+3] <- XT[(jb+kk)*XPS + lane*4]
#pragma unroll
    for (int u = 0; u < 4; ++u) {
      int kk = wq + 4 * u;           // wave-uniform
      int row = jb + kk;
      if (row < PP)                  // wave-uniform guard
        gld_lds16(XTk + (size_t)row * XPS + lr * 4, &Bt[kk * BTS]);
      // rows >= PP keep stale data; At[kk]=0 there -> contributes exact 0
    }
    // ---- cov -> At (t0r in regs; til via uniform b128; overlaps loads) ----
#pragma unroll
    for (int u = 0; u < 4; ++u) {
      int kk = wq + 4 * u;           // == (tid + 256*u) >> 6
      int kkg = jb + kk;
      float va = 0.f;
      if (kkg < PP) {
        float4 lo = *(const float4*)&til[kkg * 8];
        float4 hi = *(const float4*)&til[kkg * 8 + 4];
        float prod = 1.f, sum = 0.f, s;
        s = fabsf(t0r[0] - lo.x); prod = __fmaf_rn(prod, s, prod); sum += s;
        s = fabsf(t0r[1] - lo.y); prod = __fmaf_rn(prod, s, prod); sum += s;
        s = fabsf(t0r[2] - lo.z); prod = __fmaf_rn(prod, s, prod); sum += s;
        s = fabsf(t0r[3] - lo.w); prod = __fmaf_rn(prod, s, prod); sum += s;
        s = fabsf(t0r[4] - hi.x); prod = __fmaf_rn(prod, s, prod); sum += s;
        s = fabsf(t0r[5] - hi.y); prod = __fmaf_rn(prod, s, prod); sum += s;
        s = fabsf(t0r[6] - hi.z); prod = __fmaf_rn(prod, s, prod); sum += s;
        s = fabsf(t0r[7] - hi.w); prod = __fmaf_rn(prod, s, prod); sum += s;
        va = prod * __expf(lsig - sum);
      }
      At[kk * 64 + lr] = va;
    }
    __syncthreads();   // drains vmcnt(0): Bt ready
#pragma unroll
    for (int kk = 0; kk < 16; ++kk) {
      float4 a4 = *(const float4*)&At[kk * 64 + ty * 4];
      const float* bp = &Bt[kk * BTS + tx * 4];
      float bv[16];
      *(float4*)&bv[0]  = *(const float4*)(bp);
      *(float4*)&bv[4]  = *(const float4*)(bp + 64);
      *(float4*)&bv[8]  = *(const float4*)(bp + 128);
      *(float4*)&bv[12] = *(const float4*)(bp + 192);
      float av[4] = {a4.x, a4.y, a4.z, a4.w};
#pragma unroll
      for (int i = 0; i < 4; ++i)
#pragma unroll
        for (int q = 0; q < 16; ++q)
          acc[i][q] = __fmaf_rn(av[i], bv[q], acc[i][q]);
    }
  }
  // store: thread cols c = tx*4 + 64q (all multiples of 4; c<PP => full float4 valid)
#pragma unroll
  for (int i = 0; i < 4; ++i) {
    int r = r0 + ty * 4 + i;
    if (r < NN) {
#pragma unroll
      for (int q = 0; q < 4; ++q) {
        int c = tx * 4 + 64 * q;
        if (c < PP) {
          float4 v = make_float4(acc[i][q * 4], acc[i][q * 4 + 1], acc[i][q * 4 + 2], acc[i][q * 4 + 3]);
          *(float4*)&Ck[r * PP + c] = v;
        }
      }
    }
  }
  // ---- fused delta: per-row sumsq (cols >= PP contribute exact zeros) ----
  float ss[4];
#pragma unroll
  for (int i = 0; i < 4; ++i) {
    float s = 0.f;
#pragma unroll
    for (int q = 0; q < 16; ++q) s = __fmaf_rn(acc[i][q], acc[i][q], s);
    ss[i] = s;
  }
#pragma unroll
  for (int off = 1; off <= 8; off <<= 1) {
#pragma unroll
    for (int i = 0; i < 4; ++i) ss[i] += __shfl_xor(ss[i], off);
  }
  if (tx == 0) {
    float sig = __expf(lsig);
#pragma unroll
    for (int i = 0; i < 4; ++i) {
      int r = r0 + ty * 4 + i;
      if (r < NN) {
        float delta = fmaxf(sig * (1.f + NUGF) - ss[i], NUGF);
        float di = 1.f / delta;
        Dinv[k * NN + r] = di;
        Dg[k * NN + r] = di * Mg[(size_t)k * NN + r];
      }
    }
  }
}

// ---------------------------------------------------------------------------
// K5: R partials = Crh^T diag(Dinv) [Crh | g] over NCH K-chunks.
// 64x128 tiles; occupancy from NCH=16 (2048 blocks = 8 blocks/CU).
// XCD-GROUPING remap: all 8 tiles of a (k,kch) group land on one XCD so the
// shared 250-row Crh chunk is fetched into that XCD's L2 once. Bijective
// remap; bit-identical.
template <int NCH>
__global__ __launch_bounds__(256) void syrk_kernel(const float* __restrict__ Crh,
                                                   const float* __restrict__ Dinv,
                                                   const float* __restrict__ M,
                                                   float* __restrict__ Rp) {
  const int CH = NN / NCH;
  const int GRP_PER_XCD = (NCH * KAP) / 8;
  int lin = blockIdx.x + 8 * (blockIdx.y + NCH * blockIdx.z);
  int xcd = lin & 7, q = lin >> 3;
  int grp = xcd * GRP_PER_XCD + (q >> 3);
  int tile = q & 7;
  int k = grp / NCH, kch = grp - k * NCH;
  int it = tile >> 1, jc = tile & 1;
  int i0 = it * 64, cb = jc * 128;
  const float* Ck = Crh + (size_t)k * NN * PP;
  float* Rk = Rp + (size_t)(k * NCH + kch) * PP * RST;
  __shared__ __align__(16) float Sc[16 * 64];
  __shared__ __align__(16) float Rw[16 * 128];
  int tid = threadIdx.x, tx = tid & 15, ty = tid >> 4;
  const int kk = ty;            // staging K-row (0..15)
  const int ii4 = tx * 4;       // quad offset
  int rbase0 = kch * CH;
  const float* pA = Ck + (size_t)(rbase0 + kk) * PP + i0 + ii4;
  const float* pB = Ck + (size_t)(rbase0 + kk) * PP + cb + ii4;
  const float* pD = Dinv + (size_t)k * NN + rbase0 + kk;
  const float* pM = M + (size_t)k * NN + rbase0 + kk;
  const bool aok = (i0 + ii4 + 3 < PP);
  const int cg0 = cb + ii4, cg1 = cb + ii4 + 64;
  const bool b0f = (cg0 + 3 < PP);
  const bool b1f = (cg1 + 3 < PP);
  float4 ra, rv0, rv1;
  float acc[4][8];
#pragma unroll
  for (int i = 0; i < 4; ++i)
#pragma unroll
    for (int q2 = 0; q2 < 8; ++q2) acc[i][q2] = 0.f;

  auto stage = [&](int rb) {
    bool rok = (rb + kk < CH);
    float d = rok ? *pD : 0.f;
    if (rok && aok) {
      float4 t = *(const float4*)pA;
      ra = make_float4(t.x * d, t.y * d, t.z * d, t.w * d);
    } else ra = make_float4(0.f, 0.f, 0.f, 0.f);
    if (rok) {
      rv0 = b0f ? *(const float4*)pB : make_float4(0.f, 0.f, 0.f, 0.f);
      if (b1f) rv1 = *(const float4*)(pB + 64);
      else {
        float e[4];
#pragma unroll
        for (int u = 0; u < 4; ++u) {
          int cg = cg1 + u;
          e[u] = (cg < PP) ? pB[64 + u] : ((cg == PP) ? *pM : 0.f);
        }
        rv1 = make_float4(e[0], e[1], e[2], e[3]);
      }
    } else { rv0 = make_float4(0.f, 0.f, 0.f, 0.f); rv1 = rv0; }
    pA += 16 * PP; pB += 16 * PP; pD += 16; pM += 16;
  };
  stage(0);
  for (int rb = 0; rb < CH; rb += 16) {
    __syncthreads();
    *(float4*)&Sc[kk * 64 + ii4] = ra;
    *(float4*)&Rw[kk * 128 + ii4] = rv0;
    *(float4*)&Rw[kk * 128 + ii4 + 64] = rv1;
    __syncthreads();
    stage(rb + 16);   // overlaps with compute below (guards -> 0 past end)
#pragma unroll
    for (int kq = 0; kq < 16; ++kq) {
      float4 a4 = *(const float4*)&Sc[kq * 64 + ty * 4];
      const float* bp = &Rw[kq * 128 + tx * 4];
      float bv[8];
      *(float4*)&bv[0] = *(const float4*)(bp);
      *(float4*)&bv[4] = *(const float4*)(bp + 64);
      float av[4] = {a4.x, a4.y, a4.z, a4.w};
#pragma unroll
      for (int i = 0; i < 4; ++i)
#pragma unroll
        for (int q2 = 0; q2 < 8; ++q2)
          acc[i][q2] = __fmaf_rn(av[i], bv[q2], acc[i][q2]);
    }
  }
#pragma unroll
  for (int i = 0; i < 4; ++i) {
    int r = i0 + ty * 4 + i;
    if (r < PP) {
#pragma unroll
      for (int q2 = 0; q2 < 2; ++q2) {
        int c = cb + tx * 4 + 64 * q2;
        if (c + 3 < PP) {
          float4 v = make_float4(acc[i][q2 * 4], acc[i][q2 * 4 + 1], acc[i][q2 * 4 + 2], acc[i][q2 * 4 + 3]);
          *(float4*)&Rk[r * RST + c] = v;
        } else if (c == PP) {
          Rk[r * RST + c] = acc[i][q2 * 4];   // v column
        }
      }
    }
  }
}

// K5b: R = I + sum partials -> Afull ; v = sum partials col 200 -> Vv
template <int NCH>
__global__ void reducer_kernel(const float* __restrict__ Rp, float* __restrict__ A,
                               float* __restrict__ Vv) {
  int k = blockIdx.y;
  int idx = blockIdx.x * 256 + threadIdx.x;
  if (idx < PP * PP) {
    int i = idx / PP, j = idx - i * PP;
    float s = (i == j) ? 1.0f : 0.0f;
    for (int ch = 0; ch < NCH; ++ch) s += Rp[(size_t)((k * NCH + ch) * PP + i) * RST + j];
    A[k * PP * PP + idx] = s;
  }
  if (idx < PP) {
    float sv = 0.f;
    for (int ch = 0; ch < NCH; ++ch) sv += Rp[(size_t)((k * NCH + ch) * PP + idx) * RST + PP];
    Vv[k * PP + idx] = sv;
  }
}

// ---------------------------------------------------------------------------
// K7: Cinv_g = Dg - Dinv * (Crh @ w)
__global__ void cg_kernel(const float* __restrict__ Crh, const float* __restrict__ w,
                          const float* __restrict__ Dinv, const float* __restrict__ Dg,
                          float* __restrict__ Cg) {
  int k = blockIdx.y;
  __shared__ float ws[PP];
  for (int i = threadIdx.x; i < PP; i += 256) ws[i] = w[k * PP + i];
  __syncthreads();
  int r = blockIdx.x * 4 + (threadIdx.x >> 6);
  int lane = threadIdx.x & 63;
  const float* row = Crh + (size_t)(k * NN + r) * PP;
  float s = 0.f;
  for (int c = lane; c < PP; c += 64) s = __fmaf_rn(row[c], ws[c], s);
#pragma unroll
  for (int off = 32; off > 0; off >>= 1) s += __shfl_xor(s, off, 64);
  if (lane == 0) Cg[k * NN + r] = Dg[k * NN + r] - Dinv[k * NN + r] * s;
}

// ---------------------------------------------------------------------------
// K8: ghat partials = cov(theta0, theta) @ Cinv_g, fused cov+matvec.
// 8 row-chunks of 500 -> grid 512 = 2 blocks/CU.
__global__ __launch_bounds__(256) void pred_kernel(const float* __restrict__ th0s,
                                                   const float* __restrict__ ths,
                                                   const float* __restrict__ Lmb,
                                                   const float* __restrict__ Cg,
                                                   float* __restrict__ Gp) {
  int k = blockIdx.z, rch = blockIdx.y, it = blockIdx.x;
  int i0 = it * 256 + threadIdx.x;
  const float* t0k = th0s + k * NN0 * DD;
  const float* thk = ths + k * NN * DD;
  const float* cgk = Cg + k * NN;
  __shared__ float tsl[64 * DD];
  __shared__ float cs[64];
  float t0r[DD];
  int i0c = (i0 < NN0) ? i0 : (NN0 - 1);
#pragma unroll
  for (int j = 0; j < DD; ++j) t0r[j] = t0k[i0c * DD + j];
  float lsig = Lmb[k * 9 + 8];
  float acc = 0.f;
  int rb0 = rch * 500;
  for (int rb = 0; rb < 500; rb += 64) {
    __syncthreads();
    for (int idx = threadIdx.x; idx < 64 * DD; idx += 256) {
      int a = rb0 + rb + (idx >> 3);
      if (a > NN - 1) a = NN - 1;
      tsl[idx] = thk[a * DD + (idx & 7)];
    }
    if (threadIdx.x < 64) {
      int rrr = rb + threadIdx.x;
      cs[threadIdx.x] = (rrr < 500) ? cgk[rb0 + rrr] : 0.f;
    }
    __syncthreads();
#pragma unroll 4
    for (int rr = 0; rr < 64; ++rr) {
      float prod = 1.f, sum = 0.f;
#pragma unroll
      for (int j = 0; j < DD; ++j) {
        float s = fabsf(t0r[j] - tsl[rr * DD + j]);
        prod = __fmaf_rn(prod, s, prod);
        sum += s;
      }
      acc = __fmaf_rn(prod * __expf(lsig - sum), cs[rr], acc);
    }
  }
  if (i0 < NN0) Gp[(k * 8 + rch) * 1024 + i0] = acc;
}

// K8b: reduce ghat partials
__global__ void gred_kernel(const float* __restrict__ Gp, float* __restrict__ ghat) {
  int idx = blockIdx.x * 256 + threadIdx.x;
  if (idx >= KAP * NN0) return;
  int k = idx / NN0, i0 = idx - k * NN0;
  float s = 0.f;
  for (int ch = 0; ch < 8; ++ch) s += Gp[(k * 8 + ch) * 1024 + i0];
  ghat[idx] = s;
}

// ---------------------------------------------------------------------------
// K9: fhat = (Phi @ ghat) * Fstd + Fmean
__global__ __launch_bounds__(256) void final_kernel(const float* __restrict__ Phi,
                                                    const float* __restrict__ ghat,
                                                    const float* __restrict__ Fmean,
                                                    const float* __restrict__ Fstd,
                                                    float* __restrict__ out) {
  int it = blockIdx.y, jt = blockIdx.x;
  int i0 = it * 64, j = jt * 256 + threadIdx.x;
  __shared__ float ph[64 * KAP];
  __shared__ float fm[64], fs[64];
  for (int idx = threadIdx.x; idx < 64 * KAP; idx += 256) {
    int i = idx >> 4, kk = idx & 15;
    int ii = i0 + i; if (ii > MMR - 1) ii = MMR - 1;
    ph[idx] = Phi[ii * KAP + kk];
  }
  if (threadIdx.x < 64) {
    int ii = i0 + threadIdx.x; if (ii > MMR - 1) ii = MMR - 1;
    fm[threadIdx.x] = Fmean[ii];
    fs[threadIdx.x] = Fstd[ii];
  }
  float gj[KAP];
#pragma unroll
  for (int kk = 0; kk < KAP; ++kk) gj[kk] = (j < NN0) ? ghat[kk * NN0 + j] : 0.f;
  __syncthreads();
  if (j < NN0) {
    for (int i = 0; i < 64; ++i) {
      int ii = i0 + i;
      if (ii >= MMR) break;
      float s = 0.f;
#pragma unroll
      for (int kk = 0; kk < KAP; ++kk) s = __fmaf_rn(ph[i * KAP + kk], gj[kk], s);
      out[(size_t)ii * NN0 + j] = __fmaf_rn(s, fs[i], fm[i]);
    }
  }
}

// ---------------------------------------------------------------------------
extern "C" void kernel_launch(void* const* d_in, const int* in_sizes, int n_in,
                              void* d_out, int out_size, void* d_ws, size_t ws_size,
                              hipStream_t stream) {
  const float* theta0 = (const float*)d_in[0];
  const float* Lmb    = (const float*)d_in[1];
  // d_in[2] = lsigma2 (unused by reference output)
  const float* Phi    = (const float*)d_in[3];
  const float* theta  = (const float*)d_in[4];
  const float* thetai = (const float*)d_in[5];
  const float* M      = (const float*)d_in[6];
  const float* Fmean  = (const float*)d_in[7];
  const float* Fstd   = (const float*)d_in[8];
  float* out = (float*)d_out;
  float* ws = (float*)d_ws;

  float* ths   = ws + OFF_THS;
  float* thi   = ws + OFF_THI;
  float* th0s  = ws + OFF_TH0S;
  float* Afull = ws + OFF_AFULL;
  float* LT    = ws + OFF_LT;
  float* Xt    = ws + OFF_XT;     // padded XT (stride XPS), in LROW+XB region
  float* dli   = ws + OFF_DLI;
  float* Crh   = ws + OFF_CRH;
  float* Dinv  = ws + OFF_DINV;
  float* Dg    = ws + OFF_DG;
  float* Vv    = ws + OFF_VV;
  float* Wv    = ws + OFF_WV;
  float* Cg    = ws + OFF_CG;
  float* Gpart = ws + OFF_GPART;
  float* ghat  = ws + OFF_GHAT;
  float* Rpart = ws + OFF_RPART;

  // choose syrk K-chunk count by available workspace (16 -> 8 blocks/CU grid)
  size_t need16 = ((size_t)OFF_RPART + (size_t)KAP * 16 * PP * RST) * sizeof(float);
  size_t need8  = ((size_t)OFF_RPART + (size_t)KAP * 8  * PP * RST) * sizeof(float);
  int nch = (ws_size >= need16) ? 16 : ((ws_size >= need8) ? 8 : 4);

  scale_kernel<<<dim3(163, KAP), 256, 0, stream>>>(theta, thetai, theta0, Lmb, ths, thi, th0s);
  buildci_kernel<<<KAP, 256, 0, stream>>>(thi, Lmb, Afull);
  chol_kernel<<<KAP, 1024, 0, stream>>>(Afull, LT, dli);
  linv_kernel<<<dim3(4, KAP), 256, 0, stream>>>(LT, dli, Xt);
  crh_kernel<<<dim3(63, KAP), 256, 0, stream>>>(ths, thi, Lmb, Xt, M, Crh, Dinv, Dg);
  if (nch == 16) {
    syrk_kernel<16><<<dim3(8, 16, KAP), 256, 0, stream>>>(Crh, Dinv, M, Rpart);
    reducer_kernel<16><<<dim3(157, KAP), 256, 0, stream>>>(Rpart, Afull, Vv);
  } else if (nch == 8) {
    syrk_kernel<8><<<dim3(8, 8, KAP), 256, 0, stream>>>(Crh, Dinv, M, Rpart);
    reducer_kernel<8><<<dim3(157, KAP), 256, 0, stream>>>(Rpart, Afull, Vv);
  } else {
    syrk_kernel<4><<<dim3(8, 4, KAP), 256, 0, stream>>>(Crh, Dinv, M, Rpart);
    reducer_kernel<4><<<dim3(157, KAP), 256, 0, stream>>>(Rpart, Afull, Vv);
  }
  chol_kernel<<<KAP, 1024, 0, stream>>>(Afull, LT, dli);        // Cholesky of R
  linv_kernel<<<dim3(4, KAP), 256, 0, stream>>>(LT, dli, Xt);   // X_R = L_R^{-1} (transposed/padded)
  rsolve_kernel<<<KAP, 256, 0, stream>>>(Xt, Vv, Wv);           // w = X^T X v
  cg_kernel<<<dim3(1000, KAP), 256, 0, stream>>>(Crh, Wv, Dinv, Dg, Cg);
  pred_kernel<<<dim3(4, 8, KAP), 256, 0, stream>>>(th0s, ths, Lmb, Cg, Gpart);
  gred_kernel<<<63, 256, 0, stream>>>(Gpart, ghat);
  final_kernel<<<dim3(4, 188), 256, 0, stream>>>(Phi, ghat, Fmean, Fstd, out);
}